// Round 7
// baseline (765.388 us; speedup 1.0000x reference)
//
#include <hip/hip_runtime.h>
#include <math.h>

#define NN      50000      // N_NODES
#define BP      4096       // N_PAIRS_MAP
#define NE      500000     // N_EDGES
#define NP      1000000    // N_SCORE_PAIRS
#define FEAT    300
#define KP      320        // FEAT padded to multiple of 32
#define HID     128
#define HEADS   3
#define OUTC    10
#define HC1     (HEADS*HID)   // 384
#define EMBS    12            // embp row stride (floats, 48B = 16B-aligned)
#define TOTE    (NE+NN)       // CSR slots incl. self-loops
#define NEG_SLOPE 0.2f

static inline int cdiv(int a, int b) { return (a + b - 1) / b; }

using bfrag = __attribute__((ext_vector_type(8))) short;
using ffrag = __attribute__((ext_vector_type(4))) float;

__device__ inline float leaky(float x) { return x > 0.f ? x : NEG_SLOPE * x; }
__device__ inline unsigned short bf16_rne(float f) {
    unsigned u = __float_as_uint(f);
    unsigned r = u + 0x7FFFu + ((u >> 16) & 1u);
    return (unsigned short)(r >> 16);
}
__device__ inline float bf16f(unsigned short h) { return __uint_as_float(((unsigned)h) << 16); }
// packed-uint bf16 pair -> floats (1 VALU op each)
__device__ inline float bf16lo(unsigned u) { return __uint_as_float(u << 16); }
__device__ inline float bf16hi(unsigned u) { return __uint_as_float(u & 0xffff0000u); }

__device__ __forceinline__ void gload_lds16(const unsigned short* g, unsigned short* l) {
    __builtin_amdgcn_global_load_lds((const __attribute__((address_space(1))) void*)g,
                                     (__attribute__((address_space(3))) void*)l, 16, 0, 0);
}

__global__ void fill_f32(float* p, float v, long n) {
    long i = (long)blockIdx.x * blockDim.x + threadIdx.x;
    if (i < n) p[i] = v;
}

// fp32 [M][K] -> bf16 hi/lo [M][Kp]; 8 elems/thread, uint4 stores (G13)
__global__ void conv_pad8(const float* __restrict__ in, unsigned short* __restrict__ H,
                          unsigned short* __restrict__ L, long M, int K, int Kp) {
    long idx = (long)blockIdx.x * blockDim.x + threadIdx.x;
    int cpk = Kp >> 3;
    long total = M * cpk;
    if (idx >= total) return;
    int chunk = (int)(idx % cpk);
    long row = idx / cpk;
    int k0 = chunk * 8;
    const float* ip = in + row * K;
    float v[8];
    if (k0 + 8 <= K) {
        float4 a = *(const float4*)(ip + k0);
        float4 b = *(const float4*)(ip + k0 + 4);
        v[0]=a.x; v[1]=a.y; v[2]=a.z; v[3]=a.w; v[4]=b.x; v[5]=b.y; v[6]=b.z; v[7]=b.w;
    } else {
#pragma unroll
        for (int j = 0; j < 8; j++) { int k = k0 + j; v[j] = (k < K) ? ip[k] : 0.f; }
    }
    unsigned short hs[8], ls[8];
#pragma unroll
    for (int j = 0; j < 8; j++) {
        unsigned short h = bf16_rne(v[j]);
        hs[j] = h; ls[j] = bf16_rne(v[j] - bf16f(h));
    }
    long o = row * Kp + k0;
    *(uint4*)&H[o] = *(const uint4*)hs;
    *(uint4*)&L[o] = *(const uint4*)ls;
}

// fp32 [K][N] row-major -> bf16 hi/lo [N][Kp] (transposed, padded; small weights only)
__global__ void convT_pad(const float* __restrict__ in, unsigned short* __restrict__ H,
                          unsigned short* __restrict__ L, int K, int N, int Kp) {
    long idx = (long)blockIdx.x * blockDim.x + threadIdx.x;
    long total = (long)N * Kp;
    if (idx >= total) return;
    int k = (int)(idx % Kp);
    long n = idx / Kp;
    float f = (k < K) ? in[(long)k * N + n] : 0.f;
    unsigned short h = bf16_rne(f);
    H[idx] = h;
    L[idx] = bf16_rne(f - bf16f(h));
}

// ================== split-bf16 MFMA GEMM (64x64 tile, LDS-staged) ==================
template <int MODE>
__global__ __launch_bounds__(256) void gemm_bf(
    const unsigned short* __restrict__ Ah, const unsigned short* __restrict__ Al, int lda,
    const unsigned short* __restrict__ Bh, const unsigned short* __restrict__ Bl, int ldb,
    const float* __restrict__ bias, const float* __restrict__ addsrc,
    float* __restrict__ C0, unsigned short* __restrict__ H0, unsigned short* __restrict__ L0,
    int M, int N, int K, float scale, int ldo)
{
    __shared__ __align__(16) unsigned short Ahs[4][64][8], Als[4][64][8];
    __shared__ __align__(16) unsigned short Bhs[4][64][8], Bls[4][64][8];
    int t = threadIdx.x, w = t >> 6, l = t & 63, lrow = l & 15, lq = l >> 4;
    int rowBase = blockIdx.y * 64, colBase = blockIdx.x * 64;
    int Kr = (K + 31) & ~31;

    int arow = min(rowBase + l, M - 1);
    int brow = min(colBase + l, N - 1);
    const unsigned short* ga_h = Ah + (long)arow * lda + w * 8;
    const unsigned short* ga_l = Al + (long)arow * lda + w * 8;
    const unsigned short* gb_h = Bh + (long)brow * ldb + w * 8;
    const unsigned short* gb_l = Bl + (long)brow * ldb + w * 8;

    ffrag acc[4] = {{0.f,0.f,0.f,0.f},{0.f,0.f,0.f,0.f},{0.f,0.f,0.f,0.f},{0.f,0.f,0.f,0.f}};

    for (int k0 = 0; k0 < Kr; k0 += 32) {
        *(uint4*)&Ahs[w][l][0] = *(const uint4*)(ga_h + k0);
        *(uint4*)&Als[w][l][0] = *(const uint4*)(ga_l + k0);
        *(uint4*)&Bhs[w][l][0] = *(const uint4*)(gb_h + k0);
        *(uint4*)&Bls[w][l][0] = *(const uint4*)(gb_l + k0);
        __syncthreads();
        bfrag ah  = *(const bfrag*)&Ahs[lq][w * 16 + lrow][0];
        bfrag alo = *(const bfrag*)&Als[lq][w * 16 + lrow][0];
#pragma unroll
        for (int ct = 0; ct < 4; ct++) {
            bfrag bh = *(const bfrag*)&Bhs[lq][ct * 16 + lrow][0];
            bfrag bl = *(const bfrag*)&Bls[lq][ct * 16 + lrow][0];
            acc[ct] = __builtin_amdgcn_mfma_f32_16x16x32_bf16(ah,  bh, acc[ct], 0, 0, 0);
            acc[ct] = __builtin_amdgcn_mfma_f32_16x16x32_bf16(ah,  bl, acc[ct], 0, 0, 0);
            acc[ct] = __builtin_amdgcn_mfma_f32_16x16x32_bf16(alo, bh, acc[ct], 0, 0, 0);
        }
        __syncthreads();
    }

#pragma unroll
    for (int ct = 0; ct < 4; ct++) {
        int gc = colBase + ct * 16 + lrow;
        if (gc >= N) continue;
#pragma unroll
        for (int r = 0; r < 4; r++) {
            int gr = rowBase + w * 16 + lq * 4 + r;
            if (gr >= M) continue;
            float v = acc[ct][r];
            if (MODE == 0) {
                float o = v * scale;
                if (bias) o += bias[gc];
                if (addsrc) o += addsrc[(long)gr * ldo + gc];
                C0[(long)gr * ldo + gc] = o;
            } else if (MODE == 1) {
                float o = v + bias[gc];
                unsigned short h = bf16_rne(o);
                H0[(long)gr * ldo + gc] = h;
                L0[(long)gr * ldo + gc] = bf16_rne(o - bf16f(h));
            } else {
                float o = v + bias[gc];
                unsigned short h = bf16_rne(o);
                H0[(long)gc * ldo + gr] = h;
                L0[(long)gc * ldo + gr] = bf16_rne(o - bf16f(h));
            }
        }
    }
}

// ================== split-bf16 GEMM, 128x128 tile, global_load_lds staging ==================
// OUT: 0 = f32 out (* scale), 1 = bf16 (RNE) out
template <bool SPLITK, int OUT>
__global__ __launch_bounds__(256) void gemm_gl128(
    const unsigned short* __restrict__ Ah, long dAl, int lda,
    const unsigned short* __restrict__ Bh, long dBl, int ldb,
    float* __restrict__ C0, unsigned short* __restrict__ Hb,
    int M, int N, int K, float scale, int KC)
{
    __shared__ __align__(16) unsigned short As[128][64];
    __shared__ __align__(16) unsigned short Bs[128][64];
    int t = threadIdx.x, w = t >> 6, l = t & 63, lrow = l & 15, lq = l >> 4;
    int wr = w >> 1, wc = w & 1;
    int rowBase = blockIdx.y * 128, colBase = blockIdx.x * 128;
    int Kr = (K + 31) & ~31;
    int kbeg = SPLITK ? blockIdx.z * KC : 0;
    int kend = SPLITK ? min(Kr, kbeg + KC) : Kr;

    bool isA = (w < 2);
    const unsigned short* Mb = isA ? Ah : Bh;
    long dHL = isA ? dAl : dBl;
    int ld   = isA ? lda : ldb;
    int mx   = (isA ? M : N) - 1;
    int rb0  = (isA ? rowBase : colBase) + (w & 1) * 64;
    int lr8  = l >> 3;
    int lg   = (l & 7) ^ lr8;
    long lane_off = (long)((lg & 3) * 8) + ((lg >> 2) ? dHL : 0);
    const unsigned short* gp[8];
#pragma unroll
    for (int i = 0; i < 8; i++) {
        int r = rb0 + i * 8 + lr8;
        gp[i] = Mb + (long)min(r, mx) * ld + lane_off;
    }
    unsigned short* ldst[8];
    {
        unsigned short (*T)[64] = isA ? As : Bs;
#pragma unroll
        for (int i = 0; i < 8; i++) ldst[i] = &T[(w & 1) * 64 + i * 8][0];
    }

    ffrag acc[4][4];
#pragma unroll
    for (int m = 0; m < 4; m++)
#pragma unroll
        for (int n = 0; n < 4; n++) acc[m][n] = ffrag{0.f, 0.f, 0.f, 0.f};

    int arow0 = wr * 64 + lrow, brow0 = wc * 64 + lrow;
    int xr = lrow & 7;
    int sh = ((lq    ) ^ xr) * 8;
    int sl = ((lq + 4) ^ xr) * 8;

    for (int k0 = kbeg; k0 < kend; k0 += 32) {
#pragma unroll
        for (int i = 0; i < 8; i++) gload_lds16(gp[i] + k0, ldst[i]);
        __syncthreads();

        bfrag bh[4], bl[4];
#pragma unroll
        for (int n = 0; n < 4; n++) {
            bh[n] = *(const bfrag*)&Bs[brow0 + n * 16][sh];
            bl[n] = *(const bfrag*)&Bs[brow0 + n * 16][sl];
        }
#pragma unroll
        for (int m = 0; m < 4; m++) {
            bfrag ah = *(const bfrag*)&As[arow0 + m * 16][sh];
            bfrag al = *(const bfrag*)&As[arow0 + m * 16][sl];
#pragma unroll
            for (int n = 0; n < 4; n++) {
                acc[m][n] = __builtin_amdgcn_mfma_f32_16x16x32_bf16(ah, bh[n], acc[m][n], 0, 0, 0);
                acc[m][n] = __builtin_amdgcn_mfma_f32_16x16x32_bf16(ah, bl[n], acc[m][n], 0, 0, 0);
                acc[m][n] = __builtin_amdgcn_mfma_f32_16x16x32_bf16(al, bh[n], acc[m][n], 0, 0, 0);
            }
        }
        __syncthreads();
    }

#pragma unroll
    for (int n = 0; n < 4; n++) {
        int gc = colBase + wc * 64 + n * 16 + lrow;
        if (gc >= N) continue;
#pragma unroll
        for (int m = 0; m < 4; m++) {
#pragma unroll
            for (int r = 0; r < 4; r++) {
                int gr = rowBase + wr * 64 + m * 16 + lq * 4 + r;
                if (gr >= M) continue;
                if (OUT == 0) {
                    float* Cz = SPLITK ? (C0 + (long)blockIdx.z * M * N) : C0;
                    Cz[(long)gr * N + gc] = acc[m][n][r] * scale;
                } else {
                    Hb[(long)gr * N + gc] = bf16_rne(acc[m][n][r]);
                }
            }
        }
    }
}

// ---------- softmax rows of S -> bf16 hi/lo; 16 contiguous cols/thread ----------
__global__ __launch_bounds__(256) void softmax_hl(const float* __restrict__ S,
                                                  unsigned short* __restrict__ SH,
                                                  unsigned short* __restrict__ SL) {
    int row = blockIdx.x, tid = threadIdx.x;
    const float* p = S + (long)row * BP + tid * 16;
    float ev[16];
    __shared__ float red[256];
    float m = -1e30f;
#pragma unroll
    for (int i = 0; i < 4; i++) {
        float4 a = *(const float4*)(p + i * 4);
        ev[4*i] = a.x; ev[4*i+1] = a.y; ev[4*i+2] = a.z; ev[4*i+3] = a.w;
        m = fmaxf(m, fmaxf(fmaxf(a.x, a.y), fmaxf(a.z, a.w)));
    }
    red[tid] = m; __syncthreads();
    for (int s = 128; s > 0; s >>= 1) { if (tid < s) red[tid] = fmaxf(red[tid], red[tid + s]); __syncthreads(); }
    m = red[0]; __syncthreads();
    float sum = 0.f;
#pragma unroll
    for (int i = 0; i < 16; i++) { float e = expf(ev[i] - m); ev[i] = e; sum += e; }
    red[tid] = sum; __syncthreads();
    for (int s = 128; s > 0; s >>= 1) { if (tid < s) red[tid] += red[tid + s]; __syncthreads(); }
    float inv = 1.0f / red[0];
    unsigned short hs[16], ls[16];
#pragma unroll
    for (int i = 0; i < 16; i++) {
        float e = ev[i] * inv;
        unsigned short h = bf16_rne(e);
        hs[i] = h; ls[i] = bf16_rne(e - bf16f(h));
    }
    long o = (long)row * BP + tid * 16;
    *(uint4*)&SH[o]     = *(const uint4*)&hs[0];
    *(uint4*)&SH[o + 8] = *(const uint4*)&hs[8];
    *(uint4*)&SL[o]     = *(const uint4*)&ls[0];
    *(uint4*)&SL[o + 8] = *(const uint4*)&ls[8];
}

// ---------- split-K reduce + residual -> attn bf16 hi/lo; 8 elems/thread ----------
__global__ void splitk_reduce8(const float* __restrict__ part, const float* __restrict__ resid,
                               unsigned short* __restrict__ H, unsigned short* __restrict__ L,
                               int Mr, int Nc, int Kp2, int sk) {
    long idx = (long)blockIdx.x * blockDim.x + threadIdx.x;
    int cpk = Kp2 >> 3;
    long total = (long)Mr * cpk;
    if (idx >= total) return;
    int chunk = (int)(idx % cpk);
    long row = idx / cpk;
    int c0 = chunk * 8;
    float v[8] = {0.f,0.f,0.f,0.f,0.f,0.f,0.f,0.f};
    if (c0 + 8 <= Nc) {
        long base = row * Nc + c0;
#pragma unroll
        for (int z = 0; z < 8; z++) {
            if (z >= sk) break;
            float4 a = *(const float4*)(part + (long)z * Mr * Nc + base);
            float4 b = *(const float4*)(part + (long)z * Mr * Nc + base + 4);
            v[0]+=a.x; v[1]+=a.y; v[2]+=a.z; v[3]+=a.w; v[4]+=b.x; v[5]+=b.y; v[6]+=b.z; v[7]+=b.w;
        }
        float4 a = *(const float4*)(resid + base);
        float4 b = *(const float4*)(resid + base + 4);
        v[0]+=a.x; v[1]+=a.y; v[2]+=a.z; v[3]+=a.w; v[4]+=b.x; v[5]+=b.y; v[6]+=b.z; v[7]+=b.w;
    } else if (c0 < Nc) {
#pragma unroll
        for (int j = 0; j < 8; j++) {
            int c = c0 + j;
            if (c < Nc) {
                long base = row * Nc + c;
                float s = resid[base];
                for (int z = 0; z < sk; z++) s += part[(long)z * Mr * Nc + base];
                v[j] = s;
            }
        }
    }
    unsigned short hs[8], ls[8];
#pragma unroll
    for (int j = 0; j < 8; j++) {
        unsigned short h = bf16_rne(v[j]);
        hs[j] = h; ls[j] = bf16_rne(v[j] - bf16f(h));
    }
    long o = row * Kp2 + c0;
    *(uint4*)&H[o] = *(const uint4*)hs;
    *(uint4*)&L[o] = *(const uint4*)ls;
}

// ---------- scatter (last write wins), writing bf16 hi/lo x directly ----------
__global__ void scatter_init(int* last, const int* __restrict__ com, int B) {
    int i = blockIdx.x * blockDim.x + threadIdx.x;
    if (i < B) last[com[i]] = -1;
}
__global__ void scatter_max(int* last, const int* __restrict__ com, int B) {
    int i = blockIdx.x * blockDim.x + threadIdx.x;
    if (i < B) atomicMax(&last[com[i]], i);
}
__global__ void scatter_write_hl(const int* __restrict__ last, const int* __restrict__ com,
                                 const float* __restrict__ fused,
                                 unsigned short* __restrict__ xH, unsigned short* __restrict__ xL, int B) {
    int i = blockIdx.x;
    int node = com[i];
    if (last[node] != i) return;
    for (int c = threadIdx.x; c < KP; c += blockDim.x) {
        float f = (c < FEAT) ? fused[(long)i * FEAT + c] : 0.f;
        unsigned short h = bf16_rne(f);
        xH[(long)node * KP + c] = h;
        xL[(long)node * KP + c] = bf16_rne(f - bf16f(h));
    }
}

// ---------- layer-1 coefficients from bf16 h1, wave-per-node, uint-packed ----------
__global__ __launch_bounds__(256) void node_attn_coef3(
    const unsigned short* __restrict__ h1, const float* __restrict__ a_src,
    const float* __restrict__ a_dst, float* __restrict__ es, float* __restrict__ ed, int N)
{
    int w = threadIdx.x >> 6, lane = threadIdx.x & 63;
    int n = blockIdx.x * 4 + w;
    if (n >= N) return;
    const unsigned short* hp = h1 + (long)n * HC1;
    int c = 2 * lane;  // cols c, c+1 within each 128-col head block
    unsigned u0 = *(const unsigned*)&hp[c];
    unsigned u1 = *(const unsigned*)&hp[128 + c];
    unsigned u2 = *(const unsigned*)&hp[256 + c];
    float s0, s1, s2, d0, d1, d2;
    {
        float vl = bf16lo(u0), vh = bf16hi(u0);
        s0 = fmaf(vl, a_src[c], vh * a_src[c + 1]);
        d0 = fmaf(vl, a_dst[c], vh * a_dst[c + 1]);
        vl = bf16lo(u1); vh = bf16hi(u1);
        s1 = fmaf(vl, a_src[128 + c], vh * a_src[128 + c + 1]);
        d1 = fmaf(vl, a_dst[128 + c], vh * a_dst[128 + c + 1]);
        vl = bf16lo(u2); vh = bf16hi(u2);
        s2 = fmaf(vl, a_src[256 + c], vh * a_src[256 + c + 1]);
        d2 = fmaf(vl, a_dst[256 + c], vh * a_dst[256 + c + 1]);
    }
#pragma unroll
    for (int off = 32; off > 0; off >>= 1) {
        s0 += __shfl_down(s0, off); s1 += __shfl_down(s1, off); s2 += __shfl_down(s2, off);
        d0 += __shfl_down(d0, off); d1 += __shfl_down(d1, off); d2 += __shfl_down(d2, off);
    }
    if (lane == 0) {
        es[n * 3 + 0] = s0; es[n * 3 + 1] = s1; es[n * 3 + 2] = s2;
        ed[n * 3 + 0] = d0; ed[n * 3 + 1] = d1; ed[n * 3 + 2] = d2;
    }
}

// ================== CSR build ==================
__global__ void deg_init(int* deg, int n) {
    int i = blockIdx.x * blockDim.x + threadIdx.x;
    if (i < n) deg[i] = 1;
}
__global__ void deg_count(const int* __restrict__ dst, int* deg, int E) {
    int e = blockIdx.x * blockDim.x + threadIdx.x;
    if (e < E) atomicAdd(&deg[dst[e]], 1);
}
__global__ void scan_part(const int* __restrict__ deg, int* __restrict__ bsum, int n) {
    __shared__ int red[256];
    int tid = threadIdx.x;
    int i = blockIdx.x * 256 + tid;
    red[tid] = (i < n) ? deg[i] : 0;
    __syncthreads();
    for (int s = 128; s > 0; s >>= 1) { if (tid < s) red[tid] += red[tid + s]; __syncthreads(); }
    if (tid == 0) bsum[blockIdx.x] = red[0];
}
__global__ __launch_bounds__(256) void scan_bsum(int* __restrict__ bsum, int nb) {
    __shared__ int tmp[256];
    int tid = threadIdx.x;
    int v = (tid < nb) ? bsum[tid] : 0;
    tmp[tid] = v; __syncthreads();
    for (int off = 1; off < 256; off <<= 1) {
        int t2 = (tid >= off) ? tmp[tid - off] : 0;
        __syncthreads();
        tmp[tid] += t2;
        __syncthreads();
    }
    if (tid < nb) bsum[tid] = tmp[tid];
}
__global__ void scan_final(const int* __restrict__ deg, const int* __restrict__ bsum,
                           int* __restrict__ rowptr, int* __restrict__ curs, int n) {
    __shared__ int tmp[256];
    int tid = threadIdx.x;
    int b = blockIdx.x;
    int i = b * 256 + tid;
    int v = (i < n) ? deg[i] : 0;
    tmp[tid] = v; __syncthreads();
    for (int off = 1; off < 256; off <<= 1) {
        int t2 = (tid >= off) ? tmp[tid - off] : 0;
        __syncthreads();
        tmp[tid] += t2;
        __syncthreads();
    }
    int base = (b > 0) ? bsum[b - 1] : 0;
    if (i < n) {
        rowptr[i + 1] = base + tmp[tid];
        curs[i] = base + tmp[tid] - v;
    }
    if (b == 0 && tid == 0) rowptr[0] = 0;
}
// also records csr_dst so scoring can be a single per-edge pass
__global__ void csr_fill(const int* __restrict__ src, const int* __restrict__ dst,
                         int* cursor, int* __restrict__ csr_src, int* __restrict__ csr_dst, int E) {
    int e = blockIdx.x * blockDim.x + threadIdx.x;
    if (e >= E) return;
    int d = dst[e];
    int slot = atomicAdd(&cursor[d], 1);
    csr_src[slot] = src[e];
    csr_dst[slot] = d;
}
__global__ void csr_fill_loops(int* cursor, int* __restrict__ csr_src, int* __restrict__ csr_dst, int n) {
    int i = blockIdx.x * blockDim.x + threadIdx.x;
    if (i >= n) return;
    int slot = atomicAdd(&cursor[i], 1);
    csr_src[slot] = i;
    csr_dst[slot] = i;
}

// ---------- layer-1 scores: ONE per-edge random-gather pass ----------
__global__ void edge_score3(const int* __restrict__ csr_src, const int* __restrict__ csr_dst,
                            const float* __restrict__ es, const float* __restrict__ ed,
                            float4* __restrict__ alpha, int E) {
    int s0 = blockIdx.x * blockDim.x + threadIdx.x;
    if (s0 >= E) return;
    int s = csr_src[s0], d = csr_dst[s0];
    float l0 = leaky(es[s * 3]     + ed[d * 3]);
    float l1 = leaky(es[s * 3 + 1] + ed[d * 3 + 1]);
    float l2 = leaky(es[s * 3 + 2] + ed[d * 3 + 2]);
    alpha[s0] = float4{l0, l1, l2, 0.f};
}
// per-dst softmax over CONTIGUOUS alpha range (no random gathers)
__global__ void seg_norm3(const int* __restrict__ rowptr, float4* __restrict__ alpha, int N) {
    int d = blockIdx.x * blockDim.x + threadIdx.x;
    if (d >= N) return;
    int b = rowptr[d], e = rowptr[d + 1];
    float m0 = -1e30f, m1 = -1e30f, m2 = -1e30f;
    for (int s0 = b; s0 < e; s0++) {
        float4 a = alpha[s0];
        m0 = fmaxf(m0, a.x); m1 = fmaxf(m1, a.y); m2 = fmaxf(m2, a.z);
    }
    float dn0 = 0.f, dn1 = 0.f, dn2 = 0.f;
    for (int s0 = b; s0 < e; s0++) {
        float4 a = alpha[s0];
        float x0 = expf(a.x - m0), x1 = expf(a.y - m1), x2 = expf(a.z - m2);
        dn0 += x0; dn1 += x1; dn2 += x2;
        alpha[s0] = float4{x0, x1, x2, 0.f};
    }
    float i0 = 1.f / (dn0 + 1e-16f), i1 = 1.f / (dn1 + 1e-16f), i2 = 1.f / (dn2 + 1e-16f);
    for (int s0 = b; s0 < e; s0++) {
        float4 a = alpha[s0];
        a.x *= i0; a.y *= i1; a.z *= i2;
        alpha[s0] = a;
    }
}

// ---------- layer-2 coefs (1 head; es2 tiny, L2-resident) ----------
__global__ void csr_maxden_alpha1(const int* __restrict__ rowptr, const int* __restrict__ csr_src,
                                  const float* __restrict__ es, const float* __restrict__ ed,
                                  float* __restrict__ alpha, int N) {
    int d = blockIdx.x * blockDim.x + threadIdx.x;
    if (d >= N) return;
    float edv = ed[d];
    int b = rowptr[d], e = rowptr[d + 1];
    float mm = -1e30f;
    for (int s0 = b; s0 < e; s0++) {
        int s = csr_src[s0];
        mm = fmaxf(mm, leaky(es[s] + edv));
    }
    float dn = 0.f;
    for (int s0 = b; s0 < e; s0++) {
        int s = csr_src[s0];
        float ex = expf(leaky(es[s] + edv) - mm);
        dn += ex;
        alpha[s0] = ex;
    }
    float inv = 1.f / (dn + 1e-16f);
    for (int s0 = b; s0 < e; s0++) alpha[s0] *= inv;
}

// ---------- layer-1 aggregate (bf16 h1, uint-packed) + bias + ELU + (row @ W2) + layer-2 coef ----------
// 192 threads: thread t owns columns 2t, 2t+1 (always same head since 2t even).
// Plain gather loop — instruction-minimal: 1 uint load + 2 bit-converts + 2 FMA
// per edge per thread (depth-4 pipeline removed: it was VALU overhead, r6 PMC).
__global__ __launch_bounds__(192) void csr_agg1_fused(
    const int* __restrict__ rowptr, const int* __restrict__ csr_src,
    const float4* __restrict__ alpha,
    const unsigned short* __restrict__ h1, const float* __restrict__ b1,
    const float* __restrict__ W2, float* __restrict__ h2,
    const float* __restrict__ as2, const float* __restrict__ ad2,
    float* __restrict__ es2, float* __restrict__ ed2, int N)
{
    int d = blockIdx.x;
    int t = threadIdx.x;
    __shared__ float row[HC1];
    __shared__ float part[192][OUTC + 1];

    int b = rowptr[d], e = rowptr[d + 1];
    int c0 = 2 * t;            // columns c0, c0+1
    int hsel = t >> 6;         // head = c0/128
    float a0 = 0.f, a1 = 0.f;

    for (int s0 = b; s0 < e; s0++) {
        int s = csr_src[s0];
        float4 al4 = alpha[s0];
        unsigned u = *(const unsigned*)&h1[(long)s * HC1 + c0];
        float av = (hsel == 0) ? al4.x : ((hsel == 1) ? al4.y : al4.z);
        a0 = fmaf(bf16lo(u), av, a0);
        a1 = fmaf(bf16hi(u), av, a1);
    }

    float v0 = a0 + b1[c0];
    float v1 = a1 + b1[c0 + 1];
    row[c0]     = v0 > 0.f ? v0 : expf(v0) - 1.f;
    row[c0 + 1] = v1 > 0.f ? v1 : expf(v1) - 1.f;
    __syncthreads();

    float pc[OUTC];
#pragma unroll
    for (int c = 0; c < OUTC; c++) pc[c] = 0.f;
    for (int k = t; k < HC1; k += 192) {
        float rv = row[k];
        const float* wp = W2 + (long)k * OUTC;
#pragma unroll
        for (int c = 0; c < OUTC; c++) pc[c] = fmaf(rv, wp[c], pc[c]);
    }
#pragma unroll
    for (int c = 0; c < OUTC; c++) part[t][c] = pc[c];
    __syncthreads();
    for (int off = 96; off > 5; off >>= 1) {   // 96,48,24,12,6
        if (t < off) {
#pragma unroll
            for (int c = 0; c < OUTC; c++) part[t][c] += part[t + off][c];
        }
        __syncthreads();
    }
    if (t < OUTC) {
        float hv = part[0][t] + part[1][t] + part[2][t] + part[3][t] + part[4][t] + part[5][t];
        h2[(long)d * OUTC + t] = hv;
        part[0][t] = hv;
    }
    __syncthreads();
    if (t == 0) {
        float s = 0.f, dd = 0.f;
#pragma unroll
        for (int c = 0; c < OUTC; c++) {
            float hv = part[0][c];
            s  = fmaf(hv, as2[c], s);
            dd = fmaf(hv, ad2[c], dd);
        }
        es2[d] = s; ed2[d] = dd;
    }
}

// ---------- layer-2 aggregate + bias -> padded emb (stride 12) ----------
__global__ void csr_agg2(const int* __restrict__ rowptr, const int* __restrict__ csr_src,
                         const float* __restrict__ alpha,
                         const float* __restrict__ h2, const float* __restrict__ b2,
                         float* __restrict__ emb, int N)
{
    int idx = blockIdx.x * blockDim.x + threadIdx.x;
    if (idx >= N * EMBS) return;
    int d = idx / EMBS, c = idx - d * EMBS;
    if (c >= OUTC) { emb[idx] = 0.f; return; }
    int b = rowptr[d], e = rowptr[d + 1];
    float acc = 0.f;
    for (int s0 = b; s0 < e; s0++) {
        int s = csr_src[s0];
        acc = fmaf(h2[(long)s * OUTC + c], alpha[s0], acc);
    }
    emb[idx] = acc + b2[c];
}

// ---------- pair scores (padded emb: 3 float4 loads per row) ----------
__global__ void pair_score(const int* __restrict__ pairs, const float* __restrict__ emb,
                           float* __restrict__ out, int P) {
    int p = blockIdx.x * blockDim.x + threadIdx.x;
    if (p >= P) return;
    int i0 = pairs[2 * p], i1 = pairs[2 * p + 1];
    const float4* a = (const float4*)(emb + (long)i0 * EMBS);
    const float4* b = (const float4*)(emb + (long)i1 * EMBS);
    float4 a0 = a[0], a1 = a[1], a2 = a[2];
    float4 b0 = b[0], b1 = b[1], b2 = b[2];
    float s = a0.x*b0.x + a0.y*b0.y + a0.z*b0.z + a0.w*b0.w
            + a1.x*b1.x + a1.y*b1.y + a1.z*b1.z + a1.w*b1.w
            + a2.x*b2.x + a2.y*b2.y;
    out[p] = s;
}

extern "C" void kernel_launch(void* const* d_in, const int* in_sizes, int n_in,
                              void* d_out, int out_size, void* d_ws, size_t ws_size,
                              hipStream_t stream) {
    const float* fsub = (const float*)d_in[0];
    const float* fcom = (const float*)d_in[1];
    float*       x    = (float*)d_in[2];
    const int*   com  = (const int*)d_in[3];
    const int*   ei   = (const int*)d_in[4];
    const int*   pidx = (const int*)d_in[5];
    const float* Wq = (const float*)d_in[6];  const float* bq = (const float*)d_in[7];
    const float* Wk = (const float*)d_in[8];  const float* bk = (const float*)d_in[9];
    const float* Wv = (const float*)d_in[10]; const float* bv = (const float*)d_in[11];
    const float* Wf = (const float*)d_in[12]; const float* bf = (const float*)d_in[13];
    const float* W1 = (const float*)d_in[14];
    const float* as1 = (const float*)d_in[15]; const float* ad1 = (const float*)d_in[16];
    const float* b1 = (const float*)d_in[17];
    const float* W2 = (const float*)d_in[18];
    const float* as2 = (const float*)d_in[19]; const float* ad2 = (const float*)d_in[20];
    const float* b2 = (const float*)d_in[21];
    float* out = (float*)d_out;

    const int* src = ei;
    const int* dst = ei + NE;

    typedef unsigned short u16;
    char* ws = (char*)d_ws;
    float* S     = (float*)(ws + 0);            // dead after softmax
    u16*   SH    = (u16*)(ws + 67108864);       // dead after S@v
    u16*   SL    = (u16*)(ws + 100663296);
    u16*   fsubH = (u16*)(ws + 134217728);      // dead after q proj
    u16*   fsubL = (u16*)(ws + 136839168);
    u16*   fcomH = (u16*)(ws + 139460608);      // dead after k,v proj
    u16*   fcomL = (u16*)(ws + 142082048);
    u16*   qH    = (u16*)(ws + 144703488);      // dead after S gemm
    u16*   qL    = (u16*)(ws + 147324928);
    u16*   kH    = (u16*)(ws + 149946368);
    u16*   kL    = (u16*)(ws + 152567808);
    u16*   vTH   = (u16*)(ws + 155189248);      // dead after S@v
    u16*   vTL   = (u16*)(ws + 157646848);
    u16*   attnH = (u16*)(ws + 160104448);      // dead after fus gemm
    u16*   attnL = (u16*)(ws + 162725888);
    u16*   WqTH  = (u16*)(ws + 165347328);
    u16*   WqTL  = (u16*)(ws + 165539328);
    u16*   WkTH  = (u16*)(ws + 165731328);
    u16*   WkTL  = (u16*)(ws + 165923328);
    u16*   WvTH  = (u16*)(ws + 166115328);
    u16*   WvTL  = (u16*)(ws + 166307328);
    u16*   WfTH  = (u16*)(ws + 166499328);
    u16*   WfTL  = (u16*)(ws + 166691328);
    u16*   W1TH  = (u16*)(ws + 166883328);
    u16*   W1TL  = (u16*)(ws + 167129088);
    float* fus   = (float*)(ws + 167374848);    // alive until scatter
    float* es1   = (float*)(ws + 172290048);
    float* ed1   = (float*)(ws + 172890048);
    float* es2   = (float*)(ws + 174690048);
    float* ed2   = (float*)(ws + 174890048);
    float* h2    = (float*)(ws + 175490048);
    int*   last  = (int*)(ws + 179490048);
    int*   deg   = (int*)(ws + 179690048);
    int*   curs  = (int*)(ws + 179890048);
    int*   rowp  = (int*)(ws + 180090048);
    int*   csrc  = (int*)(ws + 180290064);      // ends 182,490,064
    int*   bsum  = (int*)(ws + 182490112);      // 196 ints
    // overlays (disjoint in time):
    float* part   = (float*)(ws + 0);           // over dead S (S@v phase), 4 slices
    u16*   h1b    = (u16*)(ws + 0);             // bf16 h1 over dead S/SH (GAT phase), 38.4MB
    u16*   xH     = (u16*)(ws + 76800000);      // over dead SH/SL; dead after h1 gemm
    u16*   xL     = (u16*)(ws + 108800000);
    float* alpha1 = (float*)(ws + 134217728);   // over dead fsubH.. (GAT phase), 8.8MB
    float* alpha2 = (float*)(ws + 144703488);   // over dead qH (GAT phase), 2.2MB -> ends 146,903,488
    int*   csrd   = (int*)(ws + 160104448);     // over dead attnH (CSR phase on), 2.2MB
    float* embp   = (float*)(ws + 147324928);   // over dead qL/kH, 2.4MB -> ends 149,724,928

    const float inv_sqrt_d = 1.0f / sqrtf((float)FEAT);

    // ===== 0. conversions =====
    hipLaunchKernelGGL(convT_pad, dim3(cdiv(FEAT*KP,256)), dim3(256), 0, stream, Wq, WqTH, WqTL, FEAT, FEAT, KP);
    hipLaunchKernelGGL(convT_pad, dim3(cdiv(FEAT*KP,256)), dim3(256), 0, stream, Wk, WkTH, WkTL, FEAT, FEAT, KP);
    hipLaunchKernelGGL(convT_pad, dim3(cdiv(FEAT*KP,256)), dim3(256), 0, stream, Wv, WvTH, WvTL, FEAT, FEAT, KP);
    hipLaunchKernelGGL(convT_pad, dim3(cdiv(FEAT*KP,256)), dim3(256), 0, stream, Wf, WfTH, WfTL, FEAT, FEAT, KP);
    hipLaunchKernelGGL(convT_pad, dim3(cdiv(HC1*KP,256)),  dim3(256), 0, stream, W1, W1TH, W1TL, FEAT, HC1, KP);
    hipLaunchKernelGGL(conv_pad8, dim3(cdiv(BP*(KP/8),256)), dim3(256), 0, stream, fsub, fsubH, fsubL, BP, FEAT, KP);
    hipLaunchKernelGGL(conv_pad8, dim3(cdiv(BP*(KP/8),256)), dim3(256), 0, stream, fcom, fcomH, fcomL, BP, FEAT, KP);
    hipLaunchKernelGGL(fill_f32, dim3(cdiv(10485760/4,256)), dim3(256), 0, stream, (float*)qH, 0.f, (long)(10485760/4));

    // ===== 1. cross attention =====
    hipLaunchKernelGGL((gemm_bf<1>), dim3(cdiv(FEAT,64), cdiv(BP,64)), dim3(256), 0, stream,
                       fsubH, fsubL, KP, WqTH, WqTL, KP, bq, nullptr, nullptr, qH, qL,
                       BP, FEAT, FEAT, 1.0f, KP);
    hipLaunchKernelGGL((gemm_bf<1>), dim3(cdiv(FEAT,64), cdiv(BP,64)), dim3(256), 0, stream,
                       fcomH, fcomL, KP, WkTH, WkTL, KP, bk, nullptr, nullptr, kH, kL,
                       BP, FEAT, FEAT, 1.0f, KP);
    hipLaunchKernelGGL((gemm_bf<2>), dim3(cdiv(FEAT,64), cdiv(BP,64)), dim3(256), 0, stream,
                       fcomH, fcomL, KP, WvTH, WvTL, KP, bv, nullptr, nullptr, vTH, vTL,
                       BP, FEAT, FEAT, 1.0f, BP);
    hipLaunchKernelGGL((gemm_gl128<false, 0>), dim3(cdiv(BP,128), cdiv(BP,128)), dim3(256), 0, stream,
                       qH, (long)(qL - qH), KP, kH, (long)(kL - kH), KP,
                       S, nullptr, BP, BP, FEAT, inv_sqrt_d, 0);
    hipLaunchKernelGGL(softmax_hl, dim3(BP), dim3(256), 0, stream, S, SH, SL);
    hipLaunchKernelGGL((gemm_gl128<true, 0>), dim3(cdiv(FEAT,128), cdiv(BP,128), 4), dim3(256), 0, stream,
                       SH, (long)(SL - SH), BP, vTH, (long)(vTL - vTH), BP,
                       part, nullptr, BP, FEAT, BP, 1.0f, 1024);
    hipLaunchKernelGGL(splitk_reduce8, dim3(cdiv(BP*(KP/8),256)), dim3(256), 0, stream,
                       part, fsub, attnH, attnL, BP, FEAT, KP, 4);
    hipLaunchKernelGGL((gemm_bf<0>), dim3(cdiv(FEAT,64), cdiv(BP,64)), dim3(256), 0, stream,
                       attnH, attnL, KP, WfTH, WfTL, KP, bf, nullptr, fus, nullptr, nullptr,
                       BP, FEAT, FEAT, 1.0f, FEAT);

    // ===== 2. convert pristine x, then scatter fused rows directly as bf16 =====
    hipLaunchKernelGGL(conv_pad8, dim3(cdiv((long)NN*(KP/8),256)), dim3(256), 0, stream, x, xH, xL, NN, FEAT, KP);
    hipLaunchKernelGGL(scatter_init, dim3(cdiv(BP,256)), dim3(256), 0, stream, last, com, BP);
    hipLaunchKernelGGL(scatter_max,  dim3(cdiv(BP,256)), dim3(256), 0, stream, last, com, BP);
    hipLaunchKernelGGL(scatter_write_hl, dim3(BP), dim3(128), 0, stream, last, com, fus, xH, xL, BP);

    // ===== 3. CSR build =====
    hipLaunchKernelGGL(deg_init,  dim3(cdiv(NN,256)), dim3(256), 0, stream, deg, NN);
    hipLaunchKernelGGL(deg_count, dim3(cdiv(NE,256)), dim3(256), 0, stream, dst, deg, NE);
    {
        int nb = cdiv(NN, 256);   // 196
        hipLaunchKernelGGL(scan_part,  dim3(nb), dim3(256), 0, stream, deg, bsum, NN);
        hipLaunchKernelGGL(scan_bsum,  dim3(1),  dim3(256), 0, stream, bsum, nb);
        hipLaunchKernelGGL(scan_final, dim3(nb), dim3(256), 0, stream, deg, bsum, rowp, curs, NN);
    }
    hipLaunchKernelGGL(csr_fill, dim3(cdiv(NE,256)), dim3(256), 0, stream, src, dst, curs, csrc, csrd, NE);
    hipLaunchKernelGGL(csr_fill_loops, dim3(cdiv(NN,256)), dim3(256), 0, stream, curs, csrc, csrd, NN);

    // ===== 4. GAT layer 1 (h1 in bf16: gather working set 38.4 MB) =====
    hipLaunchKernelGGL((gemm_gl128<false, 1>), dim3(cdiv(HC1,128), cdiv(NN,128)), dim3(256), 0, stream,
                       xH, (long)(xL - xH), KP, W1TH, (long)(W1TL - W1TH), KP,
                       nullptr, h1b, NN, HC1, FEAT, 1.0f, 0);
    hipLaunchKernelGGL(node_attn_coef3, dim3(cdiv(NN,4)), dim3(256), 0, stream,
                       h1b, as1, ad1, es1, ed1, NN);
    hipLaunchKernelGGL(edge_score3, dim3(cdiv(TOTE,256)), dim3(256), 0, stream,
                       csrc, csrd, es1, ed1, (float4*)alpha1, TOTE);
    hipLaunchKernelGGL(seg_norm3, dim3(cdiv(NN,256)), dim3(256), 0, stream,
                       rowp, (float4*)alpha1, NN);
    hipLaunchKernelGGL(csr_agg1_fused, dim3(NN), dim3(192), 0, stream,
                       rowp, csrc, (const float4*)alpha1, h1b, b1, W2, h2, as2, ad2, es2, ed2, NN);

    // ===== 5. GAT layer 2 =====
    hipLaunchKernelGGL(csr_maxden_alpha1, dim3(cdiv(NN,256)), dim3(256), 0, stream,
                       rowp, csrc, es2, ed2, alpha2, NN);
    hipLaunchKernelGGL(csr_agg2, dim3(cdiv(NN*EMBS,256)), dim3(256), 0, stream,
                       rowp, csrc, alpha2, h2, b2, embp, NN);

    // ===== 6. pair scores =====
    hipLaunchKernelGGL(pair_score, dim3(cdiv(NP,256)), dim3(256), 0, stream, pidx, embp, out, NP);
}

// Round 8
// 756.426 us; speedup vs baseline: 1.0118x; 1.0118x over previous
//
#include <hip/hip_runtime.h>
#include <math.h>

#define NN      50000      // N_NODES
#define BP      4096       // N_PAIRS_MAP
#define NE      500000     // N_EDGES
#define NP      1000000    // N_SCORE_PAIRS
#define FEAT    300
#define KP      320        // FEAT padded to multiple of 32
#define HID     128
#define HEADS   3
#define OUTC    10
#define HC1     (HEADS*HID)   // 384
#define EMBS    12            // embp row stride (floats, 48B = 16B-aligned)
#define TOTE    (NE+NN)       // CSR slots incl. self-loops
#define NEG_SLOPE 0.2f

static inline int cdiv(int a, int b) { return (a + b - 1) / b; }

using bfrag = __attribute__((ext_vector_type(8))) short;
using ffrag = __attribute__((ext_vector_type(4))) float;

__device__ inline float leaky(float x) { return x > 0.f ? x : NEG_SLOPE * x; }
__device__ inline unsigned short bf16_rne(float f) {
    unsigned u = __float_as_uint(f);
    unsigned r = u + 0x7FFFu + ((u >> 16) & 1u);
    return (unsigned short)(r >> 16);
}
__device__ inline float bf16f(unsigned short h) { return __uint_as_float(((unsigned)h) << 16); }
// packed-uint bf16 pair -> floats (1 VALU op each)
__device__ inline float bf16lo(unsigned u) { return __uint_as_float(u << 16); }
__device__ inline float bf16hi(unsigned u) { return __uint_as_float(u & 0xffff0000u); }

__device__ __forceinline__ void gload_lds16(const unsigned short* g, unsigned short* l) {
    __builtin_amdgcn_global_load_lds((const __attribute__((address_space(1))) void*)g,
                                     (__attribute__((address_space(3))) void*)l, 16, 0, 0);
}

__global__ void fill_f32(float* p, float v, long n) {
    long i = (long)blockIdx.x * blockDim.x + threadIdx.x;
    if (i < n) p[i] = v;
}

// fp32 [M][K] -> bf16 hi/lo [M][Kp]; 8 elems/thread, uint4 stores (G13)
__global__ void conv_pad8(const float* __restrict__ in, unsigned short* __restrict__ H,
                          unsigned short* __restrict__ L, long M, int K, int Kp) {
    long idx = (long)blockIdx.x * blockDim.x + threadIdx.x;
    int cpk = Kp >> 3;
    long total = M * cpk;
    if (idx >= total) return;
    int chunk = (int)(idx % cpk);
    long row = idx / cpk;
    int k0 = chunk * 8;
    const float* ip = in + row * K;
    float v[8];
    if (k0 + 8 <= K) {
        float4 a = *(const float4*)(ip + k0);
        float4 b = *(const float4*)(ip + k0 + 4);
        v[0]=a.x; v[1]=a.y; v[2]=a.z; v[3]=a.w; v[4]=b.x; v[5]=b.y; v[6]=b.z; v[7]=b.w;
    } else {
#pragma unroll
        for (int j = 0; j < 8; j++) { int k = k0 + j; v[j] = (k < K) ? ip[k] : 0.f; }
    }
    unsigned short hs[8], ls[8];
#pragma unroll
    for (int j = 0; j < 8; j++) {
        unsigned short h = bf16_rne(v[j]);
        hs[j] = h; ls[j] = bf16_rne(v[j] - bf16f(h));
    }
    long o = row * Kp + k0;
    *(uint4*)&H[o] = *(const uint4*)hs;
    *(uint4*)&L[o] = *(const uint4*)ls;
}

// fp32 [K][N] row-major -> bf16 hi/lo [N][Kp] (transposed, padded; small weights only)
__global__ void convT_pad(const float* __restrict__ in, unsigned short* __restrict__ H,
                          unsigned short* __restrict__ L, int K, int N, int Kp) {
    long idx = (long)blockIdx.x * blockDim.x + threadIdx.x;
    long total = (long)N * Kp;
    if (idx >= total) return;
    int k = (int)(idx % Kp);
    long n = idx / Kp;
    float f = (k < K) ? in[(long)k * N + n] : 0.f;
    unsigned short h = bf16_rne(f);
    H[idx] = h;
    L[idx] = bf16_rne(f - bf16f(h));
}

// ================== split-bf16 GEMM, 128x128 tile, global_load_lds staging ==================
// OUT: 0 = f32 out (acc*scale [+bias]), 1 = bf16 (RNE) out,
//      2 = bf16 hi/lo out (+bias), row-major stride ldo,
//      3 = transposed bf16 hi/lo out (+bias), stride ldo.
// MFMA loop identical across OUT (bitwise-same accumulation as the old 64-tile
// gemm_bf: same K-step order, same ah*bh / ah*bl / al*bh sequence).
template <bool SPLITK, int OUT>
__global__ __launch_bounds__(256) void gemm_gl128(
    const unsigned short* __restrict__ Ah, long dAl, int lda,
    const unsigned short* __restrict__ Bh, long dBl, int ldb,
    const float* __restrict__ bias,
    float* __restrict__ C0, unsigned short* __restrict__ Hb, unsigned short* __restrict__ Lb,
    int M, int N, int K, float scale, int ldo, int KC)
{
    __shared__ __align__(16) unsigned short As[128][64];
    __shared__ __align__(16) unsigned short Bs[128][64];
    int t = threadIdx.x, w = t >> 6, l = t & 63, lrow = l & 15, lq = l >> 4;
    int wr = w >> 1, wc = w & 1;
    int rowBase = blockIdx.y * 128, colBase = blockIdx.x * 128;
    int Kr = (K + 31) & ~31;
    int kbeg = SPLITK ? blockIdx.z * KC : 0;
    int kend = SPLITK ? min(Kr, kbeg + KC) : Kr;

    bool isA = (w < 2);
    const unsigned short* Mb = isA ? Ah : Bh;
    long dHL = isA ? dAl : dBl;
    int ld   = isA ? lda : ldb;
    int mx   = (isA ? M : N) - 1;
    int rb0  = (isA ? rowBase : colBase) + (w & 1) * 64;
    int lr8  = l >> 3;
    int lg   = (l & 7) ^ lr8;
    long lane_off = (long)((lg & 3) * 8) + ((lg >> 2) ? dHL : 0);
    const unsigned short* gp[8];
#pragma unroll
    for (int i = 0; i < 8; i++) {
        int r = rb0 + i * 8 + lr8;
        gp[i] = Mb + (long)min(r, mx) * ld + lane_off;
    }
    unsigned short* ldst[8];
    {
        unsigned short (*T)[64] = isA ? As : Bs;
#pragma unroll
        for (int i = 0; i < 8; i++) ldst[i] = &T[(w & 1) * 64 + i * 8][0];
    }

    ffrag acc[4][4];
#pragma unroll
    for (int m = 0; m < 4; m++)
#pragma unroll
        for (int n = 0; n < 4; n++) acc[m][n] = ffrag{0.f, 0.f, 0.f, 0.f};

    int arow0 = wr * 64 + lrow, brow0 = wc * 64 + lrow;
    int xr = lrow & 7;
    int sh = ((lq    ) ^ xr) * 8;
    int sl = ((lq + 4) ^ xr) * 8;

    for (int k0 = kbeg; k0 < kend; k0 += 32) {
#pragma unroll
        for (int i = 0; i < 8; i++) gload_lds16(gp[i] + k0, ldst[i]);
        __syncthreads();

        bfrag bh[4], bl[4];
#pragma unroll
        for (int n = 0; n < 4; n++) {
            bh[n] = *(const bfrag*)&Bs[brow0 + n * 16][sh];
            bl[n] = *(const bfrag*)&Bs[brow0 + n * 16][sl];
        }
#pragma unroll
        for (int m = 0; m < 4; m++) {
            bfrag ah = *(const bfrag*)&As[arow0 + m * 16][sh];
            bfrag al = *(const bfrag*)&As[arow0 + m * 16][sl];
#pragma unroll
            for (int n = 0; n < 4; n++) {
                acc[m][n] = __builtin_amdgcn_mfma_f32_16x16x32_bf16(ah, bh[n], acc[m][n], 0, 0, 0);
                acc[m][n] = __builtin_amdgcn_mfma_f32_16x16x32_bf16(ah, bl[n], acc[m][n], 0, 0, 0);
                acc[m][n] = __builtin_amdgcn_mfma_f32_16x16x32_bf16(al, bh[n], acc[m][n], 0, 0, 0);
            }
        }
        __syncthreads();
    }

#pragma unroll
    for (int n = 0; n < 4; n++) {
        int gc = colBase + wc * 64 + n * 16 + lrow;
        if (gc >= N) continue;
#pragma unroll
        for (int m = 0; m < 4; m++) {
#pragma unroll
            for (int r = 0; r < 4; r++) {
                int gr = rowBase + wr * 64 + m * 16 + lq * 4 + r;
                if (gr >= M) continue;
                float v = acc[m][n][r];
                if (OUT == 0) {
                    float* Cz = SPLITK ? (C0 + (long)blockIdx.z * M * N) : C0;
                    float o = v * scale;
                    if (bias) o += bias[gc];
                    Cz[(long)gr * N + gc] = o;
                } else if (OUT == 1) {
                    Hb[(long)gr * N + gc] = bf16_rne(v);
                } else if (OUT == 2) {
                    float o = v + bias[gc];
                    unsigned short h = bf16_rne(o);
                    Hb[(long)gr * ldo + gc] = h;
                    Lb[(long)gr * ldo + gc] = bf16_rne(o - bf16f(h));
                } else {
                    float o = v + bias[gc];
                    unsigned short h = bf16_rne(o);
                    Hb[(long)gc * ldo + gr] = h;
                    Lb[(long)gc * ldo + gr] = bf16_rne(o - bf16f(h));
                }
            }
        }
    }
}

// ---------- softmax rows of S -> bf16 hi/lo; 16 contiguous cols/thread ----------
__global__ __launch_bounds__(256) void softmax_hl(const float* __restrict__ S,
                                                  unsigned short* __restrict__ SH,
                                                  unsigned short* __restrict__ SL) {
    int row = blockIdx.x, tid = threadIdx.x;
    const float* p = S + (long)row * BP + tid * 16;
    float ev[16];
    __shared__ float red[256];
    float m = -1e30f;
#pragma unroll
    for (int i = 0; i < 4; i++) {
        float4 a = *(const float4*)(p + i * 4);
        ev[4*i] = a.x; ev[4*i+1] = a.y; ev[4*i+2] = a.z; ev[4*i+3] = a.w;
        m = fmaxf(m, fmaxf(fmaxf(a.x, a.y), fmaxf(a.z, a.w)));
    }
    red[tid] = m; __syncthreads();
    for (int s = 128; s > 0; s >>= 1) { if (tid < s) red[tid] = fmaxf(red[tid], red[tid + s]); __syncthreads(); }
    m = red[0]; __syncthreads();
    float sum = 0.f;
#pragma unroll
    for (int i = 0; i < 16; i++) { float e = expf(ev[i] - m); ev[i] = e; sum += e; }
    red[tid] = sum; __syncthreads();
    for (int s = 128; s > 0; s >>= 1) { if (tid < s) red[tid] += red[tid + s]; __syncthreads(); }
    float inv = 1.0f / red[0];
    unsigned short hs[16], ls[16];
#pragma unroll
    for (int i = 0; i < 16; i++) {
        float e = ev[i] * inv;
        unsigned short h = bf16_rne(e);
        hs[i] = h; ls[i] = bf16_rne(e - bf16f(h));
    }
    long o = (long)row * BP + tid * 16;
    *(uint4*)&SH[o]     = *(const uint4*)&hs[0];
    *(uint4*)&SH[o + 8] = *(const uint4*)&hs[8];
    *(uint4*)&SL[o]     = *(const uint4*)&ls[0];
    *(uint4*)&SL[o + 8] = *(const uint4*)&ls[8];
}

// ---------- split-K reduce + residual -> attn bf16 hi/lo; 8 elems/thread ----------
__global__ void splitk_reduce8(const float* __restrict__ part, const float* __restrict__ resid,
                               unsigned short* __restrict__ H, unsigned short* __restrict__ L,
                               int Mr, int Nc, int Kp2, int sk) {
    long idx = (long)blockIdx.x * blockDim.x + threadIdx.x;
    int cpk = Kp2 >> 3;
    long total = (long)Mr * cpk;
    if (idx >= total) return;
    int chunk = (int)(idx % cpk);
    long row = idx / cpk;
    int c0 = chunk * 8;
    float v[8] = {0.f,0.f,0.f,0.f,0.f,0.f,0.f,0.f};
    if (c0 + 8 <= Nc) {
        long base = row * Nc + c0;
#pragma unroll
        for (int z = 0; z < 8; z++) {
            if (z >= sk) break;
            float4 a = *(const float4*)(part + (long)z * Mr * Nc + base);
            float4 b = *(const float4*)(part + (long)z * Mr * Nc + base + 4);
            v[0]+=a.x; v[1]+=a.y; v[2]+=a.z; v[3]+=a.w; v[4]+=b.x; v[5]+=b.y; v[6]+=b.z; v[7]+=b.w;
        }
        float4 a = *(const float4*)(resid + base);
        float4 b = *(const float4*)(resid + base + 4);
        v[0]+=a.x; v[1]+=a.y; v[2]+=a.z; v[3]+=a.w; v[4]+=b.x; v[5]+=b.y; v[6]+=b.z; v[7]+=b.w;
    } else if (c0 < Nc) {
#pragma unroll
        for (int j = 0; j < 8; j++) {
            int c = c0 + j;
            if (c < Nc) {
                long base = row * Nc + c;
                float s = resid[base];
                for (int z = 0; z < sk; z++) s += part[(long)z * Mr * Nc + base];
                v[j] = s;
            }
        }
    }
    unsigned short hs[8], ls[8];
#pragma unroll
    for (int j = 0; j < 8; j++) {
        unsigned short h = bf16_rne(v[j]);
        hs[j] = h; ls[j] = bf16_rne(v[j] - bf16f(h));
    }
    long o = row * Kp2 + c0;
    *(uint4*)&H[o] = *(const uint4*)hs;
    *(uint4*)&L[o] = *(const uint4*)ls;
}

// ---------- scatter (last write wins), writing bf16 hi/lo x directly ----------
__global__ void scatter_init(int* last, const int* __restrict__ com, int B) {
    int i = blockIdx.x * blockDim.x + threadIdx.x;
    if (i < B) last[com[i]] = -1;
}
__global__ void scatter_max(int* last, const int* __restrict__ com, int B) {
    int i = blockIdx.x * blockDim.x + threadIdx.x;
    if (i < B) atomicMax(&last[com[i]], i);
}
__global__ void scatter_write_hl(const int* __restrict__ last, const int* __restrict__ com,
                                 const float* __restrict__ fused,
                                 unsigned short* __restrict__ xH, unsigned short* __restrict__ xL, int B) {
    int i = blockIdx.x;
    int node = com[i];
    if (last[node] != i) return;
    for (int c = threadIdx.x; c < KP; c += blockDim.x) {
        float f = (c < FEAT) ? fused[(long)i * FEAT + c] : 0.f;
        unsigned short h = bf16_rne(f);
        xH[(long)node * KP + c] = h;
        xL[(long)node * KP + c] = bf16_rne(f - bf16f(h));
    }
}

// ---------- layer-1 coefficients from bf16 h1, wave-per-node, uint-packed ----------
__global__ __launch_bounds__(256) void node_attn_coef3(
    const unsigned short* __restrict__ h1, const float* __restrict__ a_src,
    const float* __restrict__ a_dst, float* __restrict__ es, float* __restrict__ ed, int N)
{
    int w = threadIdx.x >> 6, lane = threadIdx.x & 63;
    int n = blockIdx.x * 4 + w;
    if (n >= N) return;
    const unsigned short* hp = h1 + (long)n * HC1;
    int c = 2 * lane;  // cols c, c+1 within each 128-col head block
    unsigned u0 = *(const unsigned*)&hp[c];
    unsigned u1 = *(const unsigned*)&hp[128 + c];
    unsigned u2 = *(const unsigned*)&hp[256 + c];
    float s0, s1, s2, d0, d1, d2;
    {
        float vl = bf16lo(u0), vh = bf16hi(u0);
        s0 = fmaf(vl, a_src[c], vh * a_src[c + 1]);
        d0 = fmaf(vl, a_dst[c], vh * a_dst[c + 1]);
        vl = bf16lo(u1); vh = bf16hi(u1);
        s1 = fmaf(vl, a_src[128 + c], vh * a_src[128 + c + 1]);
        d1 = fmaf(vl, a_dst[128 + c], vh * a_dst[128 + c + 1]);
        vl = bf16lo(u2); vh = bf16hi(u2);
        s2 = fmaf(vl, a_src[256 + c], vh * a_src[256 + c + 1]);
        d2 = fmaf(vl, a_dst[256 + c], vh * a_dst[256 + c + 1]);
    }
#pragma unroll
    for (int off = 32; off > 0; off >>= 1) {
        s0 += __shfl_down(s0, off); s1 += __shfl_down(s1, off); s2 += __shfl_down(s2, off);
        d0 += __shfl_down(d0, off); d1 += __shfl_down(d1, off); d2 += __shfl_down(d2, off);
    }
    if (lane == 0) {
        es[n * 3 + 0] = s0; es[n * 3 + 1] = s1; es[n * 3 + 2] = s2;
        ed[n * 3 + 0] = d0; ed[n * 3 + 1] = d1; ed[n * 3 + 2] = d2;
    }
}

// ================== CSR build ==================
__global__ void deg_init(int* deg, int n) {
    int i = blockIdx.x * blockDim.x + threadIdx.x;
    if (i < n) deg[i] = 1;
}
__global__ void deg_count(const int* __restrict__ dst, int* deg, int E) {
    int e = blockIdx.x * blockDim.x + threadIdx.x;
    if (e < E) atomicAdd(&deg[dst[e]], 1);
}
__global__ void scan_part(const int* __restrict__ deg, int* __restrict__ bsum, int n) {
    __shared__ int red[256];
    int tid = threadIdx.x;
    int i = blockIdx.x * 256 + tid;
    red[tid] = (i < n) ? deg[i] : 0;
    __syncthreads();
    for (int s = 128; s > 0; s >>= 1) { if (tid < s) red[tid] += red[tid + s]; __syncthreads(); }
    if (tid == 0) bsum[blockIdx.x] = red[0];
}
__global__ __launch_bounds__(256) void scan_bsum(int* __restrict__ bsum, int nb) {
    __shared__ int tmp[256];
    int tid = threadIdx.x;
    int v = (tid < nb) ? bsum[tid] : 0;
    tmp[tid] = v; __syncthreads();
    for (int off = 1; off < 256; off <<= 1) {
        int t2 = (tid >= off) ? tmp[tid - off] : 0;
        __syncthreads();
        tmp[tid] += t2;
        __syncthreads();
    }
    if (tid < nb) bsum[tid] = tmp[tid];
}
__global__ void scan_final(const int* __restrict__ deg, const int* __restrict__ bsum,
                           int* __restrict__ rowptr, int* __restrict__ curs, int n) {
    __shared__ int tmp[256];
    int tid = threadIdx.x;
    int b = blockIdx.x;
    int i = b * 256 + tid;
    int v = (i < n) ? deg[i] : 0;
    tmp[tid] = v; __syncthreads();
    for (int off = 1; off < 256; off <<= 1) {
        int t2 = (tid >= off) ? tmp[tid - off] : 0;
        __syncthreads();
        tmp[tid] += t2;
        __syncthreads();
    }
    int base = (b > 0) ? bsum[b - 1] : 0;
    if (i < n) {
        rowptr[i + 1] = base + tmp[tid];
        curs[i] = base + tmp[tid] - v;
    }
    if (b == 0 && tid == 0) rowptr[0] = 0;
}
// also records csr_dst so scoring can be a single per-edge pass
__global__ void csr_fill(const int* __restrict__ src, const int* __restrict__ dst,
                         int* cursor, int* __restrict__ csr_src, int* __restrict__ csr_dst, int E) {
    int e = blockIdx.x * blockDim.x + threadIdx.x;
    if (e >= E) return;
    int d = dst[e];
    int slot = atomicAdd(&cursor[d], 1);
    csr_src[slot] = src[e];
    csr_dst[slot] = d;
}
__global__ void csr_fill_loops(int* cursor, int* __restrict__ csr_src, int* __restrict__ csr_dst, int n) {
    int i = blockIdx.x * blockDim.x + threadIdx.x;
    if (i >= n) return;
    int slot = atomicAdd(&cursor[i], 1);
    csr_src[slot] = i;
    csr_dst[slot] = i;
}

// ---------- layer-1 scores: ONE per-edge random-gather pass ----------
__global__ void edge_score3(const int* __restrict__ csr_src, const int* __restrict__ csr_dst,
                            const float* __restrict__ es, const float* __restrict__ ed,
                            float4* __restrict__ alpha, int E) {
    int s0 = blockIdx.x * blockDim.x + threadIdx.x;
    if (s0 >= E) return;
    int s = csr_src[s0], d = csr_dst[s0];
    float l0 = leaky(es[s * 3]     + ed[d * 3]);
    float l1 = leaky(es[s * 3 + 1] + ed[d * 3 + 1]);
    float l2 = leaky(es[s * 3 + 2] + ed[d * 3 + 2]);
    alpha[s0] = float4{l0, l1, l2, 0.f};
}
// per-dst softmax over CONTIGUOUS alpha range (no random gathers)
__global__ void seg_norm3(const int* __restrict__ rowptr, float4* __restrict__ alpha, int N) {
    int d = blockIdx.x * blockDim.x + threadIdx.x;
    if (d >= N) return;
    int b = rowptr[d], e = rowptr[d + 1];
    float m0 = -1e30f, m1 = -1e30f, m2 = -1e30f;
    for (int s0 = b; s0 < e; s0++) {
        float4 a = alpha[s0];
        m0 = fmaxf(m0, a.x); m1 = fmaxf(m1, a.y); m2 = fmaxf(m2, a.z);
    }
    float dn0 = 0.f, dn1 = 0.f, dn2 = 0.f;
    for (int s0 = b; s0 < e; s0++) {
        float4 a = alpha[s0];
        float x0 = expf(a.x - m0), x1 = expf(a.y - m1), x2 = expf(a.z - m2);
        dn0 += x0; dn1 += x1; dn2 += x2;
        alpha[s0] = float4{x0, x1, x2, 0.f};
    }
    float i0 = 1.f / (dn0 + 1e-16f), i1 = 1.f / (dn1 + 1e-16f), i2 = 1.f / (dn2 + 1e-16f);
    for (int s0 = b; s0 < e; s0++) {
        float4 a = alpha[s0];
        a.x *= i0; a.y *= i1; a.z *= i2;
        alpha[s0] = a;
    }
}

// ---------- layer-2 coefs (1 head; es2 tiny, L2-resident) ----------
__global__ void csr_maxden_alpha1(const int* __restrict__ rowptr, const int* __restrict__ csr_src,
                                  const float* __restrict__ es, const float* __restrict__ ed,
                                  float* __restrict__ alpha, int N) {
    int d = blockIdx.x * blockDim.x + threadIdx.x;
    if (d >= N) return;
    float edv = ed[d];
    int b = rowptr[d], e = rowptr[d + 1];
    float mm = -1e30f;
    for (int s0 = b; s0 < e; s0++) {
        int s = csr_src[s0];
        mm = fmaxf(mm, leaky(es[s] + edv));
    }
    float dn = 0.f;
    for (int s0 = b; s0 < e; s0++) {
        int s = csr_src[s0];
        float ex = expf(leaky(es[s] + edv) - mm);
        dn += ex;
        alpha[s0] = ex;
    }
    float inv = 1.f / (dn + 1e-16f);
    for (int s0 = b; s0 < e; s0++) alpha[s0] *= inv;
}

// ---------- layer-1 aggregate (bf16 h1) + bias + ELU + (row @ W2) + layer-2 coef ----------
// r6 version (VERBATIM revert): depth-4 group pipeline, 128 threads, 12 row-loads
// in flight/thread. r7 proved the pipeline IS the MLP (plain loop: 111->145 us,
// VALUBusy 62->32%, latency-bound). FROZEN — do not touch again.
__global__ __launch_bounds__(128) void csr_agg1_fused(
    const int* __restrict__ rowptr, const int* __restrict__ csr_src,
    const float4* __restrict__ alpha,
    const unsigned short* __restrict__ h1, const float* __restrict__ b1,
    const float* __restrict__ W2, float* __restrict__ h2,
    const float* __restrict__ as2, const float* __restrict__ ad2,
    float* __restrict__ es2, float* __restrict__ ed2, int N)
{
    int d = blockIdx.x;
    int t = threadIdx.x;
    __shared__ float row[HC1];
    __shared__ float part[128][OUTC + 1];

    int b = rowptr[d], e = rowptr[d + 1];
    float a0 = 0.f, a1 = 0.f, a2 = 0.f;

#define LOADG(g, I, A)                                                        \
    do {                                                                      \
        int base_ = b + (g) * 4;                                              \
        _Pragma("unroll")                                                     \
        for (int j = 0; j < 4; j++) {                                         \
            int s0_ = base_ + j;                                              \
            bool v_ = s0_ < e;                                                \
            int sc_ = v_ ? s0_ : (e - 1);                                     \
            I[j] = csr_src[sc_];                                              \
            float4 t4_ = alpha[sc_];                                          \
            if (!v_) { t4_.x = 0.f; t4_.y = 0.f; t4_.z = 0.f; }               \
            A[j] = t4_;                                                       \
        }                                                                     \
    } while (0)

    int ng = (e - b + 3) >> 2;
    int   iN[4]; float4 aN[4];
    LOADG(0, iN, aN);
    float rc[12]; float4 aC[4];
#pragma unroll
    for (int j = 0; j < 4; j++) {
        const unsigned short* hp = h1 + (long)iN[j] * HC1;
        rc[3 * j] = bf16f(hp[t]); rc[3 * j + 1] = bf16f(hp[t + 128]); rc[3 * j + 2] = bf16f(hp[t + 256]);
        aC[j] = aN[j];
    }
    LOADG(1, iN, aN);
    for (int g = 1; g < ng; g++) {
        float rn[12];
#pragma unroll
        for (int j = 0; j < 4; j++) {
            const unsigned short* hp = h1 + (long)iN[j] * HC1;
            rn[3 * j] = bf16f(hp[t]); rn[3 * j + 1] = bf16f(hp[t + 128]); rn[3 * j + 2] = bf16f(hp[t + 256]);
        }
        int iT[4]; float4 aT[4];
        LOADG(g + 1, iT, aT);
#pragma unroll
        for (int j = 0; j < 4; j++) {
            a0 = fmaf(rc[3 * j],     aC[j].x, a0);
            a1 = fmaf(rc[3 * j + 1], aC[j].y, a1);
            a2 = fmaf(rc[3 * j + 2], aC[j].z, a2);
        }
#pragma unroll
        for (int j = 0; j < 12; j++) rc[j] = rn[j];
#pragma unroll
        for (int j = 0; j < 4; j++) { aC[j] = aN[j]; iN[j] = iT[j]; aN[j] = aT[j]; }
    }
#pragma unroll
    for (int j = 0; j < 4; j++) {
        a0 = fmaf(rc[3 * j],     aC[j].x, a0);
        a1 = fmaf(rc[3 * j + 1], aC[j].y, a1);
        a2 = fmaf(rc[3 * j + 2], aC[j].z, a2);
    }
#undef LOADG

    float v;
    v = a0 + b1[t];       row[t]       = v > 0.f ? v : expf(v) - 1.f;
    v = a1 + b1[t + 128]; row[t + 128] = v > 0.f ? v : expf(v) - 1.f;
    v = a2 + b1[t + 256]; row[t + 256] = v > 0.f ? v : expf(v) - 1.f;
    __syncthreads();

    float pc[OUTC];
#pragma unroll
    for (int c = 0; c < OUTC; c++) pc[c] = 0.f;
    for (int k = t; k < HC1; k += 128) {
        float rv = row[k];
        const float* wp = W2 + (long)k * OUTC;
#pragma unroll
        for (int c = 0; c < OUTC; c++) pc[c] = fmaf(rv, wp[c], pc[c]);
    }
#pragma unroll
    for (int c = 0; c < OUTC; c++) part[t][c] = pc[c];
    __syncthreads();
    for (int off = 64; off > 0; off >>= 1) {
        if (t < off) {
#pragma unroll
            for (int c = 0; c < OUTC; c++) part[t][c] += part[t + off][c];
        }
        __syncthreads();
    }
    if (t < OUTC) h2[(long)d * OUTC + t] = part[0][t];
    if (t == 0) {
        float s = 0.f, dd = 0.f;
#pragma unroll
        for (int c = 0; c < OUTC; c++) {
            float hv = part[0][c];
            s  = fmaf(hv, as2[c], s);
            dd = fmaf(hv, ad2[c], dd);
        }
        es2[d] = s; ed2[d] = dd;
    }
}

// ---------- layer-2 aggregate + bias -> padded emb (stride 12) ----------
__global__ void csr_agg2(const int* __restrict__ rowptr, const int* __restrict__ csr_src,
                         const float* __restrict__ alpha,
                         const float* __restrict__ h2, const float* __restrict__ b2,
                         float* __restrict__ emb, int N)
{
    int idx = blockIdx.x * blockDim.x + threadIdx.x;
    if (idx >= N * EMBS) return;
    int d = idx / EMBS, c = idx - d * EMBS;
    if (c >= OUTC) { emb[idx] = 0.f; return; }
    int b = rowptr[d], e = rowptr[d + 1];
    float acc = 0.f;
    for (int s0 = b; s0 < e; s0++) {
        int s = csr_src[s0];
        acc = fmaf(h2[(long)s * OUTC + c], alpha[s0], acc);
    }
    emb[idx] = acc + b2[c];
}

// ---------- pair scores (padded emb: 3 float4 loads per row) ----------
__global__ void pair_score(const int* __restrict__ pairs, const float* __restrict__ emb,
                           float* __restrict__ out, int P) {
    int p = blockIdx.x * blockDim.x + threadIdx.x;
    if (p >= P) return;
    int i0 = pairs[2 * p], i1 = pairs[2 * p + 1];
    const float4* a = (const float4*)(emb + (long)i0 * EMBS);
    const float4* b = (const float4*)(emb + (long)i1 * EMBS);
    float4 a0 = a[0], a1 = a[1], a2 = a[2];
    float4 b0 = b[0], b1 = b[1], b2 = b[2];
    float s = a0.x*b0.x + a0.y*b0.y + a0.z*b0.z + a0.w*b0.w
            + a1.x*b1.x + a1.y*b1.y + a1.z*b1.z + a1.w*b1.w
            + a2.x*b2.x + a2.y*b2.y;
    out[p] = s;
}

extern "C" void kernel_launch(void* const* d_in, const int* in_sizes, int n_in,
                              void* d_out, int out_size, void* d_ws, size_t ws_size,
                              hipStream_t stream) {
    const float* fsub = (const float*)d_in[0];
    const float* fcom = (const float*)d_in[1];
    float*       x    = (float*)d_in[2];
    const int*   com  = (const int*)d_in[3];
    const int*   ei   = (const int*)d_in[4];
    const int*   pidx = (const int*)d_in[5];
    const float* Wq = (const float*)d_in[6];  const float* bq = (const float*)d_in[7];
    const float* Wk = (const float*)d_in[8];  const float* bk = (const float*)d_in[9];
    const float* Wv = (const float*)d_in[10]; const float* bv = (const float*)d_in[11];
    const float* Wf = (const float*)d_in[12]; const float* bf = (const float*)d_in[13];
    const float* W1 = (const float*)d_in[14];
    const float* as1 = (const float*)d_in[15]; const float* ad1 = (const float*)d_in[16];
    const float* b1 = (const float*)d_in[17];
    const float* W2 = (const float*)d_in[18];
    const float* as2 = (const float*)d_in[19]; const float* ad2 = (const float*)d_in[20];
    const float* b2 = (const float*)d_in[21];
    float* out = (float*)d_out;

    const int* src = ei;
    const int* dst = ei + NE;

    typedef unsigned short u16;
    char* ws = (char*)d_ws;
    float* S     = (float*)(ws + 0);            // dead after softmax
    u16*   SH    = (u16*)(ws + 67108864);       // dead after S@v
    u16*   SL    = (u16*)(ws + 100663296);
    u16*   fsubH = (u16*)(ws + 134217728);      // dead after q proj
    u16*   fsubL = (u16*)(ws + 136839168);
    u16*   fcomH = (u16*)(ws + 139460608);      // dead after k,v proj
    u16*   fcomL = (u16*)(ws + 142082048);
    u16*   qH    = (u16*)(ws + 144703488);      // dead after S gemm
    u16*   qL    = (u16*)(ws + 147324928);
    u16*   kH    = (u16*)(ws + 149946368);
    u16*   kL    = (u16*)(ws + 152567808);
    u16*   vTH   = (u16*)(ws + 155189248);      // dead after S@v
    u16*   vTL   = (u16*)(ws + 157646848);
    u16*   attnH = (u16*)(ws + 160104448);      // dead after fus gemm
    u16*   attnL = (u16*)(ws + 162725888);
    u16*   WqTH  = (u16*)(ws + 165347328);
    u16*   WqTL  = (u16*)(ws + 165539328);
    u16*   WkTH  = (u16*)(ws + 165731328);
    u16*   WkTL  = (u16*)(ws + 165923328);
    u16*   WvTH  = (u16*)(ws + 166115328);
    u16*   WvTL  = (u16*)(ws + 166307328);
    u16*   WfTH  = (u16*)(ws + 166499328);
    u16*   WfTL  = (u16*)(ws + 166691328);
    u16*   W1TH  = (u16*)(ws + 166883328);
    u16*   W1TL  = (u16*)(ws + 167129088);
    float* fus   = (float*)(ws + 167374848);    // alive until scatter
    float* es1   = (float*)(ws + 172290048);
    float* ed1   = (float*)(ws + 172890048);
    float* es2   = (float*)(ws + 174690048);
    float* ed2   = (float*)(ws + 174890048);
    float* h2    = (float*)(ws + 175490048);
    int*   last  = (int*)(ws + 179490048);
    int*   deg   = (int*)(ws + 179690048);
    int*   curs  = (int*)(ws + 179890048);
    int*   rowp  = (int*)(ws + 180090048);
    int*   csrc  = (int*)(ws + 180290064);      // ends 182,490,064
    int*   bsum  = (int*)(ws + 182490112);      // 196 ints
    // overlays (disjoint in time):
    float* part   = (float*)(ws + 0);           // over dead S (S@v phase), 4 slices
    u16*   h1b    = (u16*)(ws + 0);             // bf16 h1 over dead S/SH (GAT phase), 38.4MB
    u16*   xH     = (u16*)(ws + 76800000);      // over dead SH/SL; dead after h1 gemm
    u16*   xL     = (u16*)(ws + 108800000);
    float* alpha1 = (float*)(ws + 134217728);   // over dead fsubH.. (GAT phase), 8.8MB
    float* alpha2 = (float*)(ws + 144703488);   // over dead qH (GAT phase), 2.2MB -> ends 146,903,488
    int*   csrd   = (int*)(ws + 160104448);     // over dead attnH (CSR phase on), 2.2MB
    float* embp   = (float*)(ws + 147324928);   // over dead qL/kH, 2.4MB -> ends 149,724,928

    const float inv_sqrt_d = 1.0f / sqrtf((float)FEAT);

    // ===== 0. conversions =====
    hipLaunchKernelGGL(convT_pad, dim3(cdiv(FEAT*KP,256)), dim3(256), 0, stream, Wq, WqTH, WqTL, FEAT, FEAT, KP);
    hipLaunchKernelGGL(convT_pad, dim3(cdiv(FEAT*KP,256)), dim3(256), 0, stream, Wk, WkTH, WkTL, FEAT, FEAT, KP);
    hipLaunchKernelGGL(convT_pad, dim3(cdiv(FEAT*KP,256)), dim3(256), 0, stream, Wv, WvTH, WvTL, FEAT, FEAT, KP);
    hipLaunchKernelGGL(convT_pad, dim3(cdiv(FEAT*KP,256)), dim3(256), 0, stream, Wf, WfTH, WfTL, FEAT, FEAT, KP);
    hipLaunchKernelGGL(convT_pad, dim3(cdiv(HC1*KP,256)),  dim3(256), 0, stream, W1, W1TH, W1TL, FEAT, HC1, KP);
    hipLaunchKernelGGL(conv_pad8, dim3(cdiv(BP*(KP/8),256)), dim3(256), 0, stream, fsub, fsubH, fsubL, BP, FEAT, KP);
    hipLaunchKernelGGL(conv_pad8, dim3(cdiv(BP*(KP/8),256)), dim3(256), 0, stream, fcom, fcomH, fcomL, BP, FEAT, KP);
    hipLaunchKernelGGL(fill_f32, dim3(cdiv(10485760/4,256)), dim3(256), 0, stream, (float*)qH, 0.f, (long)(10485760/4));

    // ===== 1. cross attention (all GEMMs on the 128x128 gl-staged structure) =====
    hipLaunchKernelGGL((gemm_gl128<false, 2>), dim3(cdiv(FEAT,128), cdiv(BP,128)), dim3(256), 0, stream,
                       fsubH, (long)(fsubL - fsubH), KP, WqTH, (long)(WqTL - WqTH), KP,
                       bq, nullptr, qH, qL, BP, FEAT, FEAT, 1.0f, KP, 0);
    hipLaunchKernelGGL((gemm_gl128<false, 2>), dim3(cdiv(FEAT,128), cdiv(BP,128)), dim3(256), 0, stream,
                       fcomH, (long)(fcomL - fcomH), KP, WkTH, (long)(WkTL - WkTH), KP,
                       bk, nullptr, kH, kL, BP, FEAT, FEAT, 1.0f, KP, 0);
    hipLaunchKernelGGL((gemm_gl128<false, 3>), dim3(cdiv(FEAT,128), cdiv(BP,128)), dim3(256), 0, stream,
                       fcomH, (long)(fcomL - fcomH), KP, WvTH, (long)(WvTL - WvTH), KP,
                       bv, nullptr, vTH, vTL, BP, FEAT, FEAT, 1.0f, BP, 0);
    hipLaunchKernelGGL((gemm_gl128<false, 0>), dim3(cdiv(BP,128), cdiv(BP,128)), dim3(256), 0, stream,
                       qH, (long)(qL - qH), KP, kH, (long)(kL - kH), KP,
                       nullptr, S, nullptr, nullptr, BP, BP, FEAT, inv_sqrt_d, 0, 0);
    hipLaunchKernelGGL(softmax_hl, dim3(BP), dim3(256), 0, stream, S, SH, SL);
    hipLaunchKernelGGL((gemm_gl128<true, 0>), dim3(cdiv(FEAT,128), cdiv(BP,128), 4), dim3(256), 0, stream,
                       SH, (long)(SL - SH), BP, vTH, (long)(vTL - vTH), BP,
                       nullptr, part, nullptr, nullptr, BP, FEAT, BP, 1.0f, 0, 1024);
    hipLaunchKernelGGL(splitk_reduce8, dim3(cdiv(BP*(KP/8),256)), dim3(256), 0, stream,
                       part, fsub, attnH, attnL, BP, FEAT, KP, 4);
    hipLaunchKernelGGL((gemm_gl128<false, 0>), dim3(cdiv(FEAT,128), cdiv(BP,128)), dim3(256), 0, stream,
                       attnH, (long)(attnL - attnH), KP, WfTH, (long)(WfTL - WfTH), KP,
                       bf, fus, nullptr, nullptr, BP, FEAT, FEAT, 1.0f, 0, 0);

    // ===== 2. convert pristine x, then scatter fused rows directly as bf16 =====
    hipLaunchKernelGGL(conv_pad8, dim3(cdiv((long)NN*(KP/8),256)), dim3(256), 0, stream, x, xH, xL, NN, FEAT, KP);
    hipLaunchKernelGGL(scatter_init, dim3(cdiv(BP,256)), dim3(256), 0, stream, last, com, BP);
    hipLaunchKernelGGL(scatter_max,  dim3(cdiv(BP,256)), dim3(256), 0, stream, last, com, BP);
    hipLaunchKernelGGL(scatter_write_hl, dim3(BP), dim3(128), 0, stream, last, com, fus, xH, xL, BP);

    // ===== 3. CSR build =====
    hipLaunchKernelGGL(deg_init,  dim3(cdiv(NN,256)), dim3(256), 0, stream, deg, NN);
    hipLaunchKernelGGL(deg_count, dim3(cdiv(NE,256)), dim3(256), 0, stream, dst, deg, NE);
    {
        int nb = cdiv(NN, 256);   // 196
        hipLaunchKernelGGL(scan_part,  dim3(nb), dim3(256), 0, stream, deg, bsum, NN);
        hipLaunchKernelGGL(scan_bsum,  dim3(1),  dim3(256), 0, stream, bsum, nb);
        hipLaunchKernelGGL(scan_final, dim3(nb), dim3(256), 0, stream, deg, bsum, rowp, curs, NN);
    }
    hipLaunchKernelGGL(csr_fill, dim3(cdiv(NE,256)), dim3(256), 0, stream, src, dst, curs, csrc, csrd, NE);
    hipLaunchKernelGGL(csr_fill_loops, dim3(cdiv(NN,256)), dim3(256), 0, stream, curs, csrc, csrd, NN);

    // ===== 4. GAT layer 1 (h1 in bf16: gather working set 38.4 MB) =====
    hipLaunchKernelGGL((gemm_gl128<false, 1>), dim3(cdiv(HC1,128), cdiv(NN,128)), dim3(256), 0, stream,
                       xH, (long)(xL - xH), KP, W1TH, (long)(W1TL - W1TH), KP,
                       nullptr, nullptr, h1b, nullptr, NN, HC1, FEAT, 1.0f, 0, 0);
    hipLaunchKernelGGL(node_attn_coef3, dim3(cdiv(NN,4)), dim3(256), 0, stream,
                       h1b, as1, ad1, es1, ed1, NN);
    hipLaunchKernelGGL(edge_score3, dim3(cdiv(TOTE,256)), dim3(256), 0, stream,
                       csrc, csrd, es1, ed1, (float4*)alpha1, TOTE);
    hipLaunchKernelGGL(seg_norm3, dim3(cdiv(NN,256)), dim3(256), 0, stream,
                       rowp, (float4*)alpha1, NN);
    hipLaunchKernelGGL(csr_agg1_fused, dim3(NN), dim3(128), 0, stream,
                       rowp, csrc, (const float4*)alpha1, h1b, b1, W2, h2, as2, ad2, es2, ed2, NN);

    // ===== 5. GAT layer 2 =====
    hipLaunchKernelGGL(csr_maxden_alpha1, dim3(cdiv(NN,256)), dim3(256), 0, stream,
                       rowp, csrc, es2, ed2, alpha2, NN);
    hipLaunchKernelGGL(csr_agg2, dim3(cdiv(NN*EMBS,256)), dim3(256), 0, stream,
                       rowp, csrc, alpha2, h2, b2, embp, NN);

    // ===== 6. pair scores =====
    hipLaunchKernelGGL(pair_score, dim3(cdiv(NP,256)), dim3(256), 0, stream, pidx, embp, out, NP);
}

// Round 9
// 704.050 us; speedup vs baseline: 1.0871x; 1.0744x over previous
//
#include <hip/hip_runtime.h>
#include <math.h>

#define NN      50000      // N_NODES
#define BP      4096       // N_PAIRS_MAP
#define NE      500000     // N_EDGES
#define NP      1000000    // N_SCORE_PAIRS
#define FEAT    300
#define KP      320        // FEAT padded to multiple of 32
#define HID     128
#define HEADS   3
#define OUTC    10
#define HC1     (HEADS*HID)   // 384
#define EMBS    12            // embp row stride (floats, 48B = 16B-aligned)
#define TOTE    (NE+NN)       // CSR slots incl. self-loops
#define NEG_SLOPE 0.2f

static inline int cdiv(int a, int b) { return (a + b - 1) / b; }

using bfrag = __attribute__((ext_vector_type(8))) short;
using ffrag = __attribute__((ext_vector_type(4))) float;

__device__ inline float leaky(float x) { return x > 0.f ? x : NEG_SLOPE * x; }
__device__ inline unsigned short bf16_rne(float f) {
    unsigned u = __float_as_uint(f);
    unsigned r = u + 0x7FFFu + ((u >> 16) & 1u);
    return (unsigned short)(r >> 16);
}
__device__ inline float bf16f(unsigned short h) { return __uint_as_float(((unsigned)h) << 16); }
// packed-uint bf16 pair -> floats (1 VALU op each)
__device__ inline float bf16lo(unsigned u) { return __uint_as_float(u << 16); }
__device__ inline float bf16hi(unsigned u) { return __uint_as_float(u & 0xffff0000u); }

__device__ __forceinline__ void gload_lds16(const unsigned short* g, unsigned short* l) {
    __builtin_amdgcn_global_load_lds((const __attribute__((address_space(1))) void*)g,
                                     (__attribute__((address_space(3))) void*)l, 16, 0, 0);
}

// fp32 [M][K] -> bf16 hi/lo [M][Kp]; 8 elems/thread, uint4 stores (G13)
__global__ void conv_pad8(const float* __restrict__ in, unsigned short* __restrict__ H,
                          unsigned short* __restrict__ L, long M, int K, int Kp) {
    long idx = (long)blockIdx.x * blockDim.x + threadIdx.x;
    int cpk = Kp >> 3;
    long total = M * cpk;
    if (idx >= total) return;
    int chunk = (int)(idx % cpk);
    long row = idx / cpk;
    int k0 = chunk * 8;
    const float* ip = in + row * K;
    float v[8];
    if (k0 + 8 <= K) {
        float4 a = *(const float4*)(ip + k0);
        float4 b = *(const float4*)(ip + k0 + 4);
        v[0]=a.x; v[1]=a.y; v[2]=a.z; v[3]=a.w; v[4]=b.x; v[5]=b.y; v[6]=b.z; v[7]=b.w;
    } else {
#pragma unroll
        for (int j = 0; j < 8; j++) { int k = k0 + j; v[j] = (k < K) ? ip[k] : 0.f; }
    }
    unsigned short hs[8], ls[8];
#pragma unroll
    for (int j = 0; j < 8; j++) {
        unsigned short h = bf16_rne(v[j]);
        hs[j] = h; ls[j] = bf16_rne(v[j] - bf16f(h));
    }
    long o = row * Kp + k0;
    *(uint4*)&H[o] = *(const uint4*)hs;
    *(uint4*)&L[o] = *(const uint4*)ls;
}

// fsub + fcom in one launch (same shape [BP][FEAT] -> [BP][KP] hi/lo)
__global__ void conv_pad8_2(const float* __restrict__ inA, const float* __restrict__ inB,
                            unsigned short* __restrict__ HA, unsigned short* __restrict__ LA,
                            unsigned short* __restrict__ HB, unsigned short* __restrict__ LB) {
    long idx = (long)blockIdx.x * blockDim.x + threadIdx.x;
    int cpk = KP >> 3;
    long total = 2L * BP * cpk;
    if (idx >= total) return;
    int chunk = (int)(idx % cpk);
    long row = idx / cpk;
    const float* in; unsigned short *H, *L;
    if (row < BP) { in = inA; H = HA; L = LA; }
    else          { in = inB; H = HB; L = LB; row -= BP; }
    int k0 = chunk * 8;
    const float* ip = in + row * FEAT;
    float v[8];
    if (k0 + 8 <= FEAT) {
        float4 a = *(const float4*)(ip + k0);
        float4 b = *(const float4*)(ip + k0 + 4);
        v[0]=a.x; v[1]=a.y; v[2]=a.z; v[3]=a.w; v[4]=b.x; v[5]=b.y; v[6]=b.z; v[7]=b.w;
    } else {
#pragma unroll
        for (int j = 0; j < 8; j++) { int k = k0 + j; v[j] = (k < FEAT) ? ip[k] : 0.f; }
    }
    unsigned short hs[8], ls[8];
#pragma unroll
    for (int j = 0; j < 8; j++) {
        unsigned short h = bf16_rne(v[j]);
        hs[j] = h; ls[j] = bf16_rne(v[j] - bf16f(h));
    }
    long o = row * KP + k0;
    *(uint4*)&H[o] = *(const uint4*)hs;
    *(uint4*)&L[o] = *(const uint4*)ls;
}

// all 5 weight transposes in ONE launch. W0..W3: [300][300]; W4: [300][384].
__global__ void convT_pad5(
    const float* __restrict__ s0, const float* __restrict__ s1, const float* __restrict__ s2,
    const float* __restrict__ s3, const float* __restrict__ s4,
    unsigned short* __restrict__ h0, unsigned short* __restrict__ l0,
    unsigned short* __restrict__ h1, unsigned short* __restrict__ l1,
    unsigned short* __restrict__ h2, unsigned short* __restrict__ l2,
    unsigned short* __restrict__ h3, unsigned short* __restrict__ l3,
    unsigned short* __restrict__ h4, unsigned short* __restrict__ l4)
{
    long idx = (long)blockIdx.x * blockDim.x + threadIdx.x;
    const long R = (long)FEAT * KP;          // 96000 per square weight
    const float* src; unsigned short *H, *L; int N; long off;
    if (idx < 4 * R) {
        int m = (int)(idx / R); off = idx - (long)m * R; N = FEAT;
        src = (m == 0) ? s0 : (m == 1) ? s1 : (m == 2) ? s2 : s3;
        H   = (m == 0) ? h0 : (m == 1) ? h1 : (m == 2) ? h2 : h3;
        L   = (m == 0) ? l0 : (m == 1) ? l1 : (m == 2) ? l2 : l3;
    } else if (idx < 4 * R + (long)HC1 * KP) {
        off = idx - 4 * R; N = HC1; src = s4; H = h4; L = l4;
    } else return;
    int k = (int)(off % KP);
    long n = off / KP;
    float f = (k < FEAT) ? src[(long)k * N + n] : 0.f;
    unsigned short h = bf16_rne(f);
    H[off] = h;
    L[off] = bf16_rne(f - bf16f(h));
}

// ================== split-bf16 MFMA GEMM (64x64 tile, LDS-staged) ==================
// For the SMALL GEMMs (q,k,v,fus: M=4096,N=300): 320 blocks vs gl128's 96 —
// r8 measured the gl128 form 34us SLOWER here (under-occupancy). Keep 64-tile.
template <int MODE>
__global__ __launch_bounds__(256) void gemm_bf(
    const unsigned short* __restrict__ Ah, const unsigned short* __restrict__ Al, int lda,
    const unsigned short* __restrict__ Bh, const unsigned short* __restrict__ Bl, int ldb,
    const float* __restrict__ bias, const float* __restrict__ addsrc,
    float* __restrict__ C0, unsigned short* __restrict__ H0, unsigned short* __restrict__ L0,
    int M, int N, int K, float scale, int ldo)
{
    __shared__ __align__(16) unsigned short Ahs[4][64][8], Als[4][64][8];
    __shared__ __align__(16) unsigned short Bhs[4][64][8], Bls[4][64][8];
    int t = threadIdx.x, w = t >> 6, l = t & 63, lrow = l & 15, lq = l >> 4;
    int rowBase = blockIdx.y * 64, colBase = blockIdx.x * 64;
    int Kr = (K + 31) & ~31;

    int arow = min(rowBase + l, M - 1);
    int brow = min(colBase + l, N - 1);
    const unsigned short* ga_h = Ah + (long)arow * lda + w * 8;
    const unsigned short* ga_l = Al + (long)arow * lda + w * 8;
    const unsigned short* gb_h = Bh + (long)brow * ldb + w * 8;
    const unsigned short* gb_l = Bl + (long)brow * ldb + w * 8;

    ffrag acc[4] = {{0.f,0.f,0.f,0.f},{0.f,0.f,0.f,0.f},{0.f,0.f,0.f,0.f},{0.f,0.f,0.f,0.f}};

    for (int k0 = 0; k0 < Kr; k0 += 32) {
        *(uint4*)&Ahs[w][l][0] = *(const uint4*)(ga_h + k0);
        *(uint4*)&Als[w][l][0] = *(const uint4*)(ga_l + k0);
        *(uint4*)&Bhs[w][l][0] = *(const uint4*)(gb_h + k0);
        *(uint4*)&Bls[w][l][0] = *(const uint4*)(gb_l + k0);
        __syncthreads();
        bfrag ah  = *(const bfrag*)&Ahs[lq][w * 16 + lrow][0];
        bfrag alo = *(const bfrag*)&Als[lq][w * 16 + lrow][0];
#pragma unroll
        for (int ct = 0; ct < 4; ct++) {
            bfrag bh = *(const bfrag*)&Bhs[lq][ct * 16 + lrow][0];
            bfrag bl = *(const bfrag*)&Bls[lq][ct * 16 + lrow][0];
            acc[ct] = __builtin_amdgcn_mfma_f32_16x16x32_bf16(ah,  bh, acc[ct], 0, 0, 0);
            acc[ct] = __builtin_amdgcn_mfma_f32_16x16x32_bf16(ah,  bl, acc[ct], 0, 0, 0);
            acc[ct] = __builtin_amdgcn_mfma_f32_16x16x32_bf16(alo, bh, acc[ct], 0, 0, 0);
        }
        __syncthreads();
    }

#pragma unroll
    for (int ct = 0; ct < 4; ct++) {
        int gc = colBase + ct * 16 + lrow;
        if (gc >= N) continue;
#pragma unroll
        for (int r = 0; r < 4; r++) {
            int gr = rowBase + w * 16 + lq * 4 + r;
            if (gr >= M) continue;
            float v = acc[ct][r];
            if (MODE == 0) {
                float o = v * scale;
                if (bias) o += bias[gc];
                if (addsrc) o += addsrc[(long)gr * ldo + gc];
                C0[(long)gr * ldo + gc] = o;
            } else if (MODE == 1) {
                float o = v + bias[gc];
                unsigned short h = bf16_rne(o);
                H0[(long)gr * ldo + gc] = h;
                L0[(long)gr * ldo + gc] = bf16_rne(o - bf16f(h));
            } else {
                float o = v + bias[gc];
                unsigned short h = bf16_rne(o);
                H0[(long)gc * ldo + gr] = h;
                L0[(long)gc * ldo + gr] = bf16_rne(o - bf16f(h));
            }
        }
    }
}

// ================== split-bf16 GEMM, 128x128 tile, global_load_lds staging ==================
// For the LARGE GEMMs only (S: 1024 blocks, S@v: 384, h1: 1173).
// OUT: 0 = f32 out (acc*scale), 1 = bf16 (RNE) out.
template <bool SPLITK, int OUT>
__global__ __launch_bounds__(256) void gemm_gl128(
    const unsigned short* __restrict__ Ah, long dAl, int lda,
    const unsigned short* __restrict__ Bh, long dBl, int ldb,
    float* __restrict__ C0, unsigned short* __restrict__ Hb,
    int M, int N, int K, float scale, int KC)
{
    __shared__ __align__(16) unsigned short As[128][64];
    __shared__ __align__(16) unsigned short Bs[128][64];
    int t = threadIdx.x, w = t >> 6, l = t & 63, lrow = l & 15, lq = l >> 4;
    int wr = w >> 1, wc = w & 1;
    int rowBase = blockIdx.y * 128, colBase = blockIdx.x * 128;
    int Kr = (K + 31) & ~31;
    int kbeg = SPLITK ? blockIdx.z * KC : 0;
    int kend = SPLITK ? min(Kr, kbeg + KC) : Kr;

    bool isA = (w < 2);
    const unsigned short* Mb = isA ? Ah : Bh;
    long dHL = isA ? dAl : dBl;
    int ld   = isA ? lda : ldb;
    int mx   = (isA ? M : N) - 1;
    int rb0  = (isA ? rowBase : colBase) + (w & 1) * 64;
    int lr8  = l >> 3;
    int lg   = (l & 7) ^ lr8;
    long lane_off = (long)((lg & 3) * 8) + ((lg >> 2) ? dHL : 0);
    const unsigned short* gp[8];
#pragma unroll
    for (int i = 0; i < 8; i++) {
        int r = rb0 + i * 8 + lr8;
        gp[i] = Mb + (long)min(r, mx) * ld + lane_off;
    }
    unsigned short* ldst[8];
    {
        unsigned short (*T)[64] = isA ? As : Bs;
#pragma unroll
        for (int i = 0; i < 8; i++) ldst[i] = &T[(w & 1) * 64 + i * 8][0];
    }

    ffrag acc[4][4];
#pragma unroll
    for (int m = 0; m < 4; m++)
#pragma unroll
        for (int n = 0; n < 4; n++) acc[m][n] = ffrag{0.f, 0.f, 0.f, 0.f};

    int arow0 = wr * 64 + lrow, brow0 = wc * 64 + lrow;
    int xr = lrow & 7;
    int sh = ((lq    ) ^ xr) * 8;
    int sl = ((lq + 4) ^ xr) * 8;

    for (int k0 = kbeg; k0 < kend; k0 += 32) {
#pragma unroll
        for (int i = 0; i < 8; i++) gload_lds16(gp[i] + k0, ldst[i]);
        __syncthreads();

        bfrag bh[4], bl[4];
#pragma unroll
        for (int n = 0; n < 4; n++) {
            bh[n] = *(const bfrag*)&Bs[brow0 + n * 16][sh];
            bl[n] = *(const bfrag*)&Bs[brow0 + n * 16][sl];
        }
#pragma unroll
        for (int m = 0; m < 4; m++) {
            bfrag ah = *(const bfrag*)&As[arow0 + m * 16][sh];
            bfrag al = *(const bfrag*)&As[arow0 + m * 16][sl];
#pragma unroll
            for (int n = 0; n < 4; n++) {
                acc[m][n] = __builtin_amdgcn_mfma_f32_16x16x32_bf16(ah, bh[n], acc[m][n], 0, 0, 0);
                acc[m][n] = __builtin_amdgcn_mfma_f32_16x16x32_bf16(ah, bl[n], acc[m][n], 0, 0, 0);
                acc[m][n] = __builtin_amdgcn_mfma_f32_16x16x32_bf16(al, bh[n], acc[m][n], 0, 0, 0);
            }
        }
        __syncthreads();
    }

#pragma unroll
    for (int n = 0; n < 4; n++) {
        int gc = colBase + wc * 64 + n * 16 + lrow;
        if (gc >= N) continue;
#pragma unroll
        for (int m = 0; m < 4; m++) {
#pragma unroll
            for (int r = 0; r < 4; r++) {
                int gr = rowBase + wr * 64 + m * 16 + lq * 4 + r;
                if (gr >= M) continue;
                if (OUT == 0) {
                    float* Cz = SPLITK ? (C0 + (long)blockIdx.z * M * N) : C0;
                    Cz[(long)gr * N + gc] = acc[m][n][r] * scale;
                } else {
                    Hb[(long)gr * N + gc] = bf16_rne(acc[m][n][r]);
                }
            }
        }
    }
}

// ---------- softmax rows of S -> bf16 hi/lo; 16 contiguous cols/thread ----------
__global__ __launch_bounds__(256) void softmax_hl(const float* __restrict__ S,
                                                  unsigned short* __restrict__ SH,
                                                  unsigned short* __restrict__ SL) {
    int row = blockIdx.x, tid = threadIdx.x;
    const float* p = S + (long)row * BP + tid * 16;
    float ev[16];
    __shared__ float red[256];
    float m = -1e30f;
#pragma unroll
    for (int i = 0; i < 4; i++) {
        float4 a = *(const float4*)(p + i * 4);
        ev[4*i] = a.x; ev[4*i+1] = a.y; ev[4*i+2] = a.z; ev[4*i+3] = a.w;
        m = fmaxf(m, fmaxf(fmaxf(a.x, a.y), fmaxf(a.z, a.w)));
    }
    red[tid] = m; __syncthreads();
    for (int s = 128; s > 0; s >>= 1) { if (tid < s) red[tid] = fmaxf(red[tid], red[tid + s]); __syncthreads(); }
    m = red[0]; __syncthreads();
    float sum = 0.f;
#pragma unroll
    for (int i = 0; i < 16; i++) { float e = expf(ev[i] - m); ev[i] = e; sum += e; }
    red[tid] = sum; __syncthreads();
    for (int s = 128; s > 0; s >>= 1) { if (tid < s) red[tid] += red[tid + s]; __syncthreads(); }
    float inv = 1.0f / red[0];
    unsigned short hs[16], ls[16];
#pragma unroll
    for (int i = 0; i < 16; i++) {
        float e = ev[i] * inv;
        unsigned short h = bf16_rne(e);
        hs[i] = h; ls[i] = bf16_rne(e - bf16f(h));
    }
    long o = (long)row * BP + tid * 16;
    *(uint4*)&SH[o]     = *(const uint4*)&hs[0];
    *(uint4*)&SH[o + 8] = *(const uint4*)&hs[8];
    *(uint4*)&SL[o]     = *(const uint4*)&ls[0];
    *(uint4*)&SL[o + 8] = *(const uint4*)&ls[8];
}

// ---------- split-K reduce + residual -> attn bf16 hi/lo; 8 elems/thread ----------
__global__ void splitk_reduce8(const float* __restrict__ part, const float* __restrict__ resid,
                               unsigned short* __restrict__ H, unsigned short* __restrict__ L,
                               int Mr, int Nc, int Kp2, int sk) {
    long idx = (long)blockIdx.x * blockDim.x + threadIdx.x;
    int cpk = Kp2 >> 3;
    long total = (long)Mr * cpk;
    if (idx >= total) return;
    int chunk = (int)(idx % cpk);
    long row = idx / cpk;
    int c0 = chunk * 8;
    float v[8] = {0.f,0.f,0.f,0.f,0.f,0.f,0.f,0.f};
    if (c0 + 8 <= Nc) {
        long base = row * Nc + c0;
#pragma unroll
        for (int z = 0; z < 8; z++) {
            if (z >= sk) break;
            float4 a = *(const float4*)(part + (long)z * Mr * Nc + base);
            float4 b = *(const float4*)(part + (long)z * Mr * Nc + base + 4);
            v[0]+=a.x; v[1]+=a.y; v[2]+=a.z; v[3]+=a.w; v[4]+=b.x; v[5]+=b.y; v[6]+=b.z; v[7]+=b.w;
        }
        float4 a = *(const float4*)(resid + base);
        float4 b = *(const float4*)(resid + base + 4);
        v[0]+=a.x; v[1]+=a.y; v[2]+=a.z; v[3]+=a.w; v[4]+=b.x; v[5]+=b.y; v[6]+=b.z; v[7]+=b.w;
    } else if (c0 < Nc) {
#pragma unroll
        for (int j = 0; j < 8; j++) {
            int c = c0 + j;
            if (c < Nc) {
                long base = row * Nc + c;
                float s = resid[base];
                for (int z = 0; z < sk; z++) s += part[(long)z * Mr * Nc + base];
                v[j] = s;
            }
        }
    }
    unsigned short hs[8], ls[8];
#pragma unroll
    for (int j = 0; j < 8; j++) {
        unsigned short h = bf16_rne(v[j]);
        hs[j] = h; ls[j] = bf16_rne(v[j] - bf16f(h));
    }
    long o = row * Kp2 + c0;
    *(uint4*)&H[o] = *(const uint4*)hs;
    *(uint4*)&L[o] = *(const uint4*)ls;
}

// ---------- scatter (last write wins), writing bf16 hi/lo x directly ----------
__global__ void scatter_init(int* last, const int* __restrict__ com, int B) {
    int i = blockIdx.x * blockDim.x + threadIdx.x;
    if (i < B) last[com[i]] = -1;
}
__global__ void scatter_max(int* last, const int* __restrict__ com, int B) {
    int i = blockIdx.x * blockDim.x + threadIdx.x;
    if (i < B) atomicMax(&last[com[i]], i);
}
__global__ void scatter_write_hl(const int* __restrict__ last, const int* __restrict__ com,
                                 const float* __restrict__ fused,
                                 unsigned short* __restrict__ xH, unsigned short* __restrict__ xL, int B) {
    int i = blockIdx.x;
    int node = com[i];
    if (last[node] != i) return;
    for (int c = threadIdx.x; c < KP; c += blockDim.x) {
        float f = (c < FEAT) ? fused[(long)i * FEAT + c] : 0.f;
        unsigned short h = bf16_rne(f);
        xH[(long)node * KP + c] = h;
        xL[(long)node * KP + c] = bf16_rne(f - bf16f(h));
    }
}

// ---------- layer-1 coefficients from bf16 h1, wave-per-node, uint-packed ----------
__global__ __launch_bounds__(256) void node_attn_coef3(
    const unsigned short* __restrict__ h1, const float* __restrict__ a_src,
    const float* __restrict__ a_dst, float* __restrict__ es, float* __restrict__ ed, int N)
{
    int w = threadIdx.x >> 6, lane = threadIdx.x & 63;
    int n = blockIdx.x * 4 + w;
    if (n >= N) return;
    const unsigned short* hp = h1 + (long)n * HC1;
    int c = 2 * lane;  // cols c, c+1 within each 128-col head block
    unsigned u0 = *(const unsigned*)&hp[c];
    unsigned u1 = *(const unsigned*)&hp[128 + c];
    unsigned u2 = *(const unsigned*)&hp[256 + c];
    float s0, s1, s2, d0, d1, d2;
    {
        float vl = bf16lo(u0), vh = bf16hi(u0);
        s0 = fmaf(vl, a_src[c], vh * a_src[c + 1]);
        d0 = fmaf(vl, a_dst[c], vh * a_dst[c + 1]);
        vl = bf16lo(u1); vh = bf16hi(u1);
        s1 = fmaf(vl, a_src[128 + c], vh * a_src[128 + c + 1]);
        d1 = fmaf(vl, a_dst[128 + c], vh * a_dst[128 + c + 1]);
        vl = bf16lo(u2); vh = bf16hi(u2);
        s2 = fmaf(vl, a_src[256 + c], vh * a_src[256 + c + 1]);
        d2 = fmaf(vl, a_dst[256 + c], vh * a_dst[256 + c + 1]);
    }
#pragma unroll
    for (int off = 32; off > 0; off >>= 1) {
        s0 += __shfl_down(s0, off); s1 += __shfl_down(s1, off); s2 += __shfl_down(s2, off);
        d0 += __shfl_down(d0, off); d1 += __shfl_down(d1, off); d2 += __shfl_down(d2, off);
    }
    if (lane == 0) {
        es[n * 3 + 0] = s0; es[n * 3 + 1] = s1; es[n * 3 + 2] = s2;
        ed[n * 3 + 0] = d0; ed[n * 3 + 1] = d1; ed[n * 3 + 2] = d2;
    }
}

// ================== CSR build ==================
// deg zeroed by hipMemsetAsync; scan reads deg[i]+1 (self-loop folded in).
__global__ void deg_count(const int* __restrict__ dst, int* deg, int E) {
    int e = blockIdx.x * blockDim.x + threadIdx.x;
    if (e < E) atomicAdd(&deg[dst[e]], 1);
}
__global__ void scan_part(const int* __restrict__ deg, int* __restrict__ bsum, int n) {
    __shared__ int red[256];
    int tid = threadIdx.x;
    int i = blockIdx.x * 256 + tid;
    red[tid] = (i < n) ? deg[i] + 1 : 0;
    __syncthreads();
    for (int s = 128; s > 0; s >>= 1) { if (tid < s) red[tid] += red[tid + s]; __syncthreads(); }
    if (tid == 0) bsum[blockIdx.x] = red[0];
}
__global__ __launch_bounds__(256) void scan_bsum(int* __restrict__ bsum, int nb) {
    __shared__ int tmp[256];
    int tid = threadIdx.x;
    int v = (tid < nb) ? bsum[tid] : 0;
    tmp[tid] = v; __syncthreads();
    for (int off = 1; off < 256; off <<= 1) {
        int t2 = (tid >= off) ? tmp[tid - off] : 0;
        __syncthreads();
        tmp[tid] += t2;
        __syncthreads();
    }
    if (tid < nb) bsum[tid] = tmp[tid];
}
__global__ void scan_final(const int* __restrict__ deg, const int* __restrict__ bsum,
                           int* __restrict__ rowptr, int* __restrict__ curs, int n) {
    __shared__ int tmp[256];
    int tid = threadIdx.x;
    int b = blockIdx.x;
    int i = b * 256 + tid;
    int v = (i < n) ? deg[i] + 1 : 0;
    tmp[tid] = v; __syncthreads();
    for (int off = 1; off < 256; off <<= 1) {
        int t2 = (tid >= off) ? tmp[tid - off] : 0;
        __syncthreads();
        tmp[tid] += t2;
        __syncthreads();
    }
    int base = (b > 0) ? bsum[b - 1] : 0;
    if (i < n) {
        rowptr[i + 1] = base + tmp[tid];
        curs[i] = base + tmp[tid] - v;
    }
    if (b == 0 && tid == 0) rowptr[0] = 0;
}
// edges + self-loops in one launch (atomic slot assignment is order-free)
__global__ void csr_fill_all(const int* __restrict__ src, const int* __restrict__ dst,
                             int* cursor, int* __restrict__ csr_src, int* __restrict__ csr_dst) {
    int e = blockIdx.x * blockDim.x + threadIdx.x;
    int s, d;
    if (e < NE)        { s = src[e]; d = dst[e]; }
    else if (e < TOTE) { s = e - NE; d = s; }
    else return;
    int slot = atomicAdd(&cursor[d], 1);
    csr_src[slot] = s;
    csr_dst[slot] = d;
}

// ---------- layer-1 scores: ONE per-edge random-gather pass ----------
__global__ void edge_score3(const int* __restrict__ csr_src, const int* __restrict__ csr_dst,
                            const float* __restrict__ es, const float* __restrict__ ed,
                            float4* __restrict__ alpha, int E) {
    int s0 = blockIdx.x * blockDim.x + threadIdx.x;
    if (s0 >= E) return;
    int s = csr_src[s0], d = csr_dst[s0];
    float l0 = leaky(es[s * 3]     + ed[d * 3]);
    float l1 = leaky(es[s * 3 + 1] + ed[d * 3 + 1]);
    float l2 = leaky(es[s * 3 + 2] + ed[d * 3 + 2]);
    alpha[s0] = float4{l0, l1, l2, 0.f};
}
// per-dst softmax over CONTIGUOUS alpha range (no random gathers)
__global__ void seg_norm3(const int* __restrict__ rowptr, float4* __restrict__ alpha, int N) {
    int d = blockIdx.x * blockDim.x + threadIdx.x;
    if (d >= N) return;
    int b = rowptr[d], e = rowptr[d + 1];
    float m0 = -1e30f, m1 = -1e30f, m2 = -1e30f;
    for (int s0 = b; s0 < e; s0++) {
        float4 a = alpha[s0];
        m0 = fmaxf(m0, a.x); m1 = fmaxf(m1, a.y); m2 = fmaxf(m2, a.z);
    }
    float dn0 = 0.f, dn1 = 0.f, dn2 = 0.f;
    for (int s0 = b; s0 < e; s0++) {
        float4 a = alpha[s0];
        float x0 = expf(a.x - m0), x1 = expf(a.y - m1), x2 = expf(a.z - m2);
        dn0 += x0; dn1 += x1; dn2 += x2;
        alpha[s0] = float4{x0, x1, x2, 0.f};
    }
    float i0 = 1.f / (dn0 + 1e-16f), i1 = 1.f / (dn1 + 1e-16f), i2 = 1.f / (dn2 + 1e-16f);
    for (int s0 = b; s0 < e; s0++) {
        float4 a = alpha[s0];
        a.x *= i0; a.y *= i1; a.z *= i2;
        alpha[s0] = a;
    }
}

// ---------- layer-2 coefs (1 head; es2 tiny, L2-resident) ----------
__global__ void csr_maxden_alpha1(const int* __restrict__ rowptr, const int* __restrict__ csr_src,
                                  const float* __restrict__ es, const float* __restrict__ ed,
                                  float* __restrict__ alpha, int N) {
    int d = blockIdx.x * blockDim.x + threadIdx.x;
    if (d >= N) return;
    float edv = ed[d];
    int b = rowptr[d], e = rowptr[d + 1];
    float mm = -1e30f;
    for (int s0 = b; s0 < e; s0++) {
        int s = csr_src[s0];
        mm = fmaxf(mm, leaky(es[s] + edv));
    }
    float dn = 0.f;
    for (int s0 = b; s0 < e; s0++) {
        int s = csr_src[s0];
        float ex = expf(leaky(es[s] + edv) - mm);
        dn += ex;
        alpha[s0] = ex;
    }
    float inv = 1.f / (dn + 1e-16f);
    for (int s0 = b; s0 < e; s0++) alpha[s0] *= inv;
}

// ---------- layer-1 aggregate (bf16 h1) + bias + ELU + (row @ W2) + layer-2 coef ----------
// r6 version: depth-4 group pipeline, 128 threads, 12 row-loads in flight/thread.
// r7 proved the pipeline IS the MLP (plain loop regressed 111->145us). FROZEN.
__global__ __launch_bounds__(128) void csr_agg1_fused(
    const int* __restrict__ rowptr, const int* __restrict__ csr_src,
    const float4* __restrict__ alpha,
    const unsigned short* __restrict__ h1, const float* __restrict__ b1,
    const float* __restrict__ W2, float* __restrict__ h2,
    const float* __restrict__ as2, const float* __restrict__ ad2,
    float* __restrict__ es2, float* __restrict__ ed2, int N)
{
    int d = blockIdx.x;
    int t = threadIdx.x;
    __shared__ float row[HC1];
    __shared__ float part[128][OUTC + 1];

    int b = rowptr[d], e = rowptr[d + 1];
    float a0 = 0.f, a1 = 0.f, a2 = 0.f;

#define LOADG(g, I, A)                                                        \
    do {                                                                      \
        int base_ = b + (g) * 4;                                              \
        _Pragma("unroll")                                                     \
        for (int j = 0; j < 4; j++) {                                         \
            int s0_ = base_ + j;                                              \
            bool v_ = s0_ < e;                                                \
            int sc_ = v_ ? s0_ : (e - 1);                                     \
            I[j] = csr_src[sc_];                                              \
            float4 t4_ = alpha[sc_];                                          \
            if (!v_) { t4_.x = 0.f; t4_.y = 0.f; t4_.z = 0.f; }               \
            A[j] = t4_;                                                       \
        }                                                                     \
    } while (0)

    int ng = (e - b + 3) >> 2;
    int   iN[4]; float4 aN[4];
    LOADG(0, iN, aN);
    float rc[12]; float4 aC[4];
#pragma unroll
    for (int j = 0; j < 4; j++) {
        const unsigned short* hp = h1 + (long)iN[j] * HC1;
        rc[3 * j] = bf16f(hp[t]); rc[3 * j + 1] = bf16f(hp[t + 128]); rc[3 * j + 2] = bf16f(hp[t + 256]);
        aC[j] = aN[j];
    }
    LOADG(1, iN, aN);
    for (int g = 1; g < ng; g++) {
        float rn[12];
#pragma unroll
        for (int j = 0; j < 4; j++) {
            const unsigned short* hp = h1 + (long)iN[j] * HC1;
            rn[3 * j] = bf16f(hp[t]); rn[3 * j + 1] = bf16f(hp[t + 128]); rn[3 * j + 2] = bf16f(hp[t + 256]);
        }
        int iT[4]; float4 aT[4];
        LOADG(g + 1, iT, aT);
#pragma unroll
        for (int j = 0; j < 4; j++) {
            a0 = fmaf(rc[3 * j],     aC[j].x, a0);
            a1 = fmaf(rc[3 * j + 1], aC[j].y, a1);
            a2 = fmaf(rc[3 * j + 2], aC[j].z, a2);
        }
#pragma unroll
        for (int j = 0; j < 12; j++) rc[j] = rn[j];
#pragma unroll
        for (int j = 0; j < 4; j++) { aC[j] = aN[j]; iN[j] = iT[j]; aN[j] = aT[j]; }
    }
#pragma unroll
    for (int j = 0; j < 4; j++) {
        a0 = fmaf(rc[3 * j],     aC[j].x, a0);
        a1 = fmaf(rc[3 * j + 1], aC[j].y, a1);
        a2 = fmaf(rc[3 * j + 2], aC[j].z, a2);
    }
#undef LOADG

    float v;
    v = a0 + b1[t];       row[t]       = v > 0.f ? v : expf(v) - 1.f;
    v = a1 + b1[t + 128]; row[t + 128] = v > 0.f ? v : expf(v) - 1.f;
    v = a2 + b1[t + 256]; row[t + 256] = v > 0.f ? v : expf(v) - 1.f;
    __syncthreads();

    float pc[OUTC];
#pragma unroll
    for (int c = 0; c < OUTC; c++) pc[c] = 0.f;
    for (int k = t; k < HC1; k += 128) {
        float rv = row[k];
        const float* wp = W2 + (long)k * OUTC;
#pragma unroll
        for (int c = 0; c < OUTC; c++) pc[c] = fmaf(rv, wp[c], pc[c]);
    }
#pragma unroll
    for (int c = 0; c < OUTC; c++) part[t][c] = pc[c];
    __syncthreads();
    for (int off = 64; off > 0; off >>= 1) {
        if (t < off) {
#pragma unroll
            for (int c = 0; c < OUTC; c++) part[t][c] += part[t + off][c];
        }
        __syncthreads();
    }
    if (t < OUTC) h2[(long)d * OUTC + t] = part[0][t];
    if (t == 0) {
        float s = 0.f, dd = 0.f;
#pragma unroll
        for (int c = 0; c < OUTC; c++) {
            float hv = part[0][c];
            s  = fmaf(hv, as2[c], s);
            dd = fmaf(hv, ad2[c], dd);
        }
        es2[d] = s; ed2[d] = dd;
    }
}

// ---------- layer-2 aggregate + bias -> padded emb (stride 12) ----------
__global__ void csr_agg2(const int* __restrict__ rowptr, const int* __restrict__ csr_src,
                         const float* __restrict__ alpha,
                         const float* __restrict__ h2, const float* __restrict__ b2,
                         float* __restrict__ emb, int N)
{
    int idx = blockIdx.x * blockDim.x + threadIdx.x;
    if (idx >= N * EMBS) return;
    int d = idx / EMBS, c = idx - d * EMBS;
    if (c >= OUTC) { emb[idx] = 0.f; return; }
    int b = rowptr[d], e = rowptr[d + 1];
    float acc = 0.f;
    for (int s0 = b; s0 < e; s0++) {
        int s = csr_src[s0];
        acc = fmaf(h2[(long)s * OUTC + c], alpha[s0], acc);
    }
    emb[idx] = acc + b2[c];
}

// ---------- pair scores (padded emb: 3 float4 loads per row) ----------
__global__ void pair_score(const int* __restrict__ pairs, const float* __restrict__ emb,
                           float* __restrict__ out, int P) {
    int p = blockIdx.x * blockDim.x + threadIdx.x;
    if (p >= P) return;
    int i0 = pairs[2 * p], i1 = pairs[2 * p + 1];
    const float4* a = (const float4*)(emb + (long)i0 * EMBS);
    const float4* b = (const float4*)(emb + (long)i1 * EMBS);
    float4 a0 = a[0], a1 = a[1], a2 = a[2];
    float4 b0 = b[0], b1 = b[1], b2 = b[2];
    float s = a0.x*b0.x + a0.y*b0.y + a0.z*b0.z + a0.w*b0.w
            + a1.x*b1.x + a1.y*b1.y + a1.z*b1.z + a1.w*b1.w
            + a2.x*b2.x + a2.y*b2.y;
    out[p] = s;
}

extern "C" void kernel_launch(void* const* d_in, const int* in_sizes, int n_in,
                              void* d_out, int out_size, void* d_ws, size_t ws_size,
                              hipStream_t stream) {
    const float* fsub = (const float*)d_in[0];
    const float* fcom = (const float*)d_in[1];
    float*       x    = (float*)d_in[2];
    const int*   com  = (const int*)d_in[3];
    const int*   ei   = (const int*)d_in[4];
    const int*   pidx = (const int*)d_in[5];
    const float* Wq = (const float*)d_in[6];  const float* bq = (const float*)d_in[7];
    const float* Wk = (const float*)d_in[8];  const float* bk = (const float*)d_in[9];
    const float* Wv = (const float*)d_in[10]; const float* bv = (const float*)d_in[11];
    const float* Wf = (const float*)d_in[12]; const float* bf = (const float*)d_in[13];
    const float* W1 = (const float*)d_in[14];
    const float* as1 = (const float*)d_in[15]; const float* ad1 = (const float*)d_in[16];
    const float* b1 = (const float*)d_in[17];
    const float* W2 = (const float*)d_in[18];
    const float* as2 = (const float*)d_in[19]; const float* ad2 = (const float*)d_in[20];
    const float* b2 = (const float*)d_in[21];
    float* out = (float*)d_out;

    const int* src = ei;
    const int* dst = ei + NE;

    typedef unsigned short u16;
    char* ws = (char*)d_ws;
    float* S     = (float*)(ws + 0);            // dead after softmax
    u16*   SH    = (u16*)(ws + 67108864);       // dead after S@v
    u16*   SL    = (u16*)(ws + 100663296);
    u16*   fsubH = (u16*)(ws + 134217728);      // dead after q proj
    u16*   fsubL = (u16*)(ws + 136839168);
    u16*   fcomH = (u16*)(ws + 139460608);      // dead after k,v proj
    u16*   fcomL = (u16*)(ws + 142082048);
    u16*   qH    = (u16*)(ws + 144703488);      // dead after S gemm
    u16*   qL    = (u16*)(ws + 147324928);
    u16*   kH    = (u16*)(ws + 149946368);
    u16*   kL    = (u16*)(ws + 152567808);
    u16*   vTH   = (u16*)(ws + 155189248);      // dead after S@v
    u16*   vTL   = (u16*)(ws + 157646848);
    u16*   attnH = (u16*)(ws + 160104448);      // dead after fus gemm
    u16*   attnL = (u16*)(ws + 162725888);
    u16*   WqTH  = (u16*)(ws + 165347328);
    u16*   WqTL  = (u16*)(ws + 165539328);
    u16*   WkTH  = (u16*)(ws + 165731328);
    u16*   WkTL  = (u16*)(ws + 165923328);
    u16*   WvTH  = (u16*)(ws + 166115328);
    u16*   WvTL  = (u16*)(ws + 166307328);
    u16*   WfTH  = (u16*)(ws + 166499328);
    u16*   WfTL  = (u16*)(ws + 166691328);
    u16*   W1TH  = (u16*)(ws + 166883328);
    u16*   W1TL  = (u16*)(ws + 167129088);
    float* fus   = (float*)(ws + 167374848);    // alive until scatter
    float* es1   = (float*)(ws + 172290048);
    float* ed1   = (float*)(ws + 172890048);
    float* es2   = (float*)(ws + 174690048);
    float* ed2   = (float*)(ws + 174890048);
    float* h2    = (float*)(ws + 175490048);
    int*   last  = (int*)(ws + 179490048);
    int*   deg   = (int*)(ws + 179690048);
    int*   curs  = (int*)(ws + 179890048);
    int*   rowp  = (int*)(ws + 180090048);
    int*   csrc  = (int*)(ws + 180290064);      // ends 182,490,064
    int*   bsum  = (int*)(ws + 182490112);      // 196 ints
    // overlays (disjoint in time):
    float* part   = (float*)(ws + 0);           // over dead S (S@v phase), 4 slices
    u16*   h1b    = (u16*)(ws + 0);             // bf16 h1 over dead S/SH (GAT phase), 38.4MB
    u16*   xH     = (u16*)(ws + 76800000);      // over dead SH/SL; dead after h1 gemm
    u16*   xL     = (u16*)(ws + 108800000);
    float* alpha1 = (float*)(ws + 134217728);   // over dead fsubH.. (GAT phase), 8.8MB
    float* alpha2 = (float*)(ws + 144703488);   // over dead qH (GAT phase), 2.2MB -> ends 146,903,488
    int*   csrd   = (int*)(ws + 160104448);     // over dead attnH (CSR phase on), 2.2MB
    float* embp   = (float*)(ws + 147324928);   // over dead qL/kH, 2.4MB -> ends 149,724,928

    const float inv_sqrt_d = 1.0f / sqrtf((float)FEAT);

    // ===== 0. conversions (batched) =====
    {
        long tot5 = 4L * FEAT * KP + (long)HC1 * KP;   // 506,880
        hipLaunchKernelGGL(convT_pad5, dim3(cdiv((int)tot5, 256)), dim3(256), 0, stream,
                           Wq, Wk, Wv, Wf, W1,
                           WqTH, WqTL, WkTH, WkTL, WvTH, WvTL, WfTH, WfTL, W1TH, W1TL);
    }
    hipLaunchKernelGGL(conv_pad8_2, dim3(cdiv(2*BP*(KP/8),256)), dim3(256), 0, stream,
                       fsub, fcom, fsubH, fsubL, fcomH, fcomL);
    hipMemsetAsync(qH, 0, 10485760, stream);   // zero q/k hi+lo (incl. K-tail cols 300..319)

    // ===== 1. cross attention =====
    // small-N projections: 64x64 tile (320 blocks; gl128's 96 blocks was -34us, r8)
    hipLaunchKernelGGL((gemm_bf<1>), dim3(cdiv(FEAT,64), cdiv(BP,64)), dim3(256), 0, stream,
                       fsubH, fsubL, KP, WqTH, WqTL, KP, bq, nullptr, nullptr, qH, qL,
                       BP, FEAT, FEAT, 1.0f, KP);
    hipLaunchKernelGGL((gemm_bf<1>), dim3(cdiv(FEAT,64), cdiv(BP,64)), dim3(256), 0, stream,
                       fcomH, fcomL, KP, WkTH, WkTL, KP, bk, nullptr, nullptr, kH, kL,
                       BP, FEAT, FEAT, 1.0f, KP);
    hipLaunchKernelGGL((gemm_bf<2>), dim3(cdiv(FEAT,64), cdiv(BP,64)), dim3(256), 0, stream,
                       fcomH, fcomL, KP, WvTH, WvTL, KP, bv, nullptr, nullptr, vTH, vTL,
                       BP, FEAT, FEAT, 1.0f, BP);
    // large GEMMs: 128x128 gl-staged
    hipLaunchKernelGGL((gemm_gl128<false, 0>), dim3(cdiv(BP,128), cdiv(BP,128)), dim3(256), 0, stream,
                       qH, (long)(qL - qH), KP, kH, (long)(kL - kH), KP,
                       S, nullptr, BP, BP, FEAT, inv_sqrt_d, 0);
    hipLaunchKernelGGL(softmax_hl, dim3(BP), dim3(256), 0, stream, S, SH, SL);
    hipLaunchKernelGGL((gemm_gl128<true, 0>), dim3(cdiv(FEAT,128), cdiv(BP,128), 4), dim3(256), 0, stream,
                       SH, (long)(SL - SH), BP, vTH, (long)(vTL - vTH), BP,
                       part, nullptr, BP, FEAT, BP, 1.0f, 1024);
    hipLaunchKernelGGL(splitk_reduce8, dim3(cdiv(BP*(KP/8),256)), dim3(256), 0, stream,
                       part, fsub, attnH, attnL, BP, FEAT, KP, 4);
    hipLaunchKernelGGL((gemm_bf<0>), dim3(cdiv(FEAT,64), cdiv(BP,64)), dim3(256), 0, stream,
                       attnH, attnL, KP, WfTH, WfTL, KP, bf, nullptr, fus, nullptr, nullptr,
                       BP, FEAT, FEAT, 1.0f, FEAT);

    // ===== 2. convert pristine x, then scatter fused rows directly as bf16 =====
    hipLaunchKernelGGL(conv_pad8, dim3(cdiv((long)NN*(KP/8),256)), dim3(256), 0, stream, x, xH, xL, NN, FEAT, KP);
    hipLaunchKernelGGL(scatter_init, dim3(cdiv(BP,256)), dim3(256), 0, stream, last, com, BP);
    hipLaunchKernelGGL(scatter_max,  dim3(cdiv(BP,256)), dim3(256), 0, stream, last, com, BP);
    hipLaunchKernelGGL(scatter_write_hl, dim3(BP), dim3(128), 0, stream, last, com, fus, xH, xL, BP);

    // ===== 3. CSR build =====
    hipMemsetAsync(deg, 0, NN * sizeof(int), stream);
    hipLaunchKernelGGL(deg_count, dim3(cdiv(NE,256)), dim3(256), 0, stream, dst, deg, NE);
    {
        int nb = cdiv(NN, 256);   // 196
        hipLaunchKernelGGL(scan_part,  dim3(nb), dim3(256), 0, stream, deg, bsum, NN);
        hipLaunchKernelGGL(scan_bsum,  dim3(1),  dim3(256), 0, stream, bsum, nb);
        hipLaunchKernelGGL(scan_final, dim3(nb), dim3(256), 0, stream, deg, bsum, rowp, curs, NN);
    }
    hipLaunchKernelGGL(csr_fill_all, dim3(cdiv(TOTE,256)), dim3(256), 0, stream,
                       src, dst, curs, csrc, csrd);

    // ===== 4. GAT layer 1 (h1 in bf16: gather working set 38.4 MB) =====
    hipLaunchKernelGGL((gemm_gl128<false, 1>), dim3(cdiv(HC1,128), cdiv(NN,128)), dim3(256), 0, stream,
                       xH, (long)(xL - xH), KP, W1TH, (long)(W1TL - W1TH), KP,
                       nullptr, h1b, NN, HC1, FEAT, 1.0f, 0);
    hipLaunchKernelGGL(node_attn_coef3, dim3(cdiv(NN,4)), dim3(256), 0, stream,
                       h1b, as1, ad1, es1, ed1, NN);
    hipLaunchKernelGGL(edge_score3, dim3(cdiv(TOTE,256)), dim3(256), 0, stream,
                       csrc, csrd, es1, ed1, (float4*)alpha1, TOTE);
    hipLaunchKernelGGL(seg_norm3, dim3(cdiv(NN,256)), dim3(256), 0, stream,
                       rowp, (float4*)alpha1, NN);
    hipLaunchKernelGGL(csr_agg1_fused, dim3(NN), dim3(128), 0, stream,
                       rowp, csrc, (const float4*)alpha1, h1b, b1, W2, h2, as2, ad2, es2, ed2, NN);

    // ===== 5. GAT layer 2 =====
    hipLaunchKernelGGL(csr_maxden_alpha1, dim3(cdiv(NN,256)), dim3(256), 0, stream,
                       rowp, csrc, es2, ed2, alpha2, NN);
    hipLaunchKernelGGL(csr_agg2, dim3(cdiv(NN*EMBS,256)), dim3(256), 0, stream,
                       rowp, csrc, alpha2, h2, b2, embp, NN);

    // ===== 6. pair scores =====
    hipLaunchKernelGGL(pair_score, dim3(cdiv(NP,256)), dim3(256), 0, stream, pidx, embp, out, NP);
}

// Round 10
// 649.594 us; speedup vs baseline: 1.1783x; 1.0838x over previous
//
#include <hip/hip_runtime.h>
#include <math.h>

#define NN      50000      // N_NODES
#define BP      4096       // N_PAIRS_MAP
#define NE      500000     // N_EDGES
#define NP      1000000    // N_SCORE_PAIRS
#define FEAT    300
#define KP      320        // FEAT padded to multiple of 32
#define HID     128
#define HEADS   3
#define OUTC    10
#define HC1     (HEADS*HID)   // 384
#define EMBS    12            // embp row stride (floats, 48B = 16B-aligned)
#define TOTE    (NE+NN)       // CSR slots incl. self-loops
#define NEG_SLOPE 0.2f

static inline int cdiv(int a, int b) { return (a + b - 1) / b; }

using bfrag = __attribute__((ext_vector_type(8))) short;
using ffrag = __attribute__((ext_vector_type(4))) float;

__device__ inline float leaky(float x) { return x > 0.f ? x : NEG_SLOPE * x; }
__device__ inline unsigned short bf16_rne(float f) {
    unsigned u = __float_as_uint(f);
    unsigned r = u + 0x7FFFu + ((u >> 16) & 1u);
    return (unsigned short)(r >> 16);
}
__device__ inline float bf16f(unsigned short h) { return __uint_as_float(((unsigned)h) << 16); }
// packed-uint bf16 pair -> floats (1 VALU op each)
__device__ inline float bf16lo(unsigned u) { return __uint_as_float(u << 16); }
__device__ inline float bf16hi(unsigned u) { return __uint_as_float(u & 0xffff0000u); }

__device__ __forceinline__ void gload_lds16(const unsigned short* g, unsigned short* l) {
    __builtin_amdgcn_global_load_lds((const __attribute__((address_space(1))) void*)g,
                                     (__attribute__((address_space(3))) void*)l, 16, 0, 0);
}

// fp32 [M][K] -> bf16 hi/lo [M][Kp]; 8 elems/thread, uint4 stores (G13)
__global__ void conv_pad8(const float* __restrict__ in, unsigned short* __restrict__ H,
                          unsigned short* __restrict__ L, long M, int K, int Kp) {
    long idx = (long)blockIdx.x * blockDim.x + threadIdx.x;
    int cpk = Kp >> 3;
    long total = M * cpk;
    if (idx >= total) return;
    int chunk = (int)(idx % cpk);
    long row = idx / cpk;
    int k0 = chunk * 8;
    const float* ip = in + row * K;
    float v[8];
    if (k0 + 8 <= K) {
        float4 a = *(const float4*)(ip + k0);
        float4 b = *(const float4*)(ip + k0 + 4);
        v[0]=a.x; v[1]=a.y; v[2]=a.z; v[3]=a.w; v[4]=b.x; v[5]=b.y; v[6]=b.z; v[7]=b.w;
    } else {
#pragma unroll
        for (int j = 0; j < 8; j++) { int k = k0 + j; v[j] = (k < K) ? ip[k] : 0.f; }
    }
    unsigned short hs[8], ls[8];
#pragma unroll
    for (int j = 0; j < 8; j++) {
        unsigned short h = bf16_rne(v[j]);
        hs[j] = h; ls[j] = bf16_rne(v[j] - bf16f(h));
    }
    long o = row * Kp + k0;
    *(uint4*)&H[o] = *(const uint4*)hs;
    *(uint4*)&L[o] = *(const uint4*)ls;
}

// fsub + fcom in one launch (same shape [BP][FEAT] -> [BP][KP] hi/lo)
__global__ void conv_pad8_2(const float* __restrict__ inA, const float* __restrict__ inB,
                            unsigned short* __restrict__ HA, unsigned short* __restrict__ LA,
                            unsigned short* __restrict__ HB, unsigned short* __restrict__ LB) {
    long idx = (long)blockIdx.x * blockDim.x + threadIdx.x;
    int cpk = KP >> 3;
    long total = 2L * BP * cpk;
    if (idx >= total) return;
    int chunk = (int)(idx % cpk);
    long row = idx / cpk;
    const float* in; unsigned short *H, *L;
    if (row < BP) { in = inA; H = HA; L = LA; }
    else          { in = inB; H = HB; L = LB; row -= BP; }
    int k0 = chunk * 8;
    const float* ip = in + row * FEAT;
    float v[8];
    if (k0 + 8 <= FEAT) {
        float4 a = *(const float4*)(ip + k0);
        float4 b = *(const float4*)(ip + k0 + 4);
        v[0]=a.x; v[1]=a.y; v[2]=a.z; v[3]=a.w; v[4]=b.x; v[5]=b.y; v[6]=b.z; v[7]=b.w;
    } else {
#pragma unroll
        for (int j = 0; j < 8; j++) { int k = k0 + j; v[j] = (k < FEAT) ? ip[k] : 0.f; }
    }
    unsigned short hs[8], ls[8];
#pragma unroll
    for (int j = 0; j < 8; j++) {
        unsigned short h = bf16_rne(v[j]);
        hs[j] = h; ls[j] = bf16_rne(v[j] - bf16f(h));
    }
    long o = row * KP + k0;
    *(uint4*)&H[o] = *(const uint4*)hs;
    *(uint4*)&L[o] = *(const uint4*)ls;
}

// all 5 weight transposes in ONE launch. W0..W3: [300][300]; W4: [300][384].
__global__ void convT_pad5(
    const float* __restrict__ s0, const float* __restrict__ s1, const float* __restrict__ s2,
    const float* __restrict__ s3, const float* __restrict__ s4,
    unsigned short* __restrict__ h0, unsigned short* __restrict__ l0,
    unsigned short* __restrict__ h1, unsigned short* __restrict__ l1,
    unsigned short* __restrict__ h2, unsigned short* __restrict__ l2,
    unsigned short* __restrict__ h3, unsigned short* __restrict__ l3,
    unsigned short* __restrict__ h4, unsigned short* __restrict__ l4)
{
    long idx = (long)blockIdx.x * blockDim.x + threadIdx.x;
    const long R = (long)FEAT * KP;          // 96000 per square weight
    const float* src; unsigned short *H, *L; int N; long off;
    if (idx < 4 * R) {
        int m = (int)(idx / R); off = idx - (long)m * R; N = FEAT;
        src = (m == 0) ? s0 : (m == 1) ? s1 : (m == 2) ? s2 : s3;
        H   = (m == 0) ? h0 : (m == 1) ? h1 : (m == 2) ? h2 : h3;
        L   = (m == 0) ? l0 : (m == 1) ? l1 : (m == 2) ? l2 : l3;
    } else if (idx < 4 * R + (long)HC1 * KP) {
        off = idx - 4 * R; N = HC1; src = s4; H = h4; L = l4;
    } else return;
    int k = (int)(off % KP);
    long n = off / KP;
    float f = (k < FEAT) ? src[(long)k * N + n] : 0.f;
    unsigned short h = bf16_rne(f);
    H[off] = h;
    L[off] = bf16_rne(f - bf16f(h));
}

// ================== split-bf16 MFMA GEMM (64x64 tile, LDS-staged) ==================
// For the SMALL GEMMs (q,k,v,fus: M=4096,N=300): 320 blocks vs gl128's 96 —
// r8 measured the gl128 form 34us SLOWER here (under-occupancy). Keep 64-tile.
template <int MODE>
__global__ __launch_bounds__(256) void gemm_bf(
    const unsigned short* __restrict__ Ah, const unsigned short* __restrict__ Al, int lda,
    const unsigned short* __restrict__ Bh, const unsigned short* __restrict__ Bl, int ldb,
    const float* __restrict__ bias, const float* __restrict__ addsrc,
    float* __restrict__ C0, unsigned short* __restrict__ H0, unsigned short* __restrict__ L0,
    int M, int N, int K, float scale, int ldo)
{
    __shared__ __align__(16) unsigned short Ahs[4][64][8], Als[4][64][8];
    __shared__ __align__(16) unsigned short Bhs[4][64][8], Bls[4][64][8];
    int t = threadIdx.x, w = t >> 6, l = t & 63, lrow = l & 15, lq = l >> 4;
    int rowBase = blockIdx.y * 64, colBase = blockIdx.x * 64;
    int Kr = (K + 31) & ~31;

    int arow = min(rowBase + l, M - 1);
    int brow = min(colBase + l, N - 1);
    const unsigned short* ga_h = Ah + (long)arow * lda + w * 8;
    const unsigned short* ga_l = Al + (long)arow * lda + w * 8;
    const unsigned short* gb_h = Bh + (long)brow * ldb + w * 8;
    const unsigned short* gb_l = Bl + (long)brow * ldb + w * 8;

    ffrag acc[4] = {{0.f,0.f,0.f,0.f},{0.f,0.f,0.f,0.f},{0.f,0.f,0.f,0.f},{0.f,0.f,0.f,0.f}};

    for (int k0 = 0; k0 < Kr; k0 += 32) {
        *(uint4*)&Ahs[w][l][0] = *(const uint4*)(ga_h + k0);
        *(uint4*)&Als[w][l][0] = *(const uint4*)(ga_l + k0);
        *(uint4*)&Bhs[w][l][0] = *(const uint4*)(gb_h + k0);
        *(uint4*)&Bls[w][l][0] = *(const uint4*)(gb_l + k0);
        __syncthreads();
        bfrag ah  = *(const bfrag*)&Ahs[lq][w * 16 + lrow][0];
        bfrag alo = *(const bfrag*)&Als[lq][w * 16 + lrow][0];
#pragma unroll
        for (int ct = 0; ct < 4; ct++) {
            bfrag bh = *(const bfrag*)&Bhs[lq][ct * 16 + lrow][0];
            bfrag bl = *(const bfrag*)&Bls[lq][ct * 16 + lrow][0];
            acc[ct] = __builtin_amdgcn_mfma_f32_16x16x32_bf16(ah,  bh, acc[ct], 0, 0, 0);
            acc[ct] = __builtin_amdgcn_mfma_f32_16x16x32_bf16(ah,  bl, acc[ct], 0, 0, 0);
            acc[ct] = __builtin_amdgcn_mfma_f32_16x16x32_bf16(alo, bh, acc[ct], 0, 0, 0);
        }
        __syncthreads();
    }

#pragma unroll
    for (int ct = 0; ct < 4; ct++) {
        int gc = colBase + ct * 16 + lrow;
        if (gc >= N) continue;
#pragma unroll
        for (int r = 0; r < 4; r++) {
            int gr = rowBase + w * 16 + lq * 4 + r;
            if (gr >= M) continue;
            float v = acc[ct][r];
            if (MODE == 0) {
                float o = v * scale;
                if (bias) o += bias[gc];
                if (addsrc) o += addsrc[(long)gr * ldo + gc];
                C0[(long)gr * ldo + gc] = o;
            } else if (MODE == 1) {
                float o = v + bias[gc];
                unsigned short h = bf16_rne(o);
                H0[(long)gr * ldo + gc] = h;
                L0[(long)gr * ldo + gc] = bf16_rne(o - bf16f(h));
            } else {
                float o = v + bias[gc];
                unsigned short h = bf16_rne(o);
                H0[(long)gc * ldo + gr] = h;
                L0[(long)gc * ldo + gr] = bf16_rne(o - bf16f(h));
            }
        }
    }
}

// ================== split-bf16 GEMM, 128x128 tile, global_load_lds staging ==================
// Used for h1 only now (full split precision). OUT: 0 = f32, 1 = bf16 out.
template <bool SPLITK, int OUT>
__global__ __launch_bounds__(256) void gemm_gl128(
    const unsigned short* __restrict__ Ah, long dAl, int lda,
    const unsigned short* __restrict__ Bh, long dBl, int ldb,
    float* __restrict__ C0, unsigned short* __restrict__ Hb,
    int M, int N, int K, float scale, int KC)
{
    __shared__ __align__(16) unsigned short As[128][64];
    __shared__ __align__(16) unsigned short Bs[128][64];
    int t = threadIdx.x, w = t >> 6, l = t & 63, lrow = l & 15, lq = l >> 4;
    int wr = w >> 1, wc = w & 1;
    int rowBase = blockIdx.y * 128, colBase = blockIdx.x * 128;
    int Kr = (K + 31) & ~31;
    int kbeg = SPLITK ? blockIdx.z * KC : 0;
    int kend = SPLITK ? min(Kr, kbeg + KC) : Kr;

    bool isA = (w < 2);
    const unsigned short* Mb = isA ? Ah : Bh;
    long dHL = isA ? dAl : dBl;
    int ld   = isA ? lda : ldb;
    int mx   = (isA ? M : N) - 1;
    int rb0  = (isA ? rowBase : colBase) + (w & 1) * 64;
    int lr8  = l >> 3;
    int lg   = (l & 7) ^ lr8;
    long lane_off = (long)((lg & 3) * 8) + ((lg >> 2) ? dHL : 0);
    const unsigned short* gp[8];
#pragma unroll
    for (int i = 0; i < 8; i++) {
        int r = rb0 + i * 8 + lr8;
        gp[i] = Mb + (long)min(r, mx) * ld + lane_off;
    }
    unsigned short* ldst[8];
    {
        unsigned short (*T)[64] = isA ? As : Bs;
#pragma unroll
        for (int i = 0; i < 8; i++) ldst[i] = &T[(w & 1) * 64 + i * 8][0];
    }

    ffrag acc[4][4];
#pragma unroll
    for (int m = 0; m < 4; m++)
#pragma unroll
        for (int n = 0; n < 4; n++) acc[m][n] = ffrag{0.f, 0.f, 0.f, 0.f};

    int arow0 = wr * 64 + lrow, brow0 = wc * 64 + lrow;
    int xr = lrow & 7;
    int sh = ((lq    ) ^ xr) * 8;
    int sl = ((lq + 4) ^ xr) * 8;

    for (int k0 = kbeg; k0 < kend; k0 += 32) {
#pragma unroll
        for (int i = 0; i < 8; i++) gload_lds16(gp[i] + k0, ldst[i]);
        __syncthreads();

        bfrag bh[4], bl[4];
#pragma unroll
        for (int n = 0; n < 4; n++) {
            bh[n] = *(const bfrag*)&Bs[brow0 + n * 16][sh];
            bl[n] = *(const bfrag*)&Bs[brow0 + n * 16][sl];
        }
#pragma unroll
        for (int m = 0; m < 4; m++) {
            bfrag ah = *(const bfrag*)&As[arow0 + m * 16][sh];
            bfrag al = *(const bfrag*)&As[arow0 + m * 16][sl];
#pragma unroll
            for (int n = 0; n < 4; n++) {
                acc[m][n] = __builtin_amdgcn_mfma_f32_16x16x32_bf16(ah, bh[n], acc[m][n], 0, 0, 0);
                acc[m][n] = __builtin_amdgcn_mfma_f32_16x16x32_bf16(ah, bl[n], acc[m][n], 0, 0, 0);
                acc[m][n] = __builtin_amdgcn_mfma_f32_16x16x32_bf16(al, bh[n], acc[m][n], 0, 0, 0);
            }
        }
        __syncthreads();
    }

#pragma unroll
    for (int n = 0; n < 4; n++) {
        int gc = colBase + wc * 64 + n * 16 + lrow;
        if (gc >= N) continue;
#pragma unroll
        for (int m = 0; m < 4; m++) {
#pragma unroll
            for (int r = 0; r < 4; r++) {
                int gr = rowBase + wr * 64 + m * 16 + lq * 4 + r;
                if (gr >= M) continue;
                if (OUT == 0) {
                    float* Cz = SPLITK ? (C0 + (long)blockIdx.z * M * N) : C0;
                    Cz[(long)gr * N + gc] = acc[m][n][r] * scale;
                } else {
                    Hb[(long)gr * N + gc] = bf16_rne(acc[m][n][r]);
                }
            }
        }
    }
}

// ================== SINGLE-bf16 GEMM, 128x128 tile, 64-k LDS rows ==================
// Same gl-staging/XOR machinery as gemm_gl128, but each 128-B LDS row holds 64
// CONTIGUOUS k (two K-steps) of the hi buffer only. Per 64-k window: 8 gloads,
// 16 ds_read_b128, 32 MFMA (vs split's 16 gloads, 32 ds, 96 MFMA). Used for the
// attention-score path (S = q@k^T and S@v) where the lo-correction is provably
// negligible (attn is O(0.03) vs residual's O(1); see r10 error analysis).
template <bool SPLITK>
__global__ __launch_bounds__(256) void gemm_gl64k(
    const unsigned short* __restrict__ Ah, int lda,
    const unsigned short* __restrict__ Bh, int ldb,
    float* __restrict__ C0, int M, int N, int K, float scale, int KC)
{
    __shared__ __align__(16) unsigned short As[128][64];
    __shared__ __align__(16) unsigned short Bs[128][64];
    int t = threadIdx.x, w = t >> 6, l = t & 63, lrow = l & 15, lq = l >> 4;
    int wr = w >> 1, wc = w & 1;
    int rowBase = blockIdx.y * 128, colBase = blockIdx.x * 128;
    int Kr = (K + 63) & ~63;
    int kbeg = SPLITK ? blockIdx.z * KC : 0;
    int kend = SPLITK ? min(Kr, kbeg + KC) : Kr;

    bool isA = (w < 2);
    const unsigned short* Mb = isA ? Ah : Bh;
    int ld   = isA ? lda : ldb;
    int mx   = (isA ? M : N) - 1;
    int rb0  = (isA ? rowBase : colBase) + (w & 1) * 64;
    int lr8  = l >> 3;
    int lg   = (l & 7) ^ lr8;           // logical k-chunk (0..7) this lane fetches
    long lane_off = (long)lg * 8;       // k-offset in elements
    const unsigned short* gp[8];
#pragma unroll
    for (int i = 0; i < 8; i++) {
        int r = rb0 + i * 8 + lr8;
        gp[i] = Mb + (long)min(r, mx) * ld + lane_off;
    }
    unsigned short* ldst[8];
    {
        unsigned short (*T)[64] = isA ? As : Bs;
#pragma unroll
        for (int i = 0; i < 8; i++) ldst[i] = &T[(w & 1) * 64 + i * 8][0];
    }

    ffrag acc[4][4];
#pragma unroll
    for (int m = 0; m < 4; m++)
#pragma unroll
        for (int n = 0; n < 4; n++) acc[m][n] = ffrag{0.f, 0.f, 0.f, 0.f};

    int arow0 = wr * 64 + lrow, brow0 = wc * 64 + lrow;
    int xr = lrow & 7;
    int sk0 = ((lq    ) ^ xr) * 8;   // physical slot of logical chunk lq   (k 0..31)
    int sk1 = ((lq + 4) ^ xr) * 8;   // physical slot of logical chunk lq+4 (k 32..63)

    for (int k0 = kbeg; k0 < kend; k0 += 64) {
#pragma unroll
        for (int i = 0; i < 8; i++) gload_lds16(gp[i] + k0, ldst[i]);
        __syncthreads();

        bfrag b0[4], b1[4];
#pragma unroll
        for (int n = 0; n < 4; n++) {
            b0[n] = *(const bfrag*)&Bs[brow0 + n * 16][sk0];
            b1[n] = *(const bfrag*)&Bs[brow0 + n * 16][sk1];
        }
#pragma unroll
        for (int m = 0; m < 4; m++) {
            bfrag a0 = *(const bfrag*)&As[arow0 + m * 16][sk0];
            bfrag a1 = *(const bfrag*)&As[arow0 + m * 16][sk1];
#pragma unroll
            for (int n = 0; n < 4; n++) {
                acc[m][n] = __builtin_amdgcn_mfma_f32_16x16x32_bf16(a0, b0[n], acc[m][n], 0, 0, 0);
                acc[m][n] = __builtin_amdgcn_mfma_f32_16x16x32_bf16(a1, b1[n], acc[m][n], 0, 0, 0);
            }
        }
        __syncthreads();
    }

    float* Cz = SPLITK ? (C0 + (long)blockIdx.z * M * N) : C0;
#pragma unroll
    for (int n = 0; n < 4; n++) {
        int gc = colBase + wc * 64 + n * 16 + lrow;
        if (gc >= N) continue;
#pragma unroll
        for (int m = 0; m < 4; m++) {
#pragma unroll
            for (int r = 0; r < 4; r++) {
                int gr = rowBase + wr * 64 + m * 16 + lq * 4 + r;
                if (gr >= M) continue;
                Cz[(long)gr * N + gc] = acc[m][n][r] * scale;
            }
        }
    }
}

// ---------- softmax rows of S -> bf16 (hi only; S@v is single-bf16 now) ----------
__global__ __launch_bounds__(256) void softmax_h(const float* __restrict__ S,
                                                 unsigned short* __restrict__ SH) {
    int row = blockIdx.x, tid = threadIdx.x;
    const float* p = S + (long)row * BP + tid * 16;
    float ev[16];
    __shared__ float red[256];
    float m = -1e30f;
#pragma unroll
    for (int i = 0; i < 4; i++) {
        float4 a = *(const float4*)(p + i * 4);
        ev[4*i] = a.x; ev[4*i+1] = a.y; ev[4*i+2] = a.z; ev[4*i+3] = a.w;
        m = fmaxf(m, fmaxf(fmaxf(a.x, a.y), fmaxf(a.z, a.w)));
    }
    red[tid] = m; __syncthreads();
    for (int s = 128; s > 0; s >>= 1) { if (tid < s) red[tid] = fmaxf(red[tid], red[tid + s]); __syncthreads(); }
    m = red[0]; __syncthreads();
    float sum = 0.f;
#pragma unroll
    for (int i = 0; i < 16; i++) { float e = expf(ev[i] - m); ev[i] = e; sum += e; }
    red[tid] = sum; __syncthreads();
    for (int s = 128; s > 0; s >>= 1) { if (tid < s) red[tid] += red[tid + s]; __syncthreads(); }
    float inv = 1.0f / red[0];
    unsigned short hs[16];
#pragma unroll
    for (int i = 0; i < 16; i++) hs[i] = bf16_rne(ev[i] * inv);
    long o = (long)row * BP + tid * 16;
    *(uint4*)&SH[o]     = *(const uint4*)&hs[0];
    *(uint4*)&SH[o + 8] = *(const uint4*)&hs[8];
}

// ---------- split-K reduce + residual -> attn bf16 hi/lo; 8 elems/thread ----------
__global__ void splitk_reduce8(const float* __restrict__ part, const float* __restrict__ resid,
                               unsigned short* __restrict__ H, unsigned short* __restrict__ L,
                               int Mr, int Nc, int Kp2, int sk) {
    long idx = (long)blockIdx.x * blockDim.x + threadIdx.x;
    int cpk = Kp2 >> 3;
    long total = (long)Mr * cpk;
    if (idx >= total) return;
    int chunk = (int)(idx % cpk);
    long row = idx / cpk;
    int c0 = chunk * 8;
    float v[8] = {0.f,0.f,0.f,0.f,0.f,0.f,0.f,0.f};
    if (c0 + 8 <= Nc) {
        long base = row * Nc + c0;
#pragma unroll
        for (int z = 0; z < 8; z++) {
            if (z >= sk) break;
            float4 a = *(const float4*)(part + (long)z * Mr * Nc + base);
            float4 b = *(const float4*)(part + (long)z * Mr * Nc + base + 4);
            v[0]+=a.x; v[1]+=a.y; v[2]+=a.z; v[3]+=a.w; v[4]+=b.x; v[5]+=b.y; v[6]+=b.z; v[7]+=b.w;
        }
        float4 a = *(const float4*)(resid + base);
        float4 b = *(const float4*)(resid + base + 4);
        v[0]+=a.x; v[1]+=a.y; v[2]+=a.z; v[3]+=a.w; v[4]+=b.x; v[5]+=b.y; v[6]+=b.z; v[7]+=b.w;
    } else if (c0 < Nc) {
#pragma unroll
        for (int j = 0; j < 8; j++) {
            int c = c0 + j;
            if (c < Nc) {
                long base = row * Nc + c;
                float s = resid[base];
                for (int z = 0; z < sk; z++) s += part[(long)z * Mr * Nc + base];
                v[j] = s;
            }
        }
    }
    unsigned short hs[8], ls[8];
#pragma unroll
    for (int j = 0; j < 8; j++) {
        unsigned short h = bf16_rne(v[j]);
        hs[j] = h; ls[j] = bf16_rne(v[j] - bf16f(h));
    }
    long o = row * Kp2 + c0;
    *(uint4*)&H[o] = *(const uint4*)hs;
    *(uint4*)&L[o] = *(const uint4*)ls;
}

// ---------- scatter (last write wins), writing bf16 hi/lo x directly ----------
__global__ void scatter_init(int* last, const int* __restrict__ com, int B) {
    int i = blockIdx.x * blockDim.x + threadIdx.x;
    if (i < B) last[com[i]] = -1;
}
__global__ void scatter_max(int* last, const int* __restrict__ com, int B) {
    int i = blockIdx.x * blockDim.x + threadIdx.x;
    if (i < B) atomicMax(&last[com[i]], i);
}
__global__ void scatter_write_hl(const int* __restrict__ last, const int* __restrict__ com,
                                 const float* __restrict__ fused,
                                 unsigned short* __restrict__ xH, unsigned short* __restrict__ xL, int B) {
    int i = blockIdx.x;
    int node = com[i];
    if (last[node] != i) return;
    for (int c = threadIdx.x; c < KP; c += blockDim.x) {
        float f = (c < FEAT) ? fused[(long)i * FEAT + c] : 0.f;
        unsigned short h = bf16_rne(f);
        xH[(long)node * KP + c] = h;
        xL[(long)node * KP + c] = bf16_rne(f - bf16f(h));
    }
}

// ---------- layer-1 coefficients from bf16 h1, wave-per-node, uint-packed ----------
__global__ __launch_bounds__(256) void node_attn_coef3(
    const unsigned short* __restrict__ h1, const float* __restrict__ a_src,
    const float* __restrict__ a_dst, float* __restrict__ es, float* __restrict__ ed, int N)
{
    int w = threadIdx.x >> 6, lane = threadIdx.x & 63;
    int n = blockIdx.x * 4 + w;
    if (n >= N) return;
    const unsigned short* hp = h1 + (long)n * HC1;
    int c = 2 * lane;  // cols c, c+1 within each 128-col head block
    unsigned u0 = *(const unsigned*)&hp[c];
    unsigned u1 = *(const unsigned*)&hp[128 + c];
    unsigned u2 = *(const unsigned*)&hp[256 + c];
    float s0, s1, s2, d0, d1, d2;
    {
        float vl = bf16lo(u0), vh = bf16hi(u0);
        s0 = fmaf(vl, a_src[c], vh * a_src[c + 1]);
        d0 = fmaf(vl, a_dst[c], vh * a_dst[c + 1]);
        vl = bf16lo(u1); vh = bf16hi(u1);
        s1 = fmaf(vl, a_src[128 + c], vh * a_src[128 + c + 1]);
        d1 = fmaf(vl, a_dst[128 + c], vh * a_dst[128 + c + 1]);
        vl = bf16lo(u2); vh = bf16hi(u2);
        s2 = fmaf(vl, a_src[256 + c], vh * a_src[256 + c + 1]);
        d2 = fmaf(vl, a_dst[256 + c], vh * a_dst[256 + c + 1]);
    }
#pragma unroll
    for (int off = 32; off > 0; off >>= 1) {
        s0 += __shfl_down(s0, off); s1 += __shfl_down(s1, off); s2 += __shfl_down(s2, off);
        d0 += __shfl_down(d0, off); d1 += __shfl_down(d1, off); d2 += __shfl_down(d2, off);
    }
    if (lane == 0) {
        es[n * 3 + 0] = s0; es[n * 3 + 1] = s1; es[n * 3 + 2] = s2;
        ed[n * 3 + 0] = d0; ed[n * 3 + 1] = d1; ed[n * 3 + 2] = d2;
    }
}

// ================== CSR build ==================
// deg zeroed by hipMemsetAsync; scan reads deg[i]+1 (self-loop folded in).
__global__ void deg_count(const int* __restrict__ dst, int* deg, int E) {
    int e = blockIdx.x * blockDim.x + threadIdx.x;
    if (e < E) atomicAdd(&deg[dst[e]], 1);
}
__global__ void scan_part(const int* __restrict__ deg, int* __restrict__ bsum, int n) {
    __shared__ int red[256];
    int tid = threadIdx.x;
    int i = blockIdx.x * 256 + tid;
    red[tid] = (i < n) ? deg[i] + 1 : 0;
    __syncthreads();
    for (int s = 128; s > 0; s >>= 1) { if (tid < s) red[tid] += red[tid + s]; __syncthreads(); }
    if (tid == 0) bsum[blockIdx.x] = red[0];
}
__global__ __launch_bounds__(256) void scan_bsum(int* __restrict__ bsum, int nb) {
    __shared__ int tmp[256];
    int tid = threadIdx.x;
    int v = (tid < nb) ? bsum[tid] : 0;
    tmp[tid] = v; __syncthreads();
    for (int off = 1; off < 256; off <<= 1) {
        int t2 = (tid >= off) ? tmp[tid - off] : 0;
        __syncthreads();
        tmp[tid] += t2;
        __syncthreads();
    }
    if (tid < nb) bsum[tid] = tmp[tid];
}
__global__ void scan_final(const int* __restrict__ deg, const int* __restrict__ bsum,
                           int* __restrict__ rowptr, int* __restrict__ curs, int n) {
    __shared__ int tmp[256];
    int tid = threadIdx.x;
    int b = blockIdx.x;
    int i = b * 256 + tid;
    int v = (i < n) ? deg[i] + 1 : 0;
    tmp[tid] = v; __syncthreads();
    for (int off = 1; off < 256; off <<= 1) {
        int t2 = (tid >= off) ? tmp[tid - off] : 0;
        __syncthreads();
        tmp[tid] += t2;
        __syncthreads();
    }
    int base = (b > 0) ? bsum[b - 1] : 0;
    if (i < n) {
        rowptr[i + 1] = base + tmp[tid];
        curs[i] = base + tmp[tid] - v;
    }
    if (b == 0 && tid == 0) rowptr[0] = 0;
}
// edges + self-loops in one launch (atomic slot assignment is order-free)
__global__ void csr_fill_all(const int* __restrict__ src, const int* __restrict__ dst,
                             int* cursor, int* __restrict__ csr_src, int* __restrict__ csr_dst) {
    int e = blockIdx.x * blockDim.x + threadIdx.x;
    int s, d;
    if (e < NE)        { s = src[e]; d = dst[e]; }
    else if (e < TOTE) { s = e - NE; d = s; }
    else return;
    int slot = atomicAdd(&cursor[d], 1);
    csr_src[slot] = s;
    csr_dst[slot] = d;
}

// ---------- layer-1 scores: ONE per-edge random-gather pass ----------
__global__ void edge_score3(const int* __restrict__ csr_src, const int* __restrict__ csr_dst,
                            const float* __restrict__ es, const float* __restrict__ ed,
                            float4* __restrict__ alpha, int E) {
    int s0 = blockIdx.x * blockDim.x + threadIdx.x;
    if (s0 >= E) return;
    int s = csr_src[s0], d = csr_dst[s0];
    float l0 = leaky(es[s * 3]     + ed[d * 3]);
    float l1 = leaky(es[s * 3 + 1] + ed[d * 3 + 1]);
    float l2 = leaky(es[s * 3 + 2] + ed[d * 3 + 2]);
    alpha[s0] = float4{l0, l1, l2, 0.f};
}
// per-dst softmax over CONTIGUOUS alpha range (no random gathers)
__global__ void seg_norm3(const int* __restrict__ rowptr, float4* __restrict__ alpha, int N) {
    int d = blockIdx.x * blockDim.x + threadIdx.x;
    if (d >= N) return;
    int b = rowptr[d], e = rowptr[d + 1];
    float m0 = -1e30f, m1 = -1e30f, m2 = -1e30f;
    for (int s0 = b; s0 < e; s0++) {
        float4 a = alpha[s0];
        m0 = fmaxf(m0, a.x); m1 = fmaxf(m1, a.y); m2 = fmaxf(m2, a.z);
    }
    float dn0 = 0.f, dn1 = 0.f, dn2 = 0.f;
    for (int s0 = b; s0 < e; s0++) {
        float4 a = alpha[s0];
        float x0 = expf(a.x - m0), x1 = expf(a.y - m1), x2 = expf(a.z - m2);
        dn0 += x0; dn1 += x1; dn2 += x2;
        alpha[s0] = float4{x0, x1, x2, 0.f};
    }
    float i0 = 1.f / (dn0 + 1e-16f), i1 = 1.f / (dn1 + 1e-16f), i2 = 1.f / (dn2 + 1e-16f);
    for (int s0 = b; s0 < e; s0++) {
        float4 a = alpha[s0];
        a.x *= i0; a.y *= i1; a.z *= i2;
        alpha[s0] = a;
    }
}

// ---------- layer-2 coefs (1 head; es2 tiny, L2-resident) ----------
__global__ void csr_maxden_alpha1(const int* __restrict__ rowptr, const int* __restrict__ csr_src,
                                  const float* __restrict__ es, const float* __restrict__ ed,
                                  float* __restrict__ alpha, int N) {
    int d = blockIdx.x * blockDim.x + threadIdx.x;
    if (d >= N) return;
    float edv = ed[d];
    int b = rowptr[d], e = rowptr[d + 1];
    float mm = -1e30f;
    for (int s0 = b; s0 < e; s0++) {
        int s = csr_src[s0];
        mm = fmaxf(mm, leaky(es[s] + edv));
    }
    float dn = 0.f;
    for (int s0 = b; s0 < e; s0++) {
        int s = csr_src[s0];
        float ex = expf(leaky(es[s] + edv) - mm);
        dn += ex;
        alpha[s0] = ex;
    }
    float inv = 1.f / (dn + 1e-16f);
    for (int s0 = b; s0 < e; s0++) alpha[s0] *= inv;
}

// ---------- layer-1 aggregate (bf16 h1) + bias + ELU + (row @ W2) + layer-2 coef ----------
// r6 version: depth-4 group pipeline, 128 threads, 12 row-loads in flight/thread.
// r7 proved the pipeline IS the MLP (plain loop regressed 111->145us). FROZEN.
__global__ __launch_bounds__(128) void csr_agg1_fused(
    const int* __restrict__ rowptr, const int* __restrict__ csr_src,
    const float4* __restrict__ alpha,
    const unsigned short* __restrict__ h1, const float* __restrict__ b1,
    const float* __restrict__ W2, float* __restrict__ h2,
    const float* __restrict__ as2, const float* __restrict__ ad2,
    float* __restrict__ es2, float* __restrict__ ed2, int N)
{
    int d = blockIdx.x;
    int t = threadIdx.x;
    __shared__ float row[HC1];
    __shared__ float part[128][OUTC + 1];

    int b = rowptr[d], e = rowptr[d + 1];
    float a0 = 0.f, a1 = 0.f, a2 = 0.f;

#define LOADG(g, I, A)                                                        \
    do {                                                                      \
        int base_ = b + (g) * 4;                                              \
        _Pragma("unroll")                                                     \
        for (int j = 0; j < 4; j++) {                                         \
            int s0_ = base_ + j;                                              \
            bool v_ = s0_ < e;                                                \
            int sc_ = v_ ? s0_ : (e - 1);                                     \
            I[j] = csr_src[sc_];                                              \
            float4 t4_ = alpha[sc_];                                          \
            if (!v_) { t4_.x = 0.f; t4_.y = 0.f; t4_.z = 0.f; }               \
            A[j] = t4_;                                                       \
        }                                                                     \
    } while (0)

    int ng = (e - b + 3) >> 2;
    int   iN[4]; float4 aN[4];
    LOADG(0, iN, aN);
    float rc[12]; float4 aC[4];
#pragma unroll
    for (int j = 0; j < 4; j++) {
        const unsigned short* hp = h1 + (long)iN[j] * HC1;
        rc[3 * j] = bf16f(hp[t]); rc[3 * j + 1] = bf16f(hp[t + 128]); rc[3 * j + 2] = bf16f(hp[t + 256]);
        aC[j] = aN[j];
    }
    LOADG(1, iN, aN);
    for (int g = 1; g < ng; g++) {
        float rn[12];
#pragma unroll
        for (int j = 0; j < 4; j++) {
            const unsigned short* hp = h1 + (long)iN[j] * HC1;
            rn[3 * j] = bf16f(hp[t]); rn[3 * j + 1] = bf16f(hp[t + 128]); rn[3 * j + 2] = bf16f(hp[t + 256]);
        }
        int iT[4]; float4 aT[4];
        LOADG(g + 1, iT, aT);
#pragma unroll
        for (int j = 0; j < 4; j++) {
            a0 = fmaf(rc[3 * j],     aC[j].x, a0);
            a1 = fmaf(rc[3 * j + 1], aC[j].y, a1);
            a2 = fmaf(rc[3 * j + 2], aC[j].z, a2);
        }
#pragma unroll
        for (int j = 0; j < 12; j++) rc[j] = rn[j];
#pragma unroll
        for (int j = 0; j < 4; j++) { aC[j] = aN[j]; iN[j] = iT[j]; aN[j] = aT[j]; }
    }
#pragma unroll
    for (int j = 0; j < 4; j++) {
        a0 = fmaf(rc[3 * j],     aC[j].x, a0);
        a1 = fmaf(rc[3 * j + 1], aC[j].y, a1);
        a2 = fmaf(rc[3 * j + 2], aC[j].z, a2);
    }
#undef LOADG

    float v;
    v = a0 + b1[t];       row[t]       = v > 0.f ? v : expf(v) - 1.f;
    v = a1 + b1[t + 128]; row[t + 128] = v > 0.f ? v : expf(v) - 1.f;
    v = a2 + b1[t + 256]; row[t + 256] = v > 0.f ? v : expf(v) - 1.f;
    __syncthreads();

    float pc[OUTC];
#pragma unroll
    for (int c = 0; c < OUTC; c++) pc[c] = 0.f;
    for (int k = t; k < HC1; k += 128) {
        float rv = row[k];
        const float* wp = W2 + (long)k * OUTC;
#pragma unroll
        for (int c = 0; c < OUTC; c++) pc[c] = fmaf(rv, wp[c], pc[c]);
    }
#pragma unroll
    for (int c = 0; c < OUTC; c++) part[t][c] = pc[c];
    __syncthreads();
    for (int off = 64; off > 0; off >>= 1) {
        if (t < off) {
#pragma unroll
            for (int c = 0; c < OUTC; c++) part[t][c] += part[t + off][c];
        }
        __syncthreads();
    }
    if (t < OUTC) h2[(long)d * OUTC + t] = part[0][t];
    if (t == 0) {
        float s = 0.f, dd = 0.f;
#pragma unroll
        for (int c = 0; c < OUTC; c++) {
            float hv = part[0][c];
            s  = fmaf(hv, as2[c], s);
            dd = fmaf(hv, ad2[c], dd);
        }
        es2[d] = s; ed2[d] = dd;
    }
}

// ---------- layer-2 aggregate + bias -> padded emb (stride 12) ----------
__global__ void csr_agg2(const int* __restrict__ rowptr, const int* __restrict__ csr_src,
                         const float* __restrict__ alpha,
                         const float* __restrict__ h2, const float* __restrict__ b2,
                         float* __restrict__ emb, int N)
{
    int idx = blockIdx.x * blockDim.x + threadIdx.x;
    if (idx >= N * EMBS) return;
    int d = idx / EMBS, c = idx - d * EMBS;
    if (c >= OUTC) { emb[idx] = 0.f; return; }
    int b = rowptr[d], e = rowptr[d + 1];
    float acc = 0.f;
    for (int s0 = b; s0 < e; s0++) {
        int s = csr_src[s0];
        acc = fmaf(h2[(long)s * OUTC + c], alpha[s0], acc);
    }
    emb[idx] = acc + b2[c];
}

// ---------- pair scores (padded emb: 3 float4 loads per row) ----------
__global__ void pair_score(const int* __restrict__ pairs, const float* __restrict__ emb,
                           float* __restrict__ out, int P) {
    int p = blockIdx.x * blockDim.x + threadIdx.x;
    if (p >= P) return;
    int i0 = pairs[2 * p], i1 = pairs[2 * p + 1];
    const float4* a = (const float4*)(emb + (long)i0 * EMBS);
    const float4* b = (const float4*)(emb + (long)i1 * EMBS);
    float4 a0 = a[0], a1 = a[1], a2 = a[2];
    float4 b0 = b[0], b1 = b[1], b2 = b[2];
    float s = a0.x*b0.x + a0.y*b0.y + a0.z*b0.z + a0.w*b0.w
            + a1.x*b1.x + a1.y*b1.y + a1.z*b1.z + a1.w*b1.w
            + a2.x*b2.x + a2.y*b2.y;
    out[p] = s;
}

extern "C" void kernel_launch(void* const* d_in, const int* in_sizes, int n_in,
                              void* d_out, int out_size, void* d_ws, size_t ws_size,
                              hipStream_t stream) {
    const float* fsub = (const float*)d_in[0];
    const float* fcom = (const float*)d_in[1];
    float*       x    = (float*)d_in[2];
    const int*   com  = (const int*)d_in[3];
    const int*   ei   = (const int*)d_in[4];
    const int*   pidx = (const int*)d_in[5];
    const float* Wq = (const float*)d_in[6];  const float* bq = (const float*)d_in[7];
    const float* Wk = (const float*)d_in[8];  const float* bk = (const float*)d_in[9];
    const float* Wv = (const float*)d_in[10]; const float* bv = (const float*)d_in[11];
    const float* Wf = (const float*)d_in[12]; const float* bf = (const float*)d_in[13];
    const float* W1 = (const float*)d_in[14];
    const float* as1 = (const float*)d_in[15]; const float* ad1 = (const float*)d_in[16];
    const float* b1 = (const float*)d_in[17];
    const float* W2 = (const float*)d_in[18];
    const float* as2 = (const float*)d_in[19]; const float* ad2 = (const float*)d_in[20];
    const float* b2 = (const float*)d_in[21];
    float* out = (float*)d_out;

    const int* src = ei;
    const int* dst = ei + NE;

    typedef unsigned short u16;
    char* ws = (char*)d_ws;
    float* S     = (float*)(ws + 0);            // dead after softmax
    u16*   SH    = (u16*)(ws + 67108864);       // dead after S@v
    u16*   SL    = (u16*)(ws + 100663296);      // unused now (kept for layout)
    u16*   fsubH = (u16*)(ws + 134217728);      // dead after q proj
    u16*   fsubL = (u16*)(ws + 136839168);
    u16*   fcomH = (u16*)(ws + 139460608);      // dead after k,v proj
    u16*   fcomL = (u16*)(ws + 142082048);
    u16*   qH    = (u16*)(ws + 144703488);      // dead after S gemm
    u16*   qL    = (u16*)(ws + 147324928);
    u16*   kH    = (u16*)(ws + 149946368);
    u16*   kL    = (u16*)(ws + 152567808);
    u16*   vTH   = (u16*)(ws + 155189248);      // dead after S@v
    u16*   vTL   = (u16*)(ws + 157646848);
    u16*   attnH = (u16*)(ws + 160104448);      // dead after fus gemm
    u16*   attnL = (u16*)(ws + 162725888);
    u16*   WqTH  = (u16*)(ws + 165347328);
    u16*   WqTL  = (u16*)(ws + 165539328);
    u16*   WkTH  = (u16*)(ws + 165731328);
    u16*   WkTL  = (u16*)(ws + 165923328);
    u16*   WvTH  = (u16*)(ws + 166115328);
    u16*   WvTL  = (u16*)(ws + 166307328);
    u16*   WfTH  = (u16*)(ws + 166499328);
    u16*   WfTL  = (u16*)(ws + 166691328);
    u16*   W1TH  = (u16*)(ws + 166883328);
    u16*   W1TL  = (u16*)(ws + 167129088);
    float* fus   = (float*)(ws + 167374848);    // alive until scatter
    float* es1   = (float*)(ws + 172290048);
    float* ed1   = (float*)(ws + 172890048);
    float* es2   = (float*)(ws + 174690048);
    float* ed2   = (float*)(ws + 174890048);
    float* h2    = (float*)(ws + 175490048);
    int*   last  = (int*)(ws + 179490048);
    int*   deg   = (int*)(ws + 179690048);
    int*   curs  = (int*)(ws + 179890048);
    int*   rowp  = (int*)(ws + 180090048);
    int*   csrc  = (int*)(ws + 180290064);      // ends 182,490,064
    int*   bsum  = (int*)(ws + 182490112);      // 196 ints
    // overlays (disjoint in time):
    float* part   = (float*)(ws + 0);           // over dead S (S@v phase), 4 slices
    u16*   h1b    = (u16*)(ws + 0);             // bf16 h1 over dead S/SH (GAT phase), 38.4MB
    u16*   xH     = (u16*)(ws + 76800000);      // over dead SH-tail/SL; dead after h1 gemm
    u16*   xL     = (u16*)(ws + 108800000);
    float* alpha1 = (float*)(ws + 134217728);   // over dead fsubH.. (GAT phase), 8.8MB
    float* alpha2 = (float*)(ws + 144703488);   // over dead qH (GAT phase), 2.2MB -> ends 146,903,488
    int*   csrd   = (int*)(ws + 160104448);     // over dead attnH (CSR phase on), 2.2MB
    float* embp   = (float*)(ws + 147324928);   // over dead qL/kH, 2.4MB -> ends 149,724,928

    const float inv_sqrt_d = 1.0f / sqrtf((float)FEAT);

    // ===== 0. conversions (batched) =====
    {
        long tot5 = 4L * FEAT * KP + (long)HC1 * KP;   // 506,880
        hipLaunchKernelGGL(convT_pad5, dim3(cdiv((int)tot5, 256)), dim3(256), 0, stream,
                           Wq, Wk, Wv, Wf, W1,
                           WqTH, WqTL, WkTH, WkTL, WvTH, WvTL, WfTH, WfTL, W1TH, W1TL);
    }
    hipLaunchKernelGGL(conv_pad8_2, dim3(cdiv(2*BP*(KP/8),256)), dim3(256), 0, stream,
                       fsub, fcom, fsubH, fsubL, fcomH, fcomL);
    hipMemsetAsync(qH, 0, 10485760, stream);   // zero q/k hi+lo (incl. K-tail cols 300..319)

    // ===== 1. cross attention =====
    // small-N projections: 64x64 tile (320 blocks; gl128's 96 blocks was -34us, r8)
    hipLaunchKernelGGL((gemm_bf<1>), dim3(cdiv(FEAT,64), cdiv(BP,64)), dim3(256), 0, stream,
                       fsubH, fsubL, KP, WqTH, WqTL, KP, bq, nullptr, nullptr, qH, qL,
                       BP, FEAT, FEAT, 1.0f, KP);
    hipLaunchKernelGGL((gemm_bf<1>), dim3(cdiv(FEAT,64), cdiv(BP,64)), dim3(256), 0, stream,
                       fcomH, fcomL, KP, WkTH, WkTL, KP, bk, nullptr, nullptr, kH, kL,
                       BP, FEAT, FEAT, 1.0f, KP);
    hipLaunchKernelGGL((gemm_bf<2>), dim3(cdiv(FEAT,64), cdiv(BP,64)), dim3(256), 0, stream,
                       fcomH, fcomL, KP, WvTH, WvTL, KP, bv, nullptr, nullptr, vTH, vTL,
                       BP, FEAT, FEAT, 1.0f, BP);
    // S = (q @ k^T) * inv_sqrt_d  — SINGLE-bf16 (error ~1e-4 on output, see analysis)
    hipLaunchKernelGGL((gemm_gl64k<false>), dim3(cdiv(BP,128), cdiv(BP,128)), dim3(256), 0, stream,
                       qH, KP, kH, KP, S, BP, BP, FEAT, inv_sqrt_d, 0);
    hipLaunchKernelGGL(softmax_h, dim3(BP), dim3(256), 0, stream, S, SH);
    // part[z] = S_z @ v — SINGLE-bf16, split-K 4x1024
    hipLaunchKernelGGL((gemm_gl64k<true>), dim3(cdiv(FEAT,128), cdiv(BP,128), 4), dim3(256), 0, stream,
                       SH, BP, vTH, BP, part, BP, FEAT, BP, 1.0f, 1024);
    hipLaunchKernelGGL(splitk_reduce8, dim3(cdiv(BP*(KP/8),256)), dim3(256), 0, stream,
                       part, fsub, attnH, attnL, BP, FEAT, KP, 4);
    hipLaunchKernelGGL((gemm_bf<0>), dim3(cdiv(FEAT,64), cdiv(BP,64)), dim3(256), 0, stream,
                       attnH, attnL, KP, WfTH, WfTL, KP, bf, nullptr, fus, nullptr, nullptr,
                       BP, FEAT, FEAT, 1.0f, FEAT);

    // ===== 2. convert pristine x, then scatter fused rows directly as bf16 =====
    hipLaunchKernelGGL(conv_pad8, dim3(cdiv((long)NN*(KP/8),256)), dim3(256), 0, stream, x, xH, xL, NN, FEAT, KP);
    hipLaunchKernelGGL(scatter_init, dim3(cdiv(BP,256)), dim3(256), 0, stream, last, com, BP);
    hipLaunchKernelGGL(scatter_max,  dim3(cdiv(BP,256)), dim3(256), 0, stream, last, com, BP);
    hipLaunchKernelGGL(scatter_write_hl, dim3(BP), dim3(128), 0, stream, last, com, fus, xH, xL, BP);

    // ===== 3. CSR build =====
    hipMemsetAsync(deg, 0, NN * sizeof(int), stream);
    hipLaunchKernelGGL(deg_count, dim3(cdiv(NE,256)), dim3(256), 0, stream, dst, deg, NE);
    {
        int nb = cdiv(NN, 256);   // 196
        hipLaunchKernelGGL(scan_part,  dim3(nb), dim3(256), 0, stream, deg, bsum, NN);
        hipLaunchKernelGGL(scan_bsum,  dim3(1),  dim3(256), 0, stream, bsum, nb);
        hipLaunchKernelGGL(scan_final, dim3(nb), dim3(256), 0, stream, deg, bsum, rowp, curs, NN);
    }
    hipLaunchKernelGGL(csr_fill_all, dim3(cdiv(TOTE,256)), dim3(256), 0, stream,
                       src, dst, curs, csrc, csrd);

    // ===== 4. GAT layer 1 (h1 in bf16: gather working set 38.4 MB) =====
    hipLaunchKernelGGL((gemm_gl128<false, 1>), dim3(cdiv(HC1,128), cdiv(NN,128)), dim3(256), 0, stream,
                       xH, (long)(xL - xH), KP, W1TH, (long)(W1TL - W1TH), KP,
                       nullptr, h1b, NN, HC1, FEAT, 1.0f, 0);
    hipLaunchKernelGGL(node_attn_coef3, dim3(cdiv(NN,4)), dim3(256), 0, stream,
                       h1b, as1, ad1, es1, ed1, NN);
    hipLaunchKernelGGL(edge_score3, dim3(cdiv(TOTE,256)), dim3(256), 0, stream,
                       csrc, csrd, es1, ed1, (float4*)alpha1, TOTE);
    hipLaunchKernelGGL(seg_norm3, dim3(cdiv(NN,256)), dim3(256), 0, stream,
                       rowp, (float4*)alpha1, NN);
    hipLaunchKernelGGL(csr_agg1_fused, dim3(NN), dim3(128), 0, stream,
                       rowp, csrc, (const float4*)alpha1, h1b, b1, W2, h2, as2, ad2, es2, ed2, NN);

    // ===== 5. GAT layer 2 =====
    hipLaunchKernelGGL(csr_maxden_alpha1, dim3(cdiv(NN,256)), dim3(256), 0, stream,
                       rowp, csrc, es2, ed2, alpha2, NN);
    hipLaunchKernelGGL(csr_agg2, dim3(cdiv(NN*EMBS,256)), dim3(256), 0, stream,
                       rowp, csrc, alpha2, h2, b2, embp, NN);

    // ===== 6. pair scores =====
    hipLaunchKernelGGL(pair_score, dim3(cdiv(NP,256)), dim3(256), 0, stream, pidx, embp, out, NP);
}

// Round 11
// 591.687 us; speedup vs baseline: 1.2936x; 1.0979x over previous
//
#include <hip/hip_runtime.h>
#include <math.h>

#define NN      50000      // N_NODES
#define BP      4096       // N_PAIRS_MAP
#define NE      500000     // N_EDGES
#define NP      1000000    // N_SCORE_PAIRS
#define FEAT    300
#define KP      320        // FEAT padded to multiple of 32
#define HID     128
#define HEADS   3
#define OUTC    10
#define HC1     (HEADS*HID)   // 384
#define EMBS    12            // embp row stride (floats, 48B = 16B-aligned)
#define TOTE    (NE+NN)       // CSR slots incl. self-loops
#define NEG_SLOPE 0.2f

static inline int cdiv(int a, int b) { return (a + b - 1) / b; }

using bfrag = __attribute__((ext_vector_type(8))) short;
using ffrag = __attribute__((ext_vector_type(4))) float;

__device__ inline float leaky(float x) { return x > 0.f ? x : NEG_SLOPE * x; }
__device__ inline unsigned short bf16_rne(float f) {
    unsigned u = __float_as_uint(f);
    unsigned r = u + 0x7FFFu + ((u >> 16) & 1u);
    return (unsigned short)(r >> 16);
}
__device__ inline float bf16f(unsigned short h) { return __uint_as_float(((unsigned)h) << 16); }
// packed-uint bf16 pair -> floats (1 VALU op each)
__device__ inline float bf16lo(unsigned u) { return __uint_as_float(u << 16); }
__device__ inline float bf16hi(unsigned u) { return __uint_as_float(u & 0xffff0000u); }

__device__ __forceinline__ void gload_lds16(const unsigned short* g, unsigned short* l) {
    __builtin_amdgcn_global_load_lds((const __attribute__((address_space(1))) void*)g,
                                     (__attribute__((address_space(3))) void*)l, 16, 0, 0);
}

// fp32 [M][K] -> bf16 hi/lo [M][Kp]; 8 elems/thread, uint4 stores (G13)
__global__ void conv_pad8(const float* __restrict__ in, unsigned short* __restrict__ H,
                          unsigned short* __restrict__ L, long M, int K, int Kp) {
    long idx = (long)blockIdx.x * blockDim.x + threadIdx.x;
    int cpk = Kp >> 3;
    long total = M * cpk;
    if (idx >= total) return;
    int chunk = (int)(idx % cpk);
    long row = idx / cpk;
    int k0 = chunk * 8;
    const float* ip = in + row * K;
    float v[8];
    if (k0 + 8 <= K) {
        float4 a = *(const float4*)(ip + k0);
        float4 b = *(const float4*)(ip + k0 + 4);
        v[0]=a.x; v[1]=a.y; v[2]=a.z; v[3]=a.w; v[4]=b.x; v[5]=b.y; v[6]=b.z; v[7]=b.w;
    } else {
#pragma unroll
        for (int j = 0; j < 8; j++) { int k = k0 + j; v[j] = (k < K) ? ip[k] : 0.f; }
    }
    unsigned short hs[8], ls[8];
#pragma unroll
    for (int j = 0; j < 8; j++) {
        unsigned short h = bf16_rne(v[j]);
        hs[j] = h; ls[j] = bf16_rne(v[j] - bf16f(h));
    }
    long o = row * Kp + k0;
    *(uint4*)&H[o] = *(const uint4*)hs;
    *(uint4*)&L[o] = *(const uint4*)ls;
}

// fsub + fcom in one launch, HI ONLY (lo buffers are dead: q/k/v are single-bf16 now)
__global__ void conv_pad8_2h(const float* __restrict__ inA, const float* __restrict__ inB,
                             unsigned short* __restrict__ HA, unsigned short* __restrict__ HB) {
    long idx = (long)blockIdx.x * blockDim.x + threadIdx.x;
    int cpk = KP >> 3;
    long total = 2L * BP * cpk;
    if (idx >= total) return;
    int chunk = (int)(idx % cpk);
    long row = idx / cpk;
    const float* in; unsigned short* H;
    if (row < BP) { in = inA; H = HA; }
    else          { in = inB; H = HB; row -= BP; }
    int k0 = chunk * 8;
    const float* ip = in + row * FEAT;
    float v[8];
    if (k0 + 8 <= FEAT) {
        float4 a = *(const float4*)(ip + k0);
        float4 b = *(const float4*)(ip + k0 + 4);
        v[0]=a.x; v[1]=a.y; v[2]=a.z; v[3]=a.w; v[4]=b.x; v[5]=b.y; v[6]=b.z; v[7]=b.w;
    } else {
#pragma unroll
        for (int j = 0; j < 8; j++) { int k = k0 + j; v[j] = (k < FEAT) ? ip[k] : 0.f; }
    }
    unsigned short hs[8];
#pragma unroll
    for (int j = 0; j < 8; j++) hs[j] = bf16_rne(v[j]);
    *(uint4*)&H[row * KP + k0] = *(const uint4*)hs;
}

// all 5 weight transposes in ONE launch. W0..W3: [300][300]; W4: [300][384].
__global__ void convT_pad5(
    const float* __restrict__ s0, const float* __restrict__ s1, const float* __restrict__ s2,
    const float* __restrict__ s3, const float* __restrict__ s4,
    unsigned short* __restrict__ h0, unsigned short* __restrict__ l0,
    unsigned short* __restrict__ h1, unsigned short* __restrict__ l1,
    unsigned short* __restrict__ h2, unsigned short* __restrict__ l2,
    unsigned short* __restrict__ h3, unsigned short* __restrict__ l3,
    unsigned short* __restrict__ h4, unsigned short* __restrict__ l4)
{
    long idx = (long)blockIdx.x * blockDim.x + threadIdx.x;
    const long R = (long)FEAT * KP;          // 96000 per square weight
    const float* src; unsigned short *H, *L; int N; long off;
    if (idx < 4 * R) {
        int m = (int)(idx / R); off = idx - (long)m * R; N = FEAT;
        src = (m == 0) ? s0 : (m == 1) ? s1 : (m == 2) ? s2 : s3;
        H   = (m == 0) ? h0 : (m == 1) ? h1 : (m == 2) ? h2 : h3;
        L   = (m == 0) ? l0 : (m == 1) ? l1 : (m == 2) ? l2 : l3;
    } else if (idx < 4 * R + (long)HC1 * KP) {
        off = idx - 4 * R; N = HC1; src = s4; H = h4; L = l4;
    } else return;
    int k = (int)(off % KP);
    long n = off / KP;
    float f = (k < FEAT) ? src[(long)k * N + n] : 0.f;
    unsigned short h = bf16_rne(f);
    H[off] = h;
    L[off] = bf16_rne(f - bf16f(h));
}

// ================== SINGLE-bf16 GEMM (64x64 tile, LDS-staged) ==================
// For q/k/v projections (M=4096, N=300 -> 320 blocks; occupancy per r8 lesson).
// Inputs hi-only; 4 MFMA + 2 LDS stages per K-step (vs split's 12 + 4).
// MODE: 1 = hi out + bias row-major (q,k); 2 = transposed hi out + bias (v).
template <int MODE>
__global__ __launch_bounds__(256) void gemm_bf1(
    const unsigned short* __restrict__ Ah, int lda,
    const unsigned short* __restrict__ Bh, int ldb,
    const float* __restrict__ bias, unsigned short* __restrict__ H0,
    int M, int N, int K, int ldo)
{
    __shared__ __align__(16) unsigned short Ahs[4][64][8];
    __shared__ __align__(16) unsigned short Bhs[4][64][8];
    int t = threadIdx.x, w = t >> 6, l = t & 63, lrow = l & 15, lq = l >> 4;
    int rowBase = blockIdx.y * 64, colBase = blockIdx.x * 64;
    int Kr = (K + 31) & ~31;

    int arow = min(rowBase + l, M - 1);
    int brow = min(colBase + l, N - 1);
    const unsigned short* ga_h = Ah + (long)arow * lda + w * 8;
    const unsigned short* gb_h = Bh + (long)brow * ldb + w * 8;

    ffrag acc[4] = {{0.f,0.f,0.f,0.f},{0.f,0.f,0.f,0.f},{0.f,0.f,0.f,0.f},{0.f,0.f,0.f,0.f}};

    for (int k0 = 0; k0 < Kr; k0 += 32) {
        *(uint4*)&Ahs[w][l][0] = *(const uint4*)(ga_h + k0);
        *(uint4*)&Bhs[w][l][0] = *(const uint4*)(gb_h + k0);
        __syncthreads();
        bfrag ah = *(const bfrag*)&Ahs[lq][w * 16 + lrow][0];
#pragma unroll
        for (int ct = 0; ct < 4; ct++) {
            bfrag bh = *(const bfrag*)&Bhs[lq][ct * 16 + lrow][0];
            acc[ct] = __builtin_amdgcn_mfma_f32_16x16x32_bf16(ah, bh, acc[ct], 0, 0, 0);
        }
        __syncthreads();
    }

#pragma unroll
    for (int ct = 0; ct < 4; ct++) {
        int gc = colBase + ct * 16 + lrow;
        if (gc >= N) continue;
#pragma unroll
        for (int r = 0; r < 4; r++) {
            int gr = rowBase + w * 16 + lq * 4 + r;
            if (gr >= M) continue;
            float o = acc[ct][r] + bias[gc];
            if (MODE == 1) H0[(long)gr * ldo + gc] = bf16_rne(o);
            else           H0[(long)gc * ldo + gr] = bf16_rne(o);
        }
    }
}

// ================== split-bf16 MFMA GEMM (64x64 tile) — fus only ==================
template <int MODE>
__global__ __launch_bounds__(256) void gemm_bf(
    const unsigned short* __restrict__ Ah, const unsigned short* __restrict__ Al, int lda,
    const unsigned short* __restrict__ Bh, const unsigned short* __restrict__ Bl, int ldb,
    const float* __restrict__ bias, const float* __restrict__ addsrc,
    float* __restrict__ C0, unsigned short* __restrict__ H0, unsigned short* __restrict__ L0,
    int M, int N, int K, float scale, int ldo)
{
    __shared__ __align__(16) unsigned short Ahs[4][64][8], Als[4][64][8];
    __shared__ __align__(16) unsigned short Bhs[4][64][8], Bls[4][64][8];
    int t = threadIdx.x, w = t >> 6, l = t & 63, lrow = l & 15, lq = l >> 4;
    int rowBase = blockIdx.y * 64, colBase = blockIdx.x * 64;
    int Kr = (K + 31) & ~31;

    int arow = min(rowBase + l, M - 1);
    int brow = min(colBase + l, N - 1);
    const unsigned short* ga_h = Ah + (long)arow * lda + w * 8;
    const unsigned short* ga_l = Al + (long)arow * lda + w * 8;
    const unsigned short* gb_h = Bh + (long)brow * ldb + w * 8;
    const unsigned short* gb_l = Bl + (long)brow * ldb + w * 8;

    ffrag acc[4] = {{0.f,0.f,0.f,0.f},{0.f,0.f,0.f,0.f},{0.f,0.f,0.f,0.f},{0.f,0.f,0.f,0.f}};

    for (int k0 = 0; k0 < Kr; k0 += 32) {
        *(uint4*)&Ahs[w][l][0] = *(const uint4*)(ga_h + k0);
        *(uint4*)&Als[w][l][0] = *(const uint4*)(ga_l + k0);
        *(uint4*)&Bhs[w][l][0] = *(const uint4*)(gb_h + k0);
        *(uint4*)&Bls[w][l][0] = *(const uint4*)(gb_l + k0);
        __syncthreads();
        bfrag ah  = *(const bfrag*)&Ahs[lq][w * 16 + lrow][0];
        bfrag alo = *(const bfrag*)&Als[lq][w * 16 + lrow][0];
#pragma unroll
        for (int ct = 0; ct < 4; ct++) {
            bfrag bh = *(const bfrag*)&Bhs[lq][ct * 16 + lrow][0];
            bfrag bl = *(const bfrag*)&Bls[lq][ct * 16 + lrow][0];
            acc[ct] = __builtin_amdgcn_mfma_f32_16x16x32_bf16(ah,  bh, acc[ct], 0, 0, 0);
            acc[ct] = __builtin_amdgcn_mfma_f32_16x16x32_bf16(ah,  bl, acc[ct], 0, 0, 0);
            acc[ct] = __builtin_amdgcn_mfma_f32_16x16x32_bf16(alo, bh, acc[ct], 0, 0, 0);
        }
        __syncthreads();
    }

#pragma unroll
    for (int ct = 0; ct < 4; ct++) {
        int gc = colBase + ct * 16 + lrow;
        if (gc >= N) continue;
#pragma unroll
        for (int r = 0; r < 4; r++) {
            int gr = rowBase + w * 16 + lq * 4 + r;
            if (gr >= M) continue;
            float v = acc[ct][r];
            if (MODE == 0) {
                float o = v * scale;
                if (bias) o += bias[gc];
                if (addsrc) o += addsrc[(long)gr * ldo + gc];
                C0[(long)gr * ldo + gc] = o;
            } else if (MODE == 1) {
                float o = v + bias[gc];
                unsigned short h = bf16_rne(o);
                H0[(long)gr * ldo + gc] = h;
                L0[(long)gr * ldo + gc] = bf16_rne(o - bf16f(h));
            } else {
                float o = v + bias[gc];
                unsigned short h = bf16_rne(o);
                H0[(long)gc * ldo + gr] = h;
                L0[(long)gc * ldo + gr] = bf16_rne(o - bf16f(h));
            }
        }
    }
}

// ================== SINGLE-bf16 GEMM, 128x128 tile, 64-k LDS rows ==================
// gl-staged; each 128-B LDS row holds 64 contiguous k. Per 64-k: 8 gloads,
// 16 ds_read_b128, 32 MFMA. Used for S, S@v (validated r10) and now h1.
// OUT: 0 = f32 out (acc*scale), 1 = bf16 (RNE) out.
template <bool SPLITK, int OUT>
__global__ __launch_bounds__(256) void gemm_gl64k(
    const unsigned short* __restrict__ Ah, int lda,
    const unsigned short* __restrict__ Bh, int ldb,
    float* __restrict__ C0, unsigned short* __restrict__ Hb,
    int M, int N, int K, float scale, int KC)
{
    __shared__ __align__(16) unsigned short As[128][64];
    __shared__ __align__(16) unsigned short Bs[128][64];
    int t = threadIdx.x, w = t >> 6, l = t & 63, lrow = l & 15, lq = l >> 4;
    int wr = w >> 1, wc = w & 1;
    int rowBase = blockIdx.y * 128, colBase = blockIdx.x * 128;
    int Kr = (K + 63) & ~63;
    int kbeg = SPLITK ? blockIdx.z * KC : 0;
    int kend = SPLITK ? min(Kr, kbeg + KC) : Kr;

    bool isA = (w < 2);
    const unsigned short* Mb = isA ? Ah : Bh;
    int ld   = isA ? lda : ldb;
    int mx   = (isA ? M : N) - 1;
    int rb0  = (isA ? rowBase : colBase) + (w & 1) * 64;
    int lr8  = l >> 3;
    int lg   = (l & 7) ^ lr8;           // logical k-chunk (0..7) this lane fetches
    long lane_off = (long)lg * 8;       // k-offset in elements
    const unsigned short* gp[8];
#pragma unroll
    for (int i = 0; i < 8; i++) {
        int r = rb0 + i * 8 + lr8;
        gp[i] = Mb + (long)min(r, mx) * ld + lane_off;
    }
    unsigned short* ldst[8];
    {
        unsigned short (*T)[64] = isA ? As : Bs;
#pragma unroll
        for (int i = 0; i < 8; i++) ldst[i] = &T[(w & 1) * 64 + i * 8][0];
    }

    ffrag acc[4][4];
#pragma unroll
    for (int m = 0; m < 4; m++)
#pragma unroll
        for (int n = 0; n < 4; n++) acc[m][n] = ffrag{0.f, 0.f, 0.f, 0.f};

    int arow0 = wr * 64 + lrow, brow0 = wc * 64 + lrow;
    int xr = lrow & 7;
    int sk0 = ((lq    ) ^ xr) * 8;   // physical slot of logical chunk lq   (k 0..31)
    int sk1 = ((lq + 4) ^ xr) * 8;   // physical slot of logical chunk lq+4 (k 32..63)

    for (int k0 = kbeg; k0 < kend; k0 += 64) {
#pragma unroll
        for (int i = 0; i < 8; i++) gload_lds16(gp[i] + k0, ldst[i]);
        __syncthreads();

        bfrag b0[4], b1[4];
#pragma unroll
        for (int n = 0; n < 4; n++) {
            b0[n] = *(const bfrag*)&Bs[brow0 + n * 16][sk0];
            b1[n] = *(const bfrag*)&Bs[brow0 + n * 16][sk1];
        }
#pragma unroll
        for (int m = 0; m < 4; m++) {
            bfrag a0 = *(const bfrag*)&As[arow0 + m * 16][sk0];
            bfrag a1 = *(const bfrag*)&As[arow0 + m * 16][sk1];
#pragma unroll
            for (int n = 0; n < 4; n++) {
                acc[m][n] = __builtin_amdgcn_mfma_f32_16x16x32_bf16(a0, b0[n], acc[m][n], 0, 0, 0);
                acc[m][n] = __builtin_amdgcn_mfma_f32_16x16x32_bf16(a1, b1[n], acc[m][n], 0, 0, 0);
            }
        }
        __syncthreads();
    }

#pragma unroll
    for (int n = 0; n < 4; n++) {
        int gc = colBase + wc * 64 + n * 16 + lrow;
        if (gc >= N) continue;
#pragma unroll
        for (int m = 0; m < 4; m++) {
#pragma unroll
            for (int r = 0; r < 4; r++) {
                int gr = rowBase + wr * 64 + m * 16 + lq * 4 + r;
                if (gr >= M) continue;
                if (OUT == 0) {
                    float* Cz = SPLITK ? (C0 + (long)blockIdx.z * M * N) : C0;
                    Cz[(long)gr * N + gc] = acc[m][n][r] * scale;
                } else {
                    Hb[(long)gr * N + gc] = bf16_rne(acc[m][n][r]);
                }
            }
        }
    }
}

// ---------- softmax rows of S -> bf16 (hi only) ----------
__global__ __launch_bounds__(256) void softmax_h(const float* __restrict__ S,
                                                 unsigned short* __restrict__ SH) {
    int row = blockIdx.x, tid = threadIdx.x;
    const float* p = S + (long)row * BP + tid * 16;
    float ev[16];
    __shared__ float red[256];
    float m = -1e30f;
#pragma unroll
    for (int i = 0; i < 4; i++) {
        float4 a = *(const float4*)(p + i * 4);
        ev[4*i] = a.x; ev[4*i+1] = a.y; ev[4*i+2] = a.z; ev[4*i+3] = a.w;
        m = fmaxf(m, fmaxf(fmaxf(a.x, a.y), fmaxf(a.z, a.w)));
    }
    red[tid] = m; __syncthreads();
    for (int s = 128; s > 0; s >>= 1) { if (tid < s) red[tid] = fmaxf(red[tid], red[tid + s]); __syncthreads(); }
    m = red[0]; __syncthreads();
    float sum = 0.f;
#pragma unroll
    for (int i = 0; i < 16; i++) { float e = expf(ev[i] - m); ev[i] = e; sum += e; }
    red[tid] = sum; __syncthreads();
    for (int s = 128; s > 0; s >>= 1) { if (tid < s) red[tid] += red[tid + s]; __syncthreads(); }
    float inv = 1.0f / red[0];
    unsigned short hs[16];
#pragma unroll
    for (int i = 0; i < 16; i++) hs[i] = bf16_rne(ev[i] * inv);
    long o = (long)row * BP + tid * 16;
    *(uint4*)&SH[o]     = *(const uint4*)&hs[0];
    *(uint4*)&SH[o + 8] = *(const uint4*)&hs[8];
}

// ---------- split-K reduce + residual -> attn bf16 hi/lo; 8 elems/thread ----------
__global__ void splitk_reduce8(const float* __restrict__ part, const float* __restrict__ resid,
                               unsigned short* __restrict__ H, unsigned short* __restrict__ L,
                               int Mr, int Nc, int Kp2, int sk) {
    long idx = (long)blockIdx.x * blockDim.x + threadIdx.x;
    int cpk = Kp2 >> 3;
    long total = (long)Mr * cpk;
    if (idx >= total) return;
    int chunk = (int)(idx % cpk);
    long row = idx / cpk;
    int c0 = chunk * 8;
    float v[8] = {0.f,0.f,0.f,0.f,0.f,0.f,0.f,0.f};
    if (c0 + 8 <= Nc) {
        long base = row * Nc + c0;
#pragma unroll
        for (int z = 0; z < 8; z++) {
            if (z >= sk) break;
            float4 a = *(const float4*)(part + (long)z * Mr * Nc + base);
            float4 b = *(const float4*)(part + (long)z * Mr * Nc + base + 4);
            v[0]+=a.x; v[1]+=a.y; v[2]+=a.z; v[3]+=a.w; v[4]+=b.x; v[5]+=b.y; v[6]+=b.z; v[7]+=b.w;
        }
        float4 a = *(const float4*)(resid + base);
        float4 b = *(const float4*)(resid + base + 4);
        v[0]+=a.x; v[1]+=a.y; v[2]+=a.z; v[3]+=a.w; v[4]+=b.x; v[5]+=b.y; v[6]+=b.z; v[7]+=b.w;
    } else if (c0 < Nc) {
#pragma unroll
        for (int j = 0; j < 8; j++) {
            int c = c0 + j;
            if (c < Nc) {
                long base = row * Nc + c;
                float s = resid[base];
                for (int z = 0; z < sk; z++) s += part[(long)z * Mr * Nc + base];
                v[j] = s;
            }
        }
    }
    unsigned short hs[8], ls[8];
#pragma unroll
    for (int j = 0; j < 8; j++) {
        unsigned short h = bf16_rne(v[j]);
        hs[j] = h; ls[j] = bf16_rne(v[j] - bf16f(h));
    }
    long o = row * Kp2 + c0;
    *(uint4*)&H[o] = *(const uint4*)hs;
    *(uint4*)&L[o] = *(const uint4*)ls;
}

// ---------- scatter (last write wins), writing bf16 hi/lo x directly ----------
__global__ void scatter_init(int* last, const int* __restrict__ com, int B) {
    int i = blockIdx.x * blockDim.x + threadIdx.x;
    if (i < B) last[com[i]] = -1;
}
__global__ void scatter_max(int* last, const int* __restrict__ com, int B) {
    int i = blockIdx.x * blockDim.x + threadIdx.x;
    if (i < B) atomicMax(&last[com[i]], i);
}
__global__ void scatter_write_hl(const int* __restrict__ last, const int* __restrict__ com,
                                 const float* __restrict__ fused,
                                 unsigned short* __restrict__ xH, unsigned short* __restrict__ xL, int B) {
    int i = blockIdx.x;
    int node = com[i];
    if (last[node] != i) return;
    for (int c = threadIdx.x; c < KP; c += blockDim.x) {
        float f = (c < FEAT) ? fused[(long)i * FEAT + c] : 0.f;
        unsigned short h = bf16_rne(f);
        xH[(long)node * KP + c] = h;
        xL[(long)node * KP + c] = bf16_rne(f - bf16f(h));
    }
}

// ---------- layer-1 coefficients from bf16 h1, wave-per-node, uint-packed ----------
__global__ __launch_bounds__(256) void node_attn_coef3(
    const unsigned short* __restrict__ h1, const float* __restrict__ a_src,
    const float* __restrict__ a_dst, float* __restrict__ es, float* __restrict__ ed, int N)
{
    int w = threadIdx.x >> 6, lane = threadIdx.x & 63;
    int n = blockIdx.x * 4 + w;
    if (n >= N) return;
    const unsigned short* hp = h1 + (long)n * HC1;
    int c = 2 * lane;  // cols c, c+1 within each 128-col head block
    unsigned u0 = *(const unsigned*)&hp[c];
    unsigned u1 = *(const unsigned*)&hp[128 + c];
    unsigned u2 = *(const unsigned*)&hp[256 + c];
    float s0, s1, s2, d0, d1, d2;
    {
        float vl = bf16lo(u0), vh = bf16hi(u0);
        s0 = fmaf(vl, a_src[c], vh * a_src[c + 1]);
        d0 = fmaf(vl, a_dst[c], vh * a_dst[c + 1]);
        vl = bf16lo(u1); vh = bf16hi(u1);
        s1 = fmaf(vl, a_src[128 + c], vh * a_src[128 + c + 1]);
        d1 = fmaf(vl, a_dst[128 + c], vh * a_dst[128 + c + 1]);
        vl = bf16lo(u2); vh = bf16hi(u2);
        s2 = fmaf(vl, a_src[256 + c], vh * a_src[256 + c + 1]);
        d2 = fmaf(vl, a_dst[256 + c], vh * a_dst[256 + c + 1]);
    }
#pragma unroll
    for (int off = 32; off > 0; off >>= 1) {
        s0 += __shfl_down(s0, off); s1 += __shfl_down(s1, off); s2 += __shfl_down(s2, off);
        d0 += __shfl_down(d0, off); d1 += __shfl_down(d1, off); d2 += __shfl_down(d2, off);
    }
    if (lane == 0) {
        es[n * 3 + 0] = s0; es[n * 3 + 1] = s1; es[n * 3 + 2] = s2;
        ed[n * 3 + 0] = d0; ed[n * 3 + 1] = d1; ed[n * 3 + 2] = d2;
    }
}

// ================== CSR build ==================
// deg zeroed by hipMemsetAsync; scan reads deg[i]+1 (self-loop folded in).
__global__ void deg_count(const int* __restrict__ dst, int* deg, int E) {
    int e = blockIdx.x * blockDim.x + threadIdx.x;
    if (e < E) atomicAdd(&deg[dst[e]], 1);
}
__global__ void scan_part(const int* __restrict__ deg, int* __restrict__ bsum, int n) {
    __shared__ int red[256];
    int tid = threadIdx.x;
    int i = blockIdx.x * 256 + tid;
    red[tid] = (i < n) ? deg[i] + 1 : 0;
    __syncthreads();
    for (int s = 128; s > 0; s >>= 1) { if (tid < s) red[tid] += red[tid + s]; __syncthreads(); }
    if (tid == 0) bsum[blockIdx.x] = red[0];
}
__global__ __launch_bounds__(256) void scan_bsum(int* __restrict__ bsum, int nb) {
    __shared__ int tmp[256];
    int tid = threadIdx.x;
    int v = (tid < nb) ? bsum[tid] : 0;
    tmp[tid] = v; __syncthreads();
    for (int off = 1; off < 256; off <<= 1) {
        int t2 = (tid >= off) ? tmp[tid - off] : 0;
        __syncthreads();
        tmp[tid] += t2;
        __syncthreads();
    }
    if (tid < nb) bsum[tid] = tmp[tid];
}
__global__ void scan_final(const int* __restrict__ deg, const int* __restrict__ bsum,
                           int* __restrict__ rowptr, int* __restrict__ curs, int n) {
    __shared__ int tmp[256];
    int tid = threadIdx.x;
    int b = blockIdx.x;
    int i = b * 256 + tid;
    int v = (i < n) ? deg[i] + 1 : 0;
    tmp[tid] = v; __syncthreads();
    for (int off = 1; off < 256; off <<= 1) {
        int t2 = (tid >= off) ? tmp[tid - off] : 0;
        __syncthreads();
        tmp[tid] += t2;
        __syncthreads();
    }
    int base = (b > 0) ? bsum[b - 1] : 0;
    if (i < n) {
        rowptr[i + 1] = base + tmp[tid];
        curs[i] = base + tmp[tid] - v;
    }
    if (b == 0 && tid == 0) rowptr[0] = 0;
}
// edges + self-loops in one launch (atomic slot assignment is order-free)
__global__ void csr_fill_all(const int* __restrict__ src, const int* __restrict__ dst,
                             int* cursor, int* __restrict__ csr_src, int* __restrict__ csr_dst) {
    int e = blockIdx.x * blockDim.x + threadIdx.x;
    int s, d;
    if (e < NE)        { s = src[e]; d = dst[e]; }
    else if (e < TOTE) { s = e - NE; d = s; }
    else return;
    int slot = atomicAdd(&cursor[d], 1);
    csr_src[slot] = s;
    csr_dst[slot] = d;
}

// ---------- layer-1 scores: ONE per-edge random-gather pass ----------
__global__ void edge_score3(const int* __restrict__ csr_src, const int* __restrict__ csr_dst,
                            const float* __restrict__ es, const float* __restrict__ ed,
                            float4* __restrict__ alpha, int E) {
    int s0 = blockIdx.x * blockDim.x + threadIdx.x;
    if (s0 >= E) return;
    int s = csr_src[s0], d = csr_dst[s0];
    float l0 = leaky(es[s * 3]     + ed[d * 3]);
    float l1 = leaky(es[s * 3 + 1] + ed[d * 3 + 1]);
    float l2 = leaky(es[s * 3 + 2] + ed[d * 3 + 2]);
    alpha[s0] = float4{l0, l1, l2, 0.f};
}
// per-dst softmax over CONTIGUOUS alpha range (no random gathers)
__global__ void seg_norm3(const int* __restrict__ rowptr, float4* __restrict__ alpha, int N) {
    int d = blockIdx.x * blockDim.x + threadIdx.x;
    if (d >= N) return;
    int b = rowptr[d], e = rowptr[d + 1];
    float m0 = -1e30f, m1 = -1e30f, m2 = -1e30f;
    for (int s0 = b; s0 < e; s0++) {
        float4 a = alpha[s0];
        m0 = fmaxf(m0, a.x); m1 = fmaxf(m1, a.y); m2 = fmaxf(m2, a.z);
    }
    float dn0 = 0.f, dn1 = 0.f, dn2 = 0.f;
    for (int s0 = b; s0 < e; s0++) {
        float4 a = alpha[s0];
        float x0 = expf(a.x - m0), x1 = expf(a.y - m1), x2 = expf(a.z - m2);
        dn0 += x0; dn1 += x1; dn2 += x2;
        alpha[s0] = float4{x0, x1, x2, 0.f};
    }
    float i0 = 1.f / (dn0 + 1e-16f), i1 = 1.f / (dn1 + 1e-16f), i2 = 1.f / (dn2 + 1e-16f);
    for (int s0 = b; s0 < e; s0++) {
        float4 a = alpha[s0];
        a.x *= i0; a.y *= i1; a.z *= i2;
        alpha[s0] = a;
    }
}

// ---------- layer-2 coefs (1 head; es2 tiny, L2-resident) ----------
__global__ void csr_maxden_alpha1(const int* __restrict__ rowptr, const int* __restrict__ csr_src,
                                  const float* __restrict__ es, const float* __restrict__ ed,
                                  float* __restrict__ alpha, int N) {
    int d = blockIdx.x * blockDim.x + threadIdx.x;
    if (d >= N) return;
    float edv = ed[d];
    int b = rowptr[d], e = rowptr[d + 1];
    float mm = -1e30f;
    for (int s0 = b; s0 < e; s0++) {
        int s = csr_src[s0];
        mm = fmaxf(mm, leaky(es[s] + edv));
    }
    float dn = 0.f;
    for (int s0 = b; s0 < e; s0++) {
        int s = csr_src[s0];
        float ex = expf(leaky(es[s] + edv) - mm);
        dn += ex;
        alpha[s0] = ex;
    }
    float inv = 1.f / (dn + 1e-16f);
    for (int s0 = b; s0 < e; s0++) alpha[s0] *= inv;
}

// ---------- layer-1 aggregate (bf16 h1) + bias + ELU + (row @ W2) + layer-2 coef ----------
// r6 version: depth-4 group pipeline, 128 threads, 12 row-loads in flight/thread.
// r7 proved the pipeline IS the MLP (plain loop regressed 111->145us). FROZEN.
__global__ __launch_bounds__(128) void csr_agg1_fused(
    const int* __restrict__ rowptr, const int* __restrict__ csr_src,
    const float4* __restrict__ alpha,
    const unsigned short* __restrict__ h1, const float* __restrict__ b1,
    const float* __restrict__ W2, float* __restrict__ h2,
    const float* __restrict__ as2, const float* __restrict__ ad2,
    float* __restrict__ es2, float* __restrict__ ed2, int N)
{
    int d = blockIdx.x;
    int t = threadIdx.x;
    __shared__ float row[HC1];
    __shared__ float part[128][OUTC + 1];

    int b = rowptr[d], e = rowptr[d + 1];
    float a0 = 0.f, a1 = 0.f, a2 = 0.f;

#define LOADG(g, I, A)                                                        \
    do {                                                                      \
        int base_ = b + (g) * 4;                                              \
        _Pragma("unroll")                                                     \
        for (int j = 0; j < 4; j++) {                                         \
            int s0_ = base_ + j;                                              \
            bool v_ = s0_ < e;                                                \
            int sc_ = v_ ? s0_ : (e - 1);                                     \
            I[j] = csr_src[sc_];                                              \
            float4 t4_ = alpha[sc_];                                          \
            if (!v_) { t4_.x = 0.f; t4_.y = 0.f; t4_.z = 0.f; }               \
            A[j] = t4_;                                                       \
        }                                                                     \
    } while (0)

    int ng = (e - b + 3) >> 2;
    int   iN[4]; float4 aN[4];
    LOADG(0, iN, aN);
    float rc[12]; float4 aC[4];
#pragma unroll
    for (int j = 0; j < 4; j++) {
        const unsigned short* hp = h1 + (long)iN[j] * HC1;
        rc[3 * j] = bf16f(hp[t]); rc[3 * j + 1] = bf16f(hp[t + 128]); rc[3 * j + 2] = bf16f(hp[t + 256]);
        aC[j] = aN[j];
    }
    LOADG(1, iN, aN);
    for (int g = 1; g < ng; g++) {
        float rn[12];
#pragma unroll
        for (int j = 0; j < 4; j++) {
            const unsigned short* hp = h1 + (long)iN[j] * HC1;
            rn[3 * j] = bf16f(hp[t]); rn[3 * j + 1] = bf16f(hp[t + 128]); rn[3 * j + 2] = bf16f(hp[t + 256]);
        }
        int iT[4]; float4 aT[4];
        LOADG(g + 1, iT, aT);
#pragma unroll
        for (int j = 0; j < 4; j++) {
            a0 = fmaf(rc[3 * j],     aC[j].x, a0);
            a1 = fmaf(rc[3 * j + 1], aC[j].y, a1);
            a2 = fmaf(rc[3 * j + 2], aC[j].z, a2);
        }
#pragma unroll
        for (int j = 0; j < 12; j++) rc[j] = rn[j];
#pragma unroll
        for (int j = 0; j < 4; j++) { aC[j] = aN[j]; iN[j] = iT[j]; aN[j] = aT[j]; }
    }
#pragma unroll
    for (int j = 0; j < 4; j++) {
        a0 = fmaf(rc[3 * j],     aC[j].x, a0);
        a1 = fmaf(rc[3 * j + 1], aC[j].y, a1);
        a2 = fmaf(rc[3 * j + 2], aC[j].z, a2);
    }
#undef LOADG

    float v;
    v = a0 + b1[t];       row[t]       = v > 0.f ? v : expf(v) - 1.f;
    v = a1 + b1[t + 128]; row[t + 128] = v > 0.f ? v : expf(v) - 1.f;
    v = a2 + b1[t + 256]; row[t + 256] = v > 0.f ? v : expf(v) - 1.f;
    __syncthreads();

    float pc[OUTC];
#pragma unroll
    for (int c = 0; c < OUTC; c++) pc[c] = 0.f;
    for (int k = t; k < HC1; k += 128) {
        float rv = row[k];
        const float* wp = W2 + (long)k * OUTC;
#pragma unroll
        for (int c = 0; c < OUTC; c++) pc[c] = fmaf(rv, wp[c], pc[c]);
    }
#pragma unroll
    for (int c = 0; c < OUTC; c++) part[t][c] = pc[c];
    __syncthreads();
    for (int off = 64; off > 0; off >>= 1) {
        if (t < off) {
#pragma unroll
            for (int c = 0; c < OUTC; c++) part[t][c] += part[t + off][c];
        }
        __syncthreads();
    }
    if (t < OUTC) h2[(long)d * OUTC + t] = part[0][t];
    if (t == 0) {
        float s = 0.f, dd = 0.f;
#pragma unroll
        for (int c = 0; c < OUTC; c++) {
            float hv = part[0][c];
            s  = fmaf(hv, as2[c], s);
            dd = fmaf(hv, ad2[c], dd);
        }
        es2[d] = s; ed2[d] = dd;
    }
}

// ---------- layer-2 aggregate + bias -> padded emb (stride 12) ----------
__global__ void csr_agg2(const int* __restrict__ rowptr, const int* __restrict__ csr_src,
                         const float* __restrict__ alpha,
                         const float* __restrict__ h2, const float* __restrict__ b2,
                         float* __restrict__ emb, int N)
{
    int idx = blockIdx.x * blockDim.x + threadIdx.x;
    if (idx >= N * EMBS) return;
    int d = idx / EMBS, c = idx - d * EMBS;
    if (c >= OUTC) { emb[idx] = 0.f; return; }
    int b = rowptr[d], e = rowptr[d + 1];
    float acc = 0.f;
    for (int s0 = b; s0 < e; s0++) {
        int s = csr_src[s0];
        acc = fmaf(h2[(long)s * OUTC + c], alpha[s0], acc);
    }
    emb[idx] = acc + b2[c];
}

// ---------- pair scores (padded emb: 3 float4 loads per row) ----------
__global__ void pair_score(const int* __restrict__ pairs, const float* __restrict__ emb,
                           float* __restrict__ out, int P) {
    int p = blockIdx.x * blockDim.x + threadIdx.x;
    if (p >= P) return;
    int i0 = pairs[2 * p], i1 = pairs[2 * p + 1];
    const float4* a = (const float4*)(emb + (long)i0 * EMBS);
    const float4* b = (const float4*)(emb + (long)i1 * EMBS);
    float4 a0 = a[0], a1 = a[1], a2 = a[2];
    float4 b0 = b[0], b1 = b[1], b2 = b[2];
    float s = a0.x*b0.x + a0.y*b0.y + a0.z*b0.z + a0.w*b0.w
            + a1.x*b1.x + a1.y*b1.y + a1.z*b1.z + a1.w*b1.w
            + a2.x*b2.x + a2.y*b2.y;
    out[p] = s;
}

extern "C" void kernel_launch(void* const* d_in, const int* in_sizes, int n_in,
                              void* d_out, int out_size, void* d_ws, size_t ws_size,
                              hipStream_t stream) {
    const float* fsub = (const float*)d_in[0];
    const float* fcom = (const float*)d_in[1];
    float*       x    = (float*)d_in[2];
    const int*   com  = (const int*)d_in[3];
    const int*   ei   = (const int*)d_in[4];
    const int*   pidx = (const int*)d_in[5];
    const float* Wq = (const float*)d_in[6];  const float* bq = (const float*)d_in[7];
    const float* Wk = (const float*)d_in[8];  const float* bk = (const float*)d_in[9];
    const float* Wv = (const float*)d_in[10]; const float* bv = (const float*)d_in[11];
    const float* Wf = (const float*)d_in[12]; const float* bf = (const float*)d_in[13];
    const float* W1 = (const float*)d_in[14];
    const float* as1 = (const float*)d_in[15]; const float* ad1 = (const float*)d_in[16];
    const float* b1 = (const float*)d_in[17];
    const float* W2 = (const float*)d_in[18];
    const float* as2 = (const float*)d_in[19]; const float* ad2 = (const float*)d_in[20];
    const float* b2 = (const float*)d_in[21];
    float* out = (float*)d_out;

    const int* src = ei;
    const int* dst = ei + NE;

    typedef unsigned short u16;
    char* ws = (char*)d_ws;
    float* S     = (float*)(ws + 0);            // dead after softmax
    u16*   SH    = (u16*)(ws + 67108864);       // dead after S@v
    u16*   fsubH = (u16*)(ws + 134217728);      // dead after q proj
    u16*   fsubL = (u16*)(ws + 136839168);      // unused
    u16*   fcomH = (u16*)(ws + 139460608);      // dead after k,v proj
    u16*   fcomL = (u16*)(ws + 142082048);      // unused
    u16*   qH    = (u16*)(ws + 144703488);      // dead after S gemm
    u16*   qL    = (u16*)(ws + 147324928);      // unused
    u16*   kH    = (u16*)(ws + 149946368);
    u16*   kL    = (u16*)(ws + 152567808);      // unused
    u16*   vTH   = (u16*)(ws + 155189248);      // dead after S@v
    u16*   vTL   = (u16*)(ws + 157646848);      // unused
    u16*   attnH = (u16*)(ws + 160104448);      // dead after fus gemm
    u16*   attnL = (u16*)(ws + 162725888);
    u16*   WqTH  = (u16*)(ws + 165347328);
    u16*   WqTL  = (u16*)(ws + 165539328);
    u16*   WkTH  = (u16*)(ws + 165731328);
    u16*   WkTL  = (u16*)(ws + 165923328);
    u16*   WvTH  = (u16*)(ws + 166115328);
    u16*   WvTL  = (u16*)(ws + 166307328);
    u16*   WfTH  = (u16*)(ws + 166499328);
    u16*   WfTL  = (u16*)(ws + 166691328);
    u16*   W1TH  = (u16*)(ws + 166883328);
    u16*   W1TL  = (u16*)(ws + 167129088);
    float* fus   = (float*)(ws + 167374848);    // alive until scatter
    float* es1   = (float*)(ws + 172290048);
    float* ed1   = (float*)(ws + 172890048);
    float* es2   = (float*)(ws + 174690048);
    float* ed2   = (float*)(ws + 174890048);
    float* h2    = (float*)(ws + 175490048);
    int*   last  = (int*)(ws + 179490048);
    int*   deg   = (int*)(ws + 179690048);
    int*   curs  = (int*)(ws + 179890048);
    int*   rowp  = (int*)(ws + 180090048);
    int*   csrc  = (int*)(ws + 180290064);      // ends 182,490,064
    int*   bsum  = (int*)(ws + 182490112);      // 196 ints
    // overlays (disjoint in time):
    float* part   = (float*)(ws + 0);           // over dead S (S@v phase), 4 slices
    u16*   h1b    = (u16*)(ws + 0);             // bf16 h1 over dead S/SH (GAT phase), 38.4MB
    u16*   xH     = (u16*)(ws + 76800000);      // over dead SH-tail; dead after h1 gemm
    u16*   xL     = (u16*)(ws + 108800000);
    float* alpha1 = (float*)(ws + 134217728);   // over dead fsubH.. (GAT phase), 8.8MB
    float* alpha2 = (float*)(ws + 144703488);   // over dead qH (GAT phase), 2.2MB -> ends 146,903,488
    int*   csrd   = (int*)(ws + 160104448);     // over dead attnH (CSR phase on), 2.2MB
    float* embp   = (float*)(ws + 147324928);   // over dead qL/kH, 2.4MB -> ends 149,724,928

    const float inv_sqrt_d = 1.0f / sqrtf((float)FEAT);

    // ===== 0. conversions (batched) =====
    {
        long tot5 = 4L * FEAT * KP + (long)HC1 * KP;   // 506,880
        hipLaunchKernelGGL(convT_pad5, dim3(cdiv((int)tot5, 256)), dim3(256), 0, stream,
                           Wq, Wk, Wv, Wf, W1,
                           WqTH, WqTL, WkTH, WkTL, WvTH, WvTL, WfTH, WfTL, W1TH, W1TL);
    }
    hipLaunchKernelGGL(conv_pad8_2h, dim3(cdiv(2*BP*(KP/8),256)), dim3(256), 0, stream,
                       fsub, fcom, fsubH, fcomH);
    hipMemsetAsync(qH, 0, 10485760, stream);   // zero qH..kL (incl. K-tail cols 300..319)

    // ===== 1. cross attention =====
    // q/k/v projections: SINGLE-bf16 64x64 tile (their outputs are consumed as
    // single bf16 by the r10-validated attention path; lo terms were discarded)
    hipLaunchKernelGGL((gemm_bf1<1>), dim3(cdiv(FEAT,64), cdiv(BP,64)), dim3(256), 0, stream,
                       fsubH, KP, WqTH, KP, bq, qH, BP, FEAT, FEAT, KP);
    hipLaunchKernelGGL((gemm_bf1<1>), dim3(cdiv(FEAT,64), cdiv(BP,64)), dim3(256), 0, stream,
                       fcomH, KP, WkTH, KP, bk, kH, BP, FEAT, FEAT, KP);
    hipLaunchKernelGGL((gemm_bf1<2>), dim3(cdiv(FEAT,64), cdiv(BP,64)), dim3(256), 0, stream,
                       fcomH, KP, WvTH, KP, bv, vTH, BP, FEAT, FEAT, BP);
    // S = (q @ k^T) * inv_sqrt_d  — single-bf16 (r10-validated)
    hipLaunchKernelGGL((gemm_gl64k<false, 0>), dim3(cdiv(BP,128), cdiv(BP,128)), dim3(256), 0, stream,
                       qH, KP, kH, KP, S, nullptr, BP, BP, FEAT, inv_sqrt_d, 0);
    hipLaunchKernelGGL(softmax_h, dim3(BP), dim3(256), 0, stream, S, SH);
    // part[z] = S_z @ v — single-bf16, split-K 4x1024
    hipLaunchKernelGGL((gemm_gl64k<true, 0>), dim3(cdiv(FEAT,128), cdiv(BP,128), 4), dim3(256), 0, stream,
                       SH, BP, vTH, BP, part, nullptr, BP, FEAT, BP, 1.0f, 1024);
    hipLaunchKernelGGL(splitk_reduce8, dim3(cdiv(BP*(KP/8),256)), dim3(256), 0, stream,
                       part, fsub, attnH, attnL, BP, FEAT, KP, 4);
    // fus = attn @ Wf + bf — FULL SPLIT precision (residual-magnitude operand)
    hipLaunchKernelGGL((gemm_bf<0>), dim3(cdiv(FEAT,64), cdiv(BP,64)), dim3(256), 0, stream,
                       attnH, attnL, KP, WfTH, WfTL, KP, bf, nullptr, fus, nullptr, nullptr,
                       BP, FEAT, FEAT, 1.0f, FEAT);

    // ===== 2. convert pristine x, then scatter fused rows directly as bf16 =====
    hipLaunchKernelGGL(conv_pad8, dim3(cdiv((long)NN*(KP/8),256)), dim3(256), 0, stream, x, xH, xL, NN, FEAT, KP);
    hipLaunchKernelGGL(scatter_init, dim3(cdiv(BP,256)), dim3(256), 0, stream, last, com, BP);
    hipLaunchKernelGGL(scatter_max,  dim3(cdiv(BP,256)), dim3(256), 0, stream, last, com, BP);
    hipLaunchKernelGGL(scatter_write_hl, dim3(BP), dim3(128), 0, stream, last, com, fus, xH, xL, BP);

    // ===== 3. CSR build =====
    hipMemsetAsync(deg, 0, NN * sizeof(int), stream);
    hipLaunchKernelGGL(deg_count, dim3(cdiv(NE,256)), dim3(256), 0, stream, dst, deg, NE);
    {
        int nb = cdiv(NN, 256);   // 196
        hipLaunchKernelGGL(scan_part,  dim3(nb), dim3(256), 0, stream, deg, bsum, NN);
        hipLaunchKernelGGL(scan_bsum,  dim3(1),  dim3(256), 0, stream, bsum, nb);
        hipLaunchKernelGGL(scan_final, dim3(nb), dim3(256), 0, stream, deg, bsum, rowp, curs, NN);
    }
    hipLaunchKernelGGL(csr_fill_all, dim3(cdiv(TOTE,256)), dim3(256), 0, stream,
                       src, dst, curs, csrc, csrd);

    // ===== 4. GAT layer 1 (h1 single-bf16 GEMM -> bf16; working set 38.4 MB) =====
    hipLaunchKernelGGL((gemm_gl64k<false, 1>), dim3(cdiv(HC1,128), cdiv(NN,128)), dim3(256), 0, stream,
                       xH, KP, W1TH, KP, nullptr, h1b, NN, HC1, FEAT, 1.0f, 0);
    hipLaunchKernelGGL(node_attn_coef3, dim3(cdiv(NN,4)), dim3(256), 0, stream,
                       h1b, as1, ad1, es1, ed1, NN);
    hipLaunchKernelGGL(edge_score3, dim3(cdiv(TOTE,256)), dim3(256), 0, stream,
                       csrc, csrd, es1, ed1, (float4*)alpha1, TOTE);
    hipLaunchKernelGGL(seg_norm3, dim3(cdiv(NN,256)), dim3(256), 0, stream,
                       rowp, (float4*)alpha1, NN);
    hipLaunchKernelGGL(csr_agg1_fused, dim3(NN), dim3(128), 0, stream,
                       rowp, csrc, (const float4*)alpha1, h1b, b1, W2, h2, as2, ad2, es2, ed2, NN);

    // ===== 5. GAT layer 2 =====
    hipLaunchKernelGGL(csr_maxden_alpha1, dim3(cdiv(NN,256)), dim3(256), 0, stream,
                       rowp, csrc, es2, ed2, alpha2, NN);
    hipLaunchKernelGGL(csr_agg2, dim3(cdiv(NN*EMBS,256)), dim3(256), 0, stream,
                       rowp, csrc, alpha2, h2, b2, embp, NN);

    // ===== 6. pair scores =====
    hipLaunchKernelGGL(pair_score, dim3(cdiv(NP,256)), dim3(256), 0, stream, pidx, embp, out, NP);
}